// Round 10
// baseline (2674.711 us; speedup 1.0000x reference)
//
#include <hip/hip_runtime.h>
#include <hip/hip_bf16.h>
#include <math.h>

#define BB 32
#define SS 512
#define DD 512
#define HH 8
#define DK 64
#define LL 6
#define NQ 8
#define FF 2048
#define CC 10

typedef unsigned int uint;
typedef unsigned short ushort_t;
using bf16x8 = __attribute__((ext_vector_type(8))) short;
using f32x4  = __attribute__((ext_vector_type(4))) float;

#define MFMA(a, b, c) __builtin_amdgcn_mfma_f32_16x16x32_bf16((a), (b), (c), 0, 0, 0)

union U8 { ushort_t u[8]; bf16x8 v; };

__device__ inline ushort_t f2bf(float x) {           // fp32 -> bf16, RNE
    uint u = __float_as_uint(x);
    u += 0x7FFFu + ((u >> 16) & 1u);
    return (ushort_t)(u >> 16);
}
// truncation split: hi = top 16 bits, lo = RNE(residual); hi+lo = v to ~2^-17 rel
__device__ inline void tsplit(float v, ushort_t& hi, ushort_t& lo) {
    uint u = __float_as_uint(v);
    hi = (ushort_t)(u >> 16);
    lo = f2bf(v - __uint_as_float(u & 0xFFFF0000u));
}
// cheap variant (lo also truncated, ~2^-16): used on A2 only
__device__ inline void tsplit_fast(float v, ushort_t& hi, ushort_t& lo) {
    uint u = __float_as_uint(v);
    hi = (ushort_t)(u >> 16);
    float res = v - __uint_as_float(u & 0xFFFF0000u);
    lo = (ushort_t)(__float_as_uint(res) >> 16);
}
__device__ inline uint packsplit(float v) {
    uint u = __float_as_uint(v) & 0xFFFF0000u;
    uint ru = __float_as_uint(v - __uint_as_float(u));
    ru += 0x7FFFu + ((ru >> 16) & 1u);
    return u | (ru >> 16);
}
__device__ inline float unpackf(uint u) {
    return __uint_as_float(u & 0xFFFF0000u) + __uint_as_float(u << 16);
}

// ---------------------------------------------------------------------------
// Kernel 1: h[b,s,d] = emb[x[b,s], d] + pe(s,d), stored packed hi|lo bf16
// ---------------------------------------------------------------------------
__global__ __launch_bounds__(256) void embed_pe(const int* __restrict__ x,
                                                const float* __restrict__ emb,
                                                uint* __restrict__ Hp) {
    int idx = blockIdx.x * 256 + threadIdx.x;
    if (idx >= BB * SS * DD) return;
    int d = idx & (DD - 1);
    int s = (idx >> 9) & (SS - 1);
    int tok = x[idx >> 9];
    int i2 = d >> 1;
    float freq = expf((float)(2 * i2) * (-9.210340371976184f / (float)DD));
    float ang = (float)s * freq;
    float pe = (d & 1) ? cosf(ang) : sinf(ang);
    Hp[idx] = packsplit(emb[(size_t)tok * DD + d] + pe);
}

// ---------------------------------------------------------------------------
// Kernel 1b: transpose + split fp32 [K][N] -> bf16 hi/lo [N][K]  (weight prep)
// ---------------------------------------------------------------------------
__global__ __launch_bounds__(256) void transpose_split_w(const float* __restrict__ in,
                                                         ushort_t* __restrict__ outh,
                                                         ushort_t* __restrict__ outl,
                                                         int K, int N) {
    __shared__ ushort_t th[64][68], tl[64][68];
    int nb = N >> 6;
    int k0 = ((int)blockIdx.x / nb) << 6;
    int n0 = ((int)blockIdx.x % nb) << 6;
    int t = threadIdx.x;
    int r = t >> 2, cb = (t & 3) << 4;
#pragma unroll
    for (int c = 0; c < 4; c++) {
        float4 v = *reinterpret_cast<const float4*>(&in[(size_t)(k0 + r) * N + n0 + cb + 4 * c]);
        float vv[4] = {v.x, v.y, v.z, v.w};
#pragma unroll
        for (int e = 0; e < 4; e++) {
            ushort_t hb, lb; tsplit(vv[e], hb, lb);
            th[r][cb + 4 * c + e] = hb;
            tl[r][cb + 4 * c + e] = lb;
        }
    }
    __syncthreads();
    int n = t >> 2, kb = (t & 3) << 4;
#pragma unroll
    for (int c = 0; c < 4; c++) {
        ushort4 oh, ol;
        oh.x = th[kb + 4 * c + 0][n]; ol.x = tl[kb + 4 * c + 0][n];
        oh.y = th[kb + 4 * c + 1][n]; ol.y = tl[kb + 4 * c + 1][n];
        oh.z = th[kb + 4 * c + 2][n]; ol.z = tl[kb + 4 * c + 2][n];
        oh.w = th[kb + 4 * c + 3][n]; ol.w = tl[kb + 4 * c + 3][n];
        *reinterpret_cast<ushort4*>(&outh[(size_t)(n0 + n) * K + k0 + kb + 4 * c]) = oh;
        *reinterpret_cast<ushort4*>(&outl[(size_t)(n0 + n) * K + k0 + kb + 4 * c]) = ol;
    }
}

// ---------------------------------------------------------------------------
// Kernel 1c: W1 [L][8][FF] -> transposed split planes [L][FF][8] bf16 hi/lo
// ---------------------------------------------------------------------------
__global__ __launch_bounds__(256) void prep_w1t(const float* __restrict__ W1all,
                                                ushort_t* __restrict__ outh,
                                                ushort_t* __restrict__ outl) {
    int l = blockIdx.y;
    int f = blockIdx.x * 256 + threadIdx.x;
    const float* W1 = W1all + (size_t)l * NQ * FF;
    U8 ph, pl;
#pragma unroll
    for (int n = 0; n < 8; n++) {
        ushort_t hb, lb; tsplit(W1[n * FF + f], hb, lb);
        ph.u[n] = hb; pl.u[n] = lb;
    }
    *reinterpret_cast<bf16x8*>(&outh[((size_t)l * FF + f) * 8]) = ph.v;
    *reinterpret_cast<bf16x8*>(&outl[((size_t)l * FF + f) * 8]) = pl.v;
}

// ---------------------------------------------------------------------------
// Kernel 2: split-precision MFMA flash attention, QBLK=128, 8 waves.
// (unchanged from round 8)
// ---------------------------------------------------------------------------
__global__ __launch_bounds__(512, 4) void flash_attn_split(const uint* __restrict__ Hp,
                                                           ushort_t* __restrict__ outh,
                                                           ushort_t* __restrict__ outl) {
    __shared__ __align__(16) ushort_t Kh[64][72], Kl[64][72];
    __shared__ __align__(16) ushort_t Vh[64][72], Vl[64][72];   // [d][j]
    __shared__ __align__(16) ushort_t Ph[128][72], Pl[128][72];

    int i0 = blockIdx.x * 128;
    int h0 = blockIdx.y * DK;
    int b  = blockIdx.z;
    const uint* baseH = Hp + (size_t)b * (SS * DD);

    int t = threadIdx.x;
    int w = t >> 6;
    int ln = t & 63;
    int l15 = ln & 15, lh = ln >> 4;

    bf16x8 aqh0, aqh1, aql0, aql1;
    {
        int row = i0 + w * 16 + l15;
        const uint* src = &baseH[(size_t)row * DD + h0 + lh * 8];
        uint4 p0 = *reinterpret_cast<const uint4*>(src);
        uint4 p1 = *reinterpret_cast<const uint4*>(src + 4);
        uint4 p2 = *reinterpret_cast<const uint4*>(src + 32);
        uint4 p3 = *reinterpret_cast<const uint4*>(src + 36);
        uint a0[8] = {p0.x, p0.y, p0.z, p0.w, p1.x, p1.y, p1.z, p1.w};
        uint a1[8] = {p2.x, p2.y, p2.z, p2.w, p3.x, p3.y, p3.z, p3.w};
        U8 h0u, l0u, h1u, l1u;
#pragma unroll
        for (int e = 0; e < 8; e++) {
            h0u.u[e] = (ushort_t)(a0[e] >> 16);
            l0u.u[e] = (ushort_t)(a0[e] & 0xFFFFu);
            h1u.u[e] = (ushort_t)(a1[e] >> 16);
            l1u.u[e] = (ushort_t)(a1[e] & 0xFFFFu);
        }
        aqh0 = h0u.v; aql0 = l0u.v; aqh1 = h1u.v; aql1 = l1u.v;
    }

    float m_[4], l_[4], al[4];
    f32x4 acc[4];
    f32x4 z4 = {0.f, 0.f, 0.f, 0.f};
#pragma unroll
    for (int r = 0; r < 4; r++) { m_[r] = -1e30f; l_[r] = 0.f; acc[r] = z4; }

    int kr = t >> 3, kcb = (t & 7) * 8;
    int vc = t & 7, vr = t >> 3;

    for (int j0 = 0; j0 < SS; j0 += 64) {
        __syncthreads();
        {
            const uint* src = &baseH[(size_t)(j0 + kr) * DD + h0 + kcb];
            uint4 p0 = *reinterpret_cast<const uint4*>(src);
            uint4 p1 = *reinterpret_cast<const uint4*>(src + 4);
            uint a[8] = {p0.x, p0.y, p0.z, p0.w, p1.x, p1.y, p1.z, p1.w};
            U8 kh, kl;
#pragma unroll
            for (int e = 0; e < 8; e++) {
                kh.u[e] = (ushort_t)(a[e] >> 16);
                kl.u[e] = (ushort_t)(a[e] & 0xFFFFu);
            }
            *reinterpret_cast<bf16x8*>(&Kh[kr][kcb]) = kh.v;
            *reinterpret_cast<bf16x8*>(&Kl[kr][kcb]) = kl.v;
        }
        __syncthreads();
#pragma unroll
        for (int e = 0; e < 8; e++) {
            int d = vc + 8 * e;
            Vh[d][vr] = Kh[vr][d];
            Vl[d][vr] = Kl[vr][d];
        }
        f32x4 sc[4];
#pragma unroll
        for (int tt = 0; tt < 4; tt++) {
            bf16x8 bh0 = *reinterpret_cast<const bf16x8*>(&Kh[tt * 16 + l15][lh * 8]);
            bf16x8 bh1 = *reinterpret_cast<const bf16x8*>(&Kh[tt * 16 + l15][32 + lh * 8]);
            bf16x8 bl0 = *reinterpret_cast<const bf16x8*>(&Kl[tt * 16 + l15][lh * 8]);
            bf16x8 bl1 = *reinterpret_cast<const bf16x8*>(&Kl[tt * 16 + l15][32 + lh * 8]);
            f32x4 s = z4;
            s = MFMA(aqh0, bh0, s);
            s = MFMA(aqh1, bh1, s);
            s = MFMA(aqh0, bl0, s);
            s = MFMA(aqh1, bl1, s);
            s = MFMA(aql0, bh0, s);
            s = MFMA(aql1, bh1, s);
            sc[tt] = s * 0.125f;
        }
#pragma unroll
        for (int r = 0; r < 4; r++) {
            float mx = fmaxf(fmaxf(sc[0][r], sc[1][r]), fmaxf(sc[2][r], sc[3][r]));
            mx = fmaxf(mx, __shfl_xor(mx, 1));
            mx = fmaxf(mx, __shfl_xor(mx, 2));
            mx = fmaxf(mx, __shfl_xor(mx, 4));
            mx = fmaxf(mx, __shfl_xor(mx, 8));
            float nm = fmaxf(m_[r], mx);
            al[r] = __expf(m_[r] - nm);
            m_[r] = nm;
            float rs = 0.f;
#pragma unroll
            for (int tt = 0; tt < 4; tt++) {
                float p = __expf(sc[tt][r] - nm);
                sc[tt][r] = p;
                rs += p;
            }
            rs += __shfl_xor(rs, 1);
            rs += __shfl_xor(rs, 2);
            rs += __shfl_xor(rs, 4);
            rs += __shfl_xor(rs, 8);
            l_[r] = l_[r] * al[r] + rs;
        }
#pragma unroll
        for (int tt = 0; tt < 4; tt++)
#pragma unroll
            for (int r = 0; r < 4; r++) {
                ushort_t hb, lb; tsplit(sc[tt][r], hb, lb);
                Ph[w * 16 + lh * 4 + r][tt * 16 + l15] = hb;
                Pl[w * 16 + lh * 4 + r][tt * 16 + l15] = lb;
            }
        __syncthreads();
#pragma unroll
        for (int td = 0; td < 4; td++) {
            acc[td][0] *= al[0];
            acc[td][1] *= al[1];
            acc[td][2] *= al[2];
            acc[td][3] *= al[3];
        }
        bf16x8 aph0 = *reinterpret_cast<const bf16x8*>(&Ph[w * 16 + l15][lh * 8]);
        bf16x8 aph1 = *reinterpret_cast<const bf16x8*>(&Ph[w * 16 + l15][32 + lh * 8]);
        bf16x8 apl0 = *reinterpret_cast<const bf16x8*>(&Pl[w * 16 + l15][lh * 8]);
        bf16x8 apl1 = *reinterpret_cast<const bf16x8*>(&Pl[w * 16 + l15][32 + lh * 8]);
#pragma unroll
        for (int td = 0; td < 4; td++) {
            bf16x8 bvh0 = *reinterpret_cast<const bf16x8*>(&Vh[td * 16 + l15][lh * 8]);
            bf16x8 bvh1 = *reinterpret_cast<const bf16x8*>(&Vh[td * 16 + l15][32 + lh * 8]);
            bf16x8 bvl0 = *reinterpret_cast<const bf16x8*>(&Vl[td * 16 + l15][lh * 8]);
            bf16x8 bvl1 = *reinterpret_cast<const bf16x8*>(&Vl[td * 16 + l15][32 + lh * 8]);
            acc[td] = MFMA(aph0, bvh0, acc[td]);
            acc[td] = MFMA(aph1, bvh1, acc[td]);
            acc[td] = MFMA(aph0, bvl0, acc[td]);
            acc[td] = MFMA(aph1, bvl1, acc[td]);
            acc[td] = MFMA(apl0, bvh0, acc[td]);
            acc[td] = MFMA(apl1, bvh1, acc[td]);
        }
    }

#pragma unroll
    for (int r = 0; r < 4; r++) {
        float inv = 1.f / l_[r];
        int row = i0 + w * 16 + lh * 4 + r;
#pragma unroll
        for (int td = 0; td < 4; td++) {
            float o = acc[td][r] * inv;
            ushort_t hb, lb; tsplit(o, hb, lb);
            size_t idx = (size_t)b * SS * DD + (size_t)row * DD + h0 + td * 16 + l15;
            outh[idx] = hb;
            outl[idx] = lb;
        }
    }
}

// ---------------------------------------------------------------------------
// Kernel 3: C fp32 = A(hi/lo [M][K]) @ Bt(pre-split hi/lo [N][K]) + bias.
// 128x128 tile, BK=64, 512 thr / 8 waves, register double-buffer prefetch:
// next tile's global loads issue during current tile's MFMA phase.
// ---------------------------------------------------------------------------
__global__ __launch_bounds__(512, 4) void gemm_split(const ushort_t* __restrict__ Ah,
                                                     const ushort_t* __restrict__ Al,
                                                     const ushort_t* __restrict__ Bth,
                                                     const ushort_t* __restrict__ Btl,
                                                     const float* __restrict__ bias,
                                                     float* __restrict__ C,
                                                     int M, int N, int K) {
    __shared__ __align__(16) ushort_t Abh[128][72], Abl[128][72];
    __shared__ __align__(16) ushort_t Bbh[128][72], Bbl[128][72];
    int nb = N >> 7;
    int m0 = ((int)blockIdx.x / nb) << 7;
    int n0 = ((int)blockIdx.x % nb) << 7;
    int t = threadIdx.x;
    int w = t >> 6, ln = t & 63, l15 = ln & 15, lh = ln >> 4;
    int wr = (w >> 2) * 64, wc = (w & 3) * 32;

    f32x4 z4 = {0.f, 0.f, 0.f, 0.f};
    f32x4 acc[4][2];
#pragma unroll
    for (int i = 0; i < 4; i++)
#pragma unroll
        for (int j = 0; j < 2; j++) acc[i][j] = z4;

    int arr = t >> 3, akk = (t & 7) * 8;   // 64 rows x 8 cols per pass

    // prologue: prefetch tile 0 into registers
    uint4 rah[2], ral[2], rbh[2], rbl[2];
#pragma unroll
    for (int r = 0; r < 2; r++) {
        int row = arr + r * 64;
        rah[r] = *reinterpret_cast<const uint4*>(&Ah[(size_t)(m0 + row) * K + akk]);
        ral[r] = *reinterpret_cast<const uint4*>(&Al[(size_t)(m0 + row) * K + akk]);
        rbh[r] = *reinterpret_cast<const uint4*>(&Bth[(size_t)(n0 + row) * K + akk]);
        rbl[r] = *reinterpret_cast<const uint4*>(&Btl[(size_t)(n0 + row) * K + akk]);
    }

    for (int k0 = 0; k0 < K; k0 += 64) {
        __syncthreads();   // prev MFMA done -> LDS writable
#pragma unroll
        for (int r = 0; r < 2; r++) {
            int row = arr + r * 64;
            *reinterpret_cast<uint4*>(&Abh[row][akk]) = rah[r];
            *reinterpret_cast<uint4*>(&Abl[row][akk]) = ral[r];
            *reinterpret_cast<uint4*>(&Bbh[row][akk]) = rbh[r];
            *reinterpret_cast<uint4*>(&Bbl[row][akk]) = rbl[r];
        }
        __syncthreads();   // LDS ready
        if (k0 + 64 < K) {
            int k1 = k0 + 64;
#pragma unroll
            for (int r = 0; r < 2; r++) {
                int row = arr + r * 64;
                rah[r] = *reinterpret_cast<const uint4*>(&Ah[(size_t)(m0 + row) * K + k1 + akk]);
                ral[r] = *reinterpret_cast<const uint4*>(&Al[(size_t)(m0 + row) * K + k1 + akk]);
                rbh[r] = *reinterpret_cast<const uint4*>(&Bth[(size_t)(n0 + row) * K + k1 + akk]);
                rbl[r] = *reinterpret_cast<const uint4*>(&Btl[(size_t)(n0 + row) * K + k1 + akk]);
            }
        }
#pragma unroll
        for (int ks = 0; ks < 2; ks++) {
            bf16x8 ah[4], al_[4];
#pragma unroll
            for (int mt = 0; mt < 4; mt++) {
                ah[mt]  = *reinterpret_cast<const bf16x8*>(&Abh[wr + mt * 16 + l15][ks * 32 + lh * 8]);
                al_[mt] = *reinterpret_cast<const bf16x8*>(&Abl[wr + mt * 16 + l15][ks * 32 + lh * 8]);
            }
#pragma unroll
            for (int nt = 0; nt < 2; nt++) {
                bf16x8 bh = *reinterpret_cast<const bf16x8*>(&Bbh[wc + nt * 16 + l15][ks * 32 + lh * 8]);
                bf16x8 bl = *reinterpret_cast<const bf16x8*>(&Bbl[wc + nt * 16 + l15][ks * 32 + lh * 8]);
#pragma unroll
                for (int mt = 0; mt < 4; mt++) {
                    acc[mt][nt] = MFMA(ah[mt], bh, acc[mt][nt]);
                    acc[mt][nt] = MFMA(ah[mt], bl, acc[mt][nt]);
                    acc[mt][nt] = MFMA(al_[mt], bh, acc[mt][nt]);
                }
            }
        }
    }
#pragma unroll
    for (int nt = 0; nt < 2; nt++) {
        int col = n0 + wc + nt * 16 + l15;
        float bs = bias[col];
#pragma unroll
        for (int mt = 0; mt < 4; mt++)
#pragma unroll
            for (int r = 0; r < 4; r++)
                C[(size_t)(m0 + wr + mt * 16 + lh * 4 + r) * N + col] = acc[mt][nt][r] + bs;
    }
}

// ---------------------------------------------------------------------------
// Kernel 4: Hp = pack(layernorm(unpack(Hp) + add) * g + b)
// ---------------------------------------------------------------------------
__global__ __launch_bounds__(256) void ln_residual(uint* __restrict__ Hp,
                                                   const float* __restrict__ add,
                                                   const float* __restrict__ g,
                                                   const float* __restrict__ bta) {
    int row = blockIdx.x * 4 + (threadIdx.x >> 6);
    int lane = threadIdx.x & 63;
    uint* hp = Hp + (size_t)row * DD;
    const float* ap = add + (size_t)row * DD;
    float v[8];
    float sum = 0.f;
#pragma unroll
    for (int i = 0; i < 8; i++) {
        int d = lane + i * 64;
        v[i] = unpackf(hp[d]) + ap[d];
        sum += v[i];
    }
#pragma unroll
    for (int off = 32; off > 0; off >>= 1) sum += __shfl_xor(sum, off);
    float mu = sum * (1.f / DD);
    float s2 = 0.f;
#pragma unroll
    for (int i = 0; i < 8; i++) {
        float d2 = v[i] - mu;
        s2 += d2 * d2;
    }
#pragma unroll
    for (int off = 32; off > 0; off >>= 1) s2 += __shfl_xor(s2, off);
    float inv = rsqrtf(s2 * (1.f / DD) + 1e-5f);
#pragma unroll
    for (int i = 0; i < 8; i++) {
        int d = lane + i * 64;
        hp[d] = packsplit((v[i] - mu) * inv * g[d] + bta[d]);
    }
}

// ---------------------------------------------------------------------------
// Kernel 5: fused FFN, 128x128 tile, BK=64, 512 thr / 8 waves, register
// double-buffer prefetch of W2 tiles and W1 fragments.
// A2 = relu(qout@W1+b1) on the matrix pipe.
// ---------------------------------------------------------------------------
__global__ __launch_bounds__(512, 4) void ffn_split(const uint* __restrict__ Hp,
                                                    const ushort_t* __restrict__ W1th,
                                                    const ushort_t* __restrict__ W1tl,
                                                    const float* __restrict__ b1,
                                                    const ushort_t* __restrict__ W2th,
                                                    const ushort_t* __restrict__ W2tl,
                                                    const float* __restrict__ b2,
                                                    const float* __restrict__ theta,
                                                    float* __restrict__ outp) {
    __shared__ __align__(16) ushort_t Abh[128][72], Abl[128][72];
    __shared__ __align__(16) ushort_t Bbh[128][72], Bbl[128][72];
    __shared__ __align__(16) ushort_t qsh[129][8], qsl[129][8];
    __shared__ float tcs[8];

    int t = threadIdx.x;
    int m0 = (int)(blockIdx.x >> 2) * 128;
    int n0 = (int)(blockIdx.x & 3) * 128;
    if (t < 8) {
        tcs[t] = cosf(theta[t]);
        qsh[128][t] = 0;
        qsl[128][t] = 0;
    }
    __syncthreads();
#pragma unroll
    for (int i = 0; i < 2; i++) {
        int idx = t + i * 512;
        int m = idx >> 3, n = idx & 7;
        float q = cosf(unpackf(Hp[(size_t)(m0 + m) * DD + n])) * tcs[n];
        ushort_t hb, lb; tsplit(q, hb, lb);
        qsh[m][n] = hb;
        qsl[m][n] = lb;
    }

    int w = t >> 6, ln = t & 63, l15 = ln & 15, lh = ln >> 4;
    int wr = (w >> 2) * 64, wc = (w & 3) * 32;
    bool lh0 = (lh == 0);
    f32x4 z4 = {0.f, 0.f, 0.f, 0.f};
    bf16x8 z8 = {0, 0, 0, 0, 0, 0, 0, 0};
    f32x4 acc[4][2];
#pragma unroll
    for (int i = 0; i < 4; i++)
#pragma unroll
        for (int j = 0; j < 2; j++) acc[i][j] = z4;

    int brr = t >> 3, bkk = (t & 7) * 8;

    // prologue: prefetch B tile 0 + W1 frags 0
    uint4 rbh[2], rbl[2];
    bf16x8 rwh[4], rwl[4];
#pragma unroll
    for (int r = 0; r < 2; r++) {
        int row = brr + r * 64;
        rbh[r] = *reinterpret_cast<const uint4*>(&W2th[(size_t)(n0 + row) * FF + bkk]);
        rbl[r] = *reinterpret_cast<const uint4*>(&W2tl[(size_t)(n0 + row) * FF + bkk]);
    }
#pragma unroll
    for (int fq = 0; fq < 4; fq++) {
        rwh[fq] = *reinterpret_cast<const bf16x8*>(&W1th[(size_t)(fq * 16 + l15) * 8]);
        rwl[fq] = *reinterpret_cast<const bf16x8*>(&W1tl[(size_t)(fq * 16 + l15) * 8]);
    }

    for (int k0 = 0; k0 < FF; k0 += 64) {
        __syncthreads();   // prev MFMA done -> LDS writable
        // ---- B tile: registers -> LDS
#pragma unroll
        for (int r = 0; r < 2; r++) {
            int row = brr + r * 64;
            *reinterpret_cast<uint4*>(&Bbh[row][bkk]) = rbh[r];
            *reinterpret_cast<uint4*>(&Bbl[row][bkk]) = rbl[r];
        }
        // ---- A2 via MFMA using prefetched W1 frags: wave w computes rows w*16..+15
        {
            bf16x8 wh[4], wl[4];
#pragma unroll
            for (int fq = 0; fq < 4; fq++) {
                wh[fq] = lh0 ? rwh[fq] : z8;
                wl[fq] = lh0 ? rwl[fq] : z8;
            }
            int m = w * 16 + l15;
            int mrow = lh0 ? m : 128;
            bf16x8 qh  = *reinterpret_cast<const bf16x8*>(&qsh[mrow][0]);
            bf16x8 ql_ = *reinterpret_cast<const bf16x8*>(&qsl[mrow][0]);
#pragma unroll
            for (int fq = 0; fq < 4; fq++) {
                f32x4 d = z4;
                d = MFMA(wh[fq], qh, d);
                d = MFMA(wh[fq], ql_, d);
                d = MFMA(wl[fq], qh, d);
                float4 b1v = *reinterpret_cast<const float4*>(&b1[k0 + fq * 16 + lh * 4]);
                float v0 = fmaxf(d[0] + b1v.x, 0.f);
                float v1 = fmaxf(d[1] + b1v.y, 0.f);
                float v2 = fmaxf(d[2] + b1v.z, 0.f);
                float v3 = fmaxf(d[3] + b1v.w, 0.f);
                ushort_t h0_, l0_, h1_, l1_, h2_, l2_, h3_, l3_;
                tsplit_fast(v0, h0_, l0_);
                tsplit_fast(v1, h1_, l1_);
                tsplit_fast(v2, h2_, l2_);
                tsplit_fast(v3, h3_, l3_);
                uint2 hu, lu;
                hu.x = (uint)h0_ | ((uint)h1_ << 16);
                hu.y = (uint)h2_ | ((uint)h3_ << 16);
                lu.x = (uint)l0_ | ((uint)l1_ << 16);
                lu.y = (uint)l2_ | ((uint)l3_ << 16);
                *reinterpret_cast<uint2*>(&Abh[m][fq * 16 + lh * 4]) = hu;
                *reinterpret_cast<uint2*>(&Abl[m][fq * 16 + lh * 4]) = lu;
            }
        }
        __syncthreads();   // LDS ready
        // ---- prefetch next tile (overlaps with MFMA below)
        if (k0 + 64 < FF) {
            int k1 = k0 + 64;
#pragma unroll
            for (int r = 0; r < 2; r++) {
                int row = brr + r * 64;
                rbh[r] = *reinterpret_cast<const uint4*>(&W2th[(size_t)(n0 + row) * FF + k1 + bkk]);
                rbl[r] = *reinterpret_cast<const uint4*>(&W2tl[(size_t)(n0 + row) * FF + k1 + bkk]);
            }
#pragma unroll
            for (int fq = 0; fq < 4; fq++) {
                rwh[fq] = *reinterpret_cast<const bf16x8*>(&W1th[(size_t)(k1 + fq * 16 + l15) * 8]);
                rwl[fq] = *reinterpret_cast<const bf16x8*>(&W1tl[(size_t)(k1 + fq * 16 + l15) * 8]);
            }
        }
        // ---- main GEMM: wave owns 64x32
#pragma unroll
        for (int ks = 0; ks < 2; ks++) {
            bf16x8 ah[4], al_[4];
#pragma unroll
            for (int mt = 0; mt < 4; mt++) {
                ah[mt]  = *reinterpret_cast<const bf16x8*>(&Abh[wr + mt * 16 + l15][ks * 32 + lh * 8]);
                al_[mt] = *reinterpret_cast<const bf16x8*>(&Abl[wr + mt * 16 + l15][ks * 32 + lh * 8]);
            }
#pragma unroll
            for (int nt = 0; nt < 2; nt++) {
                bf16x8 bh = *reinterpret_cast<const bf16x8*>(&Bbh[wc + nt * 16 + l15][ks * 32 + lh * 8]);
                bf16x8 bl = *reinterpret_cast<const bf16x8*>(&Bbl[wc + nt * 16 + l15][ks * 32 + lh * 8]);
#pragma unroll
                for (int mt = 0; mt < 4; mt++) {
                    acc[mt][nt] = MFMA(ah[mt], bh, acc[mt][nt]);
                    acc[mt][nt] = MFMA(ah[mt], bl, acc[mt][nt]);
                    acc[mt][nt] = MFMA(al_[mt], bh, acc[mt][nt]);
                }
            }
        }
    }
#pragma unroll
    for (int nt = 0; nt < 2; nt++) {
        int col = n0 + wc + nt * 16 + l15;
        float bs = b2[col];
#pragma unroll
        for (int mt = 0; mt < 4; mt++)
#pragma unroll
            for (int r = 0; r < 4; r++)
                outp[(size_t)(m0 + wr + mt * 16 + lh * 4 + r) * DD + col] = acc[mt][nt][r] + bs;
    }
}

// ---------------------------------------------------------------------------
// Kernel 6: pooled[b,d] = mean_s h[b,s,d]
// ---------------------------------------------------------------------------
__global__ __launch_bounds__(256) void pool_mean(const uint* __restrict__ Hp,
                                                 float* __restrict__ pooled) {
    int idx = blockIdx.x * 256 + threadIdx.x;
    if (idx >= BB * DD) return;
    int b = idx >> 9, d = idx & 511;
    float s = 0.f;
    for (int j = 0; j < SS; j++) s += unpackf(Hp[((size_t)b * SS + j) * DD + d]);
    pooled[idx] = s * (1.f / SS);
}

// ---------------------------------------------------------------------------
// Kernel 7: out[b,c] = pooled[b,:] . clf_w[:,c] + clf_b[c]
// ---------------------------------------------------------------------------
__global__ __launch_bounds__(64) void classifier(const float* __restrict__ pooled,
                                                 const float* __restrict__ W,
                                                 const float* __restrict__ bias,
                                                 float* __restrict__ out) {
    int o = blockIdx.x;
    int b = o / CC, c = o % CC;
    int lane = threadIdx.x;
    float s = 0.f;
    for (int d = lane; d < DD; d += 64) s += pooled[b * DD + d] * W[d * CC + c];
#pragma unroll
    for (int off = 32; off > 0; off >>= 1) s += __shfl_xor(s, off);
    if (lane == 0) out[o] = s + bias[c];
}

// ---------------------------------------------------------------------------
extern "C" void kernel_launch(void* const* d_in, const int* in_sizes, int n_in,
                              void* d_out, int out_size, void* d_ws, size_t ws_size,
                              hipStream_t stream) {
    (void)in_sizes; (void)n_in; (void)out_size; (void)ws_size;
    const int*   x      = (const int*)d_in[0];
    const float* emb    = (const float*)d_in[1];
    const float* ln1_g  = (const float*)d_in[2];
    const float* ln1_b  = (const float*)d_in[3];
    const float* ln2_g  = (const float*)d_in[4];
    const float* ln2_b  = (const float*)d_in[5];
    const float* attn_w = (const float*)d_in[6];
    const float* attn_b = (const float*)d_in[7];
    const float* theta  = (const float*)d_in[8];
    const float* ffn_w1 = (const float*)d_in[9];
    const float* ffn_b1 = (const float*)d_in[10];
    const float* ffn_w2 = (const float*)d_in[11];
    const float* ffn_b2 = (const float*)d_in[12];
    const float* clf_w  = (const float*)d_in[13];
    const float* clf_b  = (const float*)d_in[14];
    float* out = (float*)d_out;

    char* ws = (char*)d_ws;
    uint*     Hp     = (uint*)(ws);                     // 32 MB packed hi|lo
    float*    t2     = (float*)(ws + 33554432);         // 32 MB fp32
    ushort_t* t1h    = (ushort_t*)(ws + 67108864);      // 16 MB bf16 hi
    ushort_t* t1l    = (ushort_t*)(ws + 83886080);      // 16 MB bf16 lo
    float*    pooled = (float*)(ws + 100663296);        // 64 KB
    ushort_t* Wath   = (ushort_t*)(ws + 100728832);     // 512 KB attn_w hi
    ushort_t* Watl   = (ushort_t*)(ws + 101253120);     // 512 KB attn_w lo
    ushort_t* W1th6  = (ushort_t*)(ws + 101777408);     // 192 KB W1t hi
    ushort_t* W1tl6  = (ushort_t*)(ws + 101974016);     // 192 KB W1t lo
    ushort_t* W2th   = (ushort_t*)(ws + 67108864);      // reuses t1h region
    ushort_t* W2tl   = (ushort_t*)(ws + 67108864 + 2097152);

    embed_pe<<<(BB * SS * DD + 255) / 256, 256, 0, stream>>>(x, emb, Hp);
    prep_w1t<<<dim3(FF / 256, LL), 256, 0, stream>>>(ffn_w1, W1th6, W1tl6);

    for (int l = 0; l < LL; l++) {
        flash_attn_split<<<dim3(SS / 128, HH, BB), 512, 0, stream>>>(Hp, t1h, t1l);
        transpose_split_w<<<(DD / 64) * (DD / 64), 256, 0, stream>>>(
            attn_w + (size_t)l * DD * DD, Wath, Watl, DD, DD);
        gemm_split<<<(16384 / 128) * (DD / 128), 512, 0, stream>>>(
            t1h, t1l, Wath, Watl, attn_b + l * DD, t2, BB * SS, DD, DD);
        ln_residual<<<BB * SS / 4, 256, 0, stream>>>(Hp, t2, ln1_g + l * DD, ln1_b + l * DD);
        transpose_split_w<<<(FF / 64) * (DD / 64), 256, 0, stream>>>(
            ffn_w2 + (size_t)l * FF * DD, W2th, W2tl, FF, DD);
        ffn_split<<<(16384 / 128) * (DD / 128), 512, 0, stream>>>(
            Hp, W1th6 + (size_t)l * FF * 8, W1tl6 + (size_t)l * FF * 8, ffn_b1 + l * FF,
            W2th, W2tl, ffn_b2 + l * DD, theta + l * NQ, t2);
        ln_residual<<<BB * SS / 4, 256, 0, stream>>>(Hp, t2, ln2_g + l * DD, ln2_b + l * DD);
    }

    pool_mean<<<(BB * DD + 255) / 256, 256, 0, stream>>>(Hp, pooled);
    classifier<<<BB * CC, 64, 0, stream>>>(pooled, clf_w, clf_b, out);
}

// Round 13
// 1994.072 us; speedup vs baseline: 1.3413x; 1.3413x over previous
//
#include <hip/hip_runtime.h>
#include <hip/hip_bf16.h>
#include <math.h>

#define BB 32
#define SS 512
#define DD 512
#define HH 8
#define DK 64
#define LL 6
#define NQ 8
#define FF 2048
#define CC 10

typedef unsigned int uint;
typedef unsigned short ushort_t;
using bf16x8 = __attribute__((ext_vector_type(8))) short;
using f32x4  = __attribute__((ext_vector_type(4))) float;

#define MFMA(a, b, c) __builtin_amdgcn_mfma_f32_16x16x32_bf16((a), (b), (c), 0, 0, 0)

union U8 { ushort_t u[8]; bf16x8 v; };

__device__ __forceinline__ void gload16(const void* g, void* l) {
    __builtin_amdgcn_global_load_lds((__attribute__((address_space(1))) void*)g,
                                     (__attribute__((address_space(3))) void*)l,
                                     16, 0, 0);
}

__device__ inline ushort_t f2bf(float x) {           // fp32 -> bf16, RNE
    uint u = __float_as_uint(x);
    u += 0x7FFFu + ((u >> 16) & 1u);
    return (ushort_t)(u >> 16);
}
// truncation split: hi = top 16 bits, lo = RNE(residual)
__device__ inline void tsplit(float v, ushort_t& hi, ushort_t& lo) {
    uint u = __float_as_uint(v);
    hi = (ushort_t)(u >> 16);
    lo = f2bf(v - __uint_as_float(u & 0xFFFF0000u));
}
// cheap variant (lo also truncated): used on A2 only
__device__ inline void tsplit_fast(float v, ushort_t& hi, ushort_t& lo) {
    uint u = __float_as_uint(v);
    hi = (ushort_t)(u >> 16);
    float res = v - __uint_as_float(u & 0xFFFF0000u);
    lo = (ushort_t)(__float_as_uint(res) >> 16);
}
__device__ inline uint packsplit(float v) {
    uint u = __float_as_uint(v) & 0xFFFF0000u;
    uint ru = __float_as_uint(v - __uint_as_float(u));
    ru += 0x7FFFu + ((ru >> 16) & 1u);
    return u | (ru >> 16);
}
__device__ inline float unpackf(uint u) {
    return __uint_as_float(u & 0xFFFF0000u) + __uint_as_float(u << 16);
}

// ---------------------------------------------------------------------------
// Kernel 1: h = emb[x] + pe, stored packed hi|lo bf16
// ---------------------------------------------------------------------------
__global__ __launch_bounds__(256) void embed_pe(const int* __restrict__ x,
                                                const float* __restrict__ emb,
                                                uint* __restrict__ Hp) {
    int idx = blockIdx.x * 256 + threadIdx.x;
    if (idx >= BB * SS * DD) return;
    int d = idx & (DD - 1);
    int s = (idx >> 9) & (SS - 1);
    int tok = x[idx >> 9];
    int i2 = d >> 1;
    float freq = expf((float)(2 * i2) * (-9.210340371976184f / (float)DD));
    float ang = (float)s * freq;
    float pe = (d & 1) ? cosf(ang) : sinf(ang);
    Hp[idx] = packsplit(emb[(size_t)tok * DD + d] + pe);
}

// ---------------------------------------------------------------------------
// Kernel 1b: transpose + split fp32 [K][N] -> bf16 hi/lo [N][K]
// ---------------------------------------------------------------------------
__global__ __launch_bounds__(256) void transpose_split_w(const float* __restrict__ in,
                                                         ushort_t* __restrict__ outh,
                                                         ushort_t* __restrict__ outl,
                                                         int K, int N) {
    __shared__ ushort_t th[64][68], tl[64][68];
    int nb = N >> 6;
    int k0 = ((int)blockIdx.x / nb) << 6;
    int n0 = ((int)blockIdx.x % nb) << 6;
    int t = threadIdx.x;
    int r = t >> 2, cb = (t & 3) << 4;
#pragma unroll
    for (int c = 0; c < 4; c++) {
        float4 v = *reinterpret_cast<const float4*>(&in[(size_t)(k0 + r) * N + n0 + cb + 4 * c]);
        float vv[4] = {v.x, v.y, v.z, v.w};
#pragma unroll
        for (int e = 0; e < 4; e++) {
            ushort_t hb, lb; tsplit(vv[e], hb, lb);
            th[r][cb + 4 * c + e] = hb;
            tl[r][cb + 4 * c + e] = lb;
        }
    }
    __syncthreads();
    int n = t >> 2, kb = (t & 3) << 4;
#pragma unroll
    for (int c = 0; c < 4; c++) {
        ushort4 oh, ol;
        oh.x = th[kb + 4 * c + 0][n]; ol.x = tl[kb + 4 * c + 0][n];
        oh.y = th[kb + 4 * c + 1][n]; ol.y = tl[kb + 4 * c + 1][n];
        oh.z = th[kb + 4 * c + 2][n]; ol.z = tl[kb + 4 * c + 2][n];
        oh.w = th[kb + 4 * c + 3][n]; ol.w = tl[kb + 4 * c + 3][n];
        *reinterpret_cast<ushort4*>(&outh[(size_t)(n0 + n) * K + k0 + kb + 4 * c]) = oh;
        *reinterpret_cast<ushort4*>(&outl[(size_t)(n0 + n) * K + k0 + kb + 4 * c]) = ol;
    }
}

// ---------------------------------------------------------------------------
// Kernel 1c: W1 [L][8][FF] -> transposed split planes [L][FF][8] bf16 hi/lo
// ---------------------------------------------------------------------------
__global__ __launch_bounds__(256) void prep_w1t(const float* __restrict__ W1all,
                                                ushort_t* __restrict__ outh,
                                                ushort_t* __restrict__ outl) {
    int l = blockIdx.y;
    int f = blockIdx.x * 256 + threadIdx.x;
    const float* W1 = W1all + (size_t)l * NQ * FF;
    U8 ph, pl;
#pragma unroll
    for (int n = 0; n < 8; n++) {
        ushort_t hb, lb; tsplit(W1[n * FF + f], hb, lb);
        ph.u[n] = hb; pl.u[n] = lb;
    }
    *reinterpret_cast<bf16x8*>(&outh[((size_t)l * FF + f) * 8]) = ph.v;
    *reinterpret_cast<bf16x8*>(&outl[((size_t)l * FF + f) * 8]) = pl.v;
}

// ---------------------------------------------------------------------------
// Kernel 2: split-precision MFMA flash attention, QBLK=128, 8 waves.
// (unchanged from round 8)
// ---------------------------------------------------------------------------
__global__ __launch_bounds__(512, 4) void flash_attn_split(const uint* __restrict__ Hp,
                                                           ushort_t* __restrict__ outh,
                                                           ushort_t* __restrict__ outl) {
    __shared__ __align__(16) ushort_t Kh[64][72], Kl[64][72];
    __shared__ __align__(16) ushort_t Vh[64][72], Vl[64][72];   // [d][j]
    __shared__ __align__(16) ushort_t Ph[128][72], Pl[128][72];

    int i0 = blockIdx.x * 128;
    int h0 = blockIdx.y * DK;
    int b  = blockIdx.z;
    const uint* baseH = Hp + (size_t)b * (SS * DD);

    int t = threadIdx.x;
    int w = t >> 6;
    int ln = t & 63;
    int l15 = ln & 15, lh = ln >> 4;

    bf16x8 aqh0, aqh1, aql0, aql1;
    {
        int row = i0 + w * 16 + l15;
        const uint* src = &baseH[(size_t)row * DD + h0 + lh * 8];
        uint4 p0 = *reinterpret_cast<const uint4*>(src);
        uint4 p1 = *reinterpret_cast<const uint4*>(src + 4);
        uint4 p2 = *reinterpret_cast<const uint4*>(src + 32);
        uint4 p3 = *reinterpret_cast<const uint4*>(src + 36);
        uint a0[8] = {p0.x, p0.y, p0.z, p0.w, p1.x, p1.y, p1.z, p1.w};
        uint a1[8] = {p2.x, p2.y, p2.z, p2.w, p3.x, p3.y, p3.z, p3.w};
        U8 h0u, l0u, h1u, l1u;
#pragma unroll
        for (int e = 0; e < 8; e++) {
            h0u.u[e] = (ushort_t)(a0[e] >> 16);
            l0u.u[e] = (ushort_t)(a0[e] & 0xFFFFu);
            h1u.u[e] = (ushort_t)(a1[e] >> 16);
            l1u.u[e] = (ushort_t)(a1[e] & 0xFFFFu);
        }
        aqh0 = h0u.v; aql0 = l0u.v; aqh1 = h1u.v; aql1 = l1u.v;
    }

    float m_[4], l_[4], al[4];
    f32x4 acc[4];
    f32x4 z4 = {0.f, 0.f, 0.f, 0.f};
#pragma unroll
    for (int r = 0; r < 4; r++) { m_[r] = -1e30f; l_[r] = 0.f; acc[r] = z4; }

    int kr = t >> 3, kcb = (t & 7) * 8;
    int vc = t & 7, vr = t >> 3;

    for (int j0 = 0; j0 < SS; j0 += 64) {
        __syncthreads();
        {
            const uint* src = &baseH[(size_t)(j0 + kr) * DD + h0 + kcb];
            uint4 p0 = *reinterpret_cast<const uint4*>(src);
            uint4 p1 = *reinterpret_cast<const uint4*>(src + 4);
            uint a[8] = {p0.x, p0.y, p0.z, p0.w, p1.x, p1.y, p1.z, p1.w};
            U8 kh, kl;
#pragma unroll
            for (int e = 0; e < 8; e++) {
                kh.u[e] = (ushort_t)(a[e] >> 16);
                kl.u[e] = (ushort_t)(a[e] & 0xFFFFu);
            }
            *reinterpret_cast<bf16x8*>(&Kh[kr][kcb]) = kh.v;
            *reinterpret_cast<bf16x8*>(&Kl[kr][kcb]) = kl.v;
        }
        __syncthreads();
#pragma unroll
        for (int e = 0; e < 8; e++) {
            int d = vc + 8 * e;
            Vh[d][vr] = Kh[vr][d];
            Vl[d][vr] = Kl[vr][d];
        }
        f32x4 sc[4];
#pragma unroll
        for (int tt = 0; tt < 4; tt++) {
            bf16x8 bh0 = *reinterpret_cast<const bf16x8*>(&Kh[tt * 16 + l15][lh * 8]);
            bf16x8 bh1 = *reinterpret_cast<const bf16x8*>(&Kh[tt * 16 + l15][32 + lh * 8]);
            bf16x8 bl0 = *reinterpret_cast<const bf16x8*>(&Kl[tt * 16 + l15][lh * 8]);
            bf16x8 bl1 = *reinterpret_cast<const bf16x8*>(&Kl[tt * 16 + l15][32 + lh * 8]);
            f32x4 s = z4;
            s = MFMA(aqh0, bh0, s);
            s = MFMA(aqh1, bh1, s);
            s = MFMA(aqh0, bl0, s);
            s = MFMA(aqh1, bl1, s);
            s = MFMA(aql0, bh0, s);
            s = MFMA(aql1, bh1, s);
            sc[tt] = s * 0.125f;
        }
#pragma unroll
        for (int r = 0; r < 4; r++) {
            float mx = fmaxf(fmaxf(sc[0][r], sc[1][r]), fmaxf(sc[2][r], sc[3][r]));
            mx = fmaxf(mx, __shfl_xor(mx, 1));
            mx = fmaxf(mx, __shfl_xor(mx, 2));
            mx = fmaxf(mx, __shfl_xor(mx, 4));
            mx = fmaxf(mx, __shfl_xor(mx, 8));
            float nm = fmaxf(m_[r], mx);
            al[r] = __expf(m_[r] - nm);
            m_[r] = nm;
            float rs = 0.f;
#pragma unroll
            for (int tt = 0; tt < 4; tt++) {
                float p = __expf(sc[tt][r] - nm);
                sc[tt][r] = p;
                rs += p;
            }
            rs += __shfl_xor(rs, 1);
            rs += __shfl_xor(rs, 2);
            rs += __shfl_xor(rs, 4);
            rs += __shfl_xor(rs, 8);
            l_[r] = l_[r] * al[r] + rs;
        }
#pragma unroll
        for (int tt = 0; tt < 4; tt++)
#pragma unroll
            for (int r = 0; r < 4; r++) {
                ushort_t hb, lb; tsplit(sc[tt][r], hb, lb);
                Ph[w * 16 + lh * 4 + r][tt * 16 + l15] = hb;
                Pl[w * 16 + lh * 4 + r][tt * 16 + l15] = lb;
            }
        __syncthreads();
#pragma unroll
        for (int td = 0; td < 4; td++) {
            acc[td][0] *= al[0];
            acc[td][1] *= al[1];
            acc[td][2] *= al[2];
            acc[td][3] *= al[3];
        }
        bf16x8 aph0 = *reinterpret_cast<const bf16x8*>(&Ph[w * 16 + l15][lh * 8]);
        bf16x8 aph1 = *reinterpret_cast<const bf16x8*>(&Ph[w * 16 + l15][32 + lh * 8]);
        bf16x8 apl0 = *reinterpret_cast<const bf16x8*>(&Pl[w * 16 + l15][lh * 8]);
        bf16x8 apl1 = *reinterpret_cast<const bf16x8*>(&Pl[w * 16 + l15][32 + lh * 8]);
#pragma unroll
        for (int td = 0; td < 4; td++) {
            bf16x8 bvh0 = *reinterpret_cast<const bf16x8*>(&Vh[td * 16 + l15][lh * 8]);
            bf16x8 bvh1 = *reinterpret_cast<const bf16x8*>(&Vh[td * 16 + l15][32 + lh * 8]);
            bf16x8 bvl0 = *reinterpret_cast<const bf16x8*>(&Vl[td * 16 + l15][lh * 8]);
            bf16x8 bvl1 = *reinterpret_cast<const bf16x8*>(&Vl[td * 16 + l15][32 + lh * 8]);
            acc[td] = MFMA(aph0, bvh0, acc[td]);
            acc[td] = MFMA(aph1, bvh1, acc[td]);
            acc[td] = MFMA(aph0, bvl0, acc[td]);
            acc[td] = MFMA(aph1, bvl1, acc[td]);
            acc[td] = MFMA(apl0, bvh0, acc[td]);
            acc[td] = MFMA(apl1, bvh1, acc[td]);
        }
    }

#pragma unroll
    for (int r = 0; r < 4; r++) {
        float inv = 1.f / l_[r];
        int row = i0 + w * 16 + lh * 4 + r;
#pragma unroll
        for (int td = 0; td < 4; td++) {
            float o = acc[td][r] * inv;
            ushort_t hb, lb; tsplit(o, hb, lb);
            size_t idx = (size_t)b * SS * DD + (size_t)row * DD + h0 + td * 16 + l15;
            outh[idx] = hb;
            outl[idx] = lb;
        }
    }
}

// swizzled fragment read from an unpadded [128][64] plane:
// logical 16B chunk (ks*4+lh) of row -> physical chunk XOR (row&7)
#define SWZREAD(plane, row, ks) \
    (*reinterpret_cast<const bf16x8*>(&(plane)[row][((((ks) * 4 + lh) ^ ((row) & 7)) * 8)]))

// ---------------------------------------------------------------------------
// Kernel 3: C fp32 = A(hi/lo [M][K]) @ Bt(pre-split hi/lo [N][K]) + bias.
// 128x128 tile, BK=64, 512 thr / 8 waves. Double-buffered LDS filled by
// global_load_lds DMA (linear dest, inverse-swizzled source, swizzled read).
// One barrier per k-tile; next tile's DMA overlaps current MFMA.
// ---------------------------------------------------------------------------
__global__ __launch_bounds__(512, 2) void gemm_split(const ushort_t* __restrict__ Ah,
                                                     const ushort_t* __restrict__ Al,
                                                     const ushort_t* __restrict__ Bth,
                                                     const ushort_t* __restrict__ Btl,
                                                     const float* __restrict__ bias,
                                                     float* __restrict__ C,
                                                     int M, int N, int K) {
    __shared__ __align__(16) ushort_t sAh[2][128][64], sAl[2][128][64];
    __shared__ __align__(16) ushort_t sBh[2][128][64], sBl[2][128][64];
    int nb = N >> 7;
    int m0 = ((int)blockIdx.x / nb) << 7;
    int n0 = ((int)blockIdx.x % nb) << 7;
    int t = threadIdx.x;
    int w = t >> 6, ln = t & 63, l15 = ln & 15, lh = ln >> 4;
    int wr = (w >> 2) * 64, wc = (w & 3) * 32;

    f32x4 z4 = {0.f, 0.f, 0.f, 0.f};
    f32x4 acc[4][2];
#pragma unroll
    for (int i = 0; i < 4; i++)
#pragma unroll
        for (int j = 0; j < 2; j++) acc[i][j] = z4;

    int srow = ln >> 3;                 // 0..7 row within wave chunk
    int schunk = (ln & 7) ^ srow;       // inverse-swizzled source 16B chunk

    auto stage = [&](int buf, int kk) {
#pragma unroll
        for (int p = 0; p < 2; p++) {
            int rbase = (w + p * 8) * 8;
            int grow = rbase + srow;
            int gc = kk + schunk * 8;
            gload16(&Ah[(size_t)(m0 + grow) * K + gc],  &sAh[buf][rbase][0]);
            gload16(&Al[(size_t)(m0 + grow) * K + gc],  &sAl[buf][rbase][0]);
            gload16(&Bth[(size_t)(n0 + grow) * K + gc], &sBh[buf][rbase][0]);
            gload16(&Btl[(size_t)(n0 + grow) * K + gc], &sBl[buf][rbase][0]);
        }
    };

    stage(0, 0);
    __syncthreads();
    int cur = 0;
    int ntile = K >> 6;

    for (int kt = 0; kt < ntile; kt++) {
        if (kt + 1 < ntile) stage(cur ^ 1, (kt + 1) * 64);
#pragma unroll
        for (int ks = 0; ks < 2; ks++) {
            bf16x8 ah[4], al_[4];
#pragma unroll
            for (int mt = 0; mt < 4; mt++) {
                int row = wr + mt * 16 + l15;
                ah[mt]  = SWZREAD(sAh[cur], row, ks);
                al_[mt] = SWZREAD(sAl[cur], row, ks);
            }
#pragma unroll
            for (int nt = 0; nt < 2; nt++) {
                int row = wc + nt * 16 + l15;
                bf16x8 bh = SWZREAD(sBh[cur], row, ks);
                bf16x8 bl = SWZREAD(sBl[cur], row, ks);
#pragma unroll
                for (int mt = 0; mt < 4; mt++) {
                    acc[mt][nt] = MFMA(ah[mt], bh, acc[mt][nt]);
                    acc[mt][nt] = MFMA(ah[mt], bl, acc[mt][nt]);
                    acc[mt][nt] = MFMA(al_[mt], bh, acc[mt][nt]);
                }
            }
        }
        __syncthreads();   // drains DMA for tile kt+1; frees buf[cur]
        cur ^= 1;
    }
#pragma unroll
    for (int nt = 0; nt < 2; nt++) {
        int col = n0 + wc + nt * 16 + l15;
        float bs = bias[col];
#pragma unroll
        for (int mt = 0; mt < 4; mt++)
#pragma unroll
            for (int r = 0; r < 4; r++)
                C[(size_t)(m0 + wr + mt * 16 + lh * 4 + r) * N + col] = acc[mt][nt][r] + bs;
    }
}

// ---------------------------------------------------------------------------
// Kernel 4: Hp = pack(layernorm(unpack(Hp) + add) * g + b)
// ---------------------------------------------------------------------------
__global__ __launch_bounds__(256) void ln_residual(uint* __restrict__ Hp,
                                                   const float* __restrict__ add,
                                                   const float* __restrict__ g,
                                                   const float* __restrict__ bta) {
    int row = blockIdx.x * 4 + (threadIdx.x >> 6);
    int lane = threadIdx.x & 63;
    uint* hp = Hp + (size_t)row * DD;
    const float* ap = add + (size_t)row * DD;
    float v[8];
    float sum = 0.f;
#pragma unroll
    for (int i = 0; i < 8; i++) {
        int d = lane + i * 64;
        v[i] = unpackf(hp[d]) + ap[d];
        sum += v[i];
    }
#pragma unroll
    for (int off = 32; off > 0; off >>= 1) sum += __shfl_xor(sum, off);
    float mu = sum * (1.f / DD);
    float s2 = 0.f;
#pragma unroll
    for (int i = 0; i < 8; i++) {
        float d2 = v[i] - mu;
        s2 += d2 * d2;
    }
#pragma unroll
    for (int off = 32; off > 0; off >>= 1) s2 += __shfl_xor(s2, off);
    float inv = rsqrtf(s2 * (1.f / DD) + 1e-5f);
#pragma unroll
    for (int i = 0; i < 8; i++) {
        int d = lane + i * 64;
        hp[d] = packsplit((v[i] - mu) * inv * g[d] + bta[d]);
    }
}

// ---------------------------------------------------------------------------
// Kernel 5: fused FFN, 128x128 tile, BK=64, 512 thr / 8 waves.
// A2 = relu(qout@W1+b1) on the matrix pipe (padded A-LDS, unchanged path);
// B double-buffered via global_load_lds DMA, loads overlap main GEMM.
// W1 fragments prefetched in registers one tile ahead.
// ---------------------------------------------------------------------------
__global__ __launch_bounds__(512, 2) void ffn_split(const uint* __restrict__ Hp,
                                                    const ushort_t* __restrict__ W1th,
                                                    const ushort_t* __restrict__ W1tl,
                                                    const float* __restrict__ b1,
                                                    const ushort_t* __restrict__ W2th,
                                                    const ushort_t* __restrict__ W2tl,
                                                    const float* __restrict__ b2,
                                                    const float* __restrict__ theta,
                                                    float* __restrict__ outp) {
    __shared__ __align__(16) ushort_t Abh[128][72], Abl[128][72];
    __shared__ __align__(16) ushort_t sBh[2][128][64], sBl[2][128][64];
    __shared__ __align__(16) ushort_t qsh[129][8], qsl[129][8];
    __shared__ float tcs[8];

    int t = threadIdx.x;
    int m0 = (int)(blockIdx.x >> 2) * 128;
    int n0 = (int)(blockIdx.x & 3) * 128;
    if (t < 8) {
        tcs[t] = cosf(theta[t]);
        qsh[128][t] = 0;
        qsl[128][t] = 0;
    }
    __syncthreads();
#pragma unroll
    for (int i = 0; i < 2; i++) {
        int idx = t + i * 512;
        int m = idx >> 3, n = idx & 7;
        float q = cosf(unpackf(Hp[(size_t)(m0 + m) * DD + n])) * tcs[n];
        ushort_t hb, lb; tsplit(q, hb, lb);
        qsh[m][n] = hb;
        qsl[m][n] = lb;
    }

    int w = t >> 6, ln = t & 63, l15 = ln & 15, lh = ln >> 4;
    int wr = (w >> 2) * 64, wc = (w & 3) * 32;
    bool lh0 = (lh == 0);
    f32x4 z4 = {0.f, 0.f, 0.f, 0.f};
    bf16x8 z8 = {0, 0, 0, 0, 0, 0, 0, 0};
    f32x4 acc[4][2];
#pragma unroll
    for (int i = 0; i < 4; i++)
#pragma unroll
        for (int j = 0; j < 2; j++) acc[i][j] = z4;

    int srow = ln >> 3;
    int schunk = (ln & 7) ^ srow;

    auto stageB = [&](int buf, int kk) {
#pragma unroll
        for (int p = 0; p < 2; p++) {
            int rbase = (w + p * 8) * 8;
            int grow = rbase + srow;
            int gc = kk + schunk * 8;
            gload16(&W2th[(size_t)(n0 + grow) * FF + gc], &sBh[buf][rbase][0]);
            gload16(&W2tl[(size_t)(n0 + grow) * FF + gc], &sBl[buf][rbase][0]);
        }
    };

    // prologue: B tile 0 DMA + W1 frag prefetch tile 0
    bf16x8 rwh[4], rwl[4];
    stageB(0, 0);
#pragma unroll
    for (int fq = 0; fq < 4; fq++) {
        rwh[fq] = *reinterpret_cast<const bf16x8*>(&W1th[(size_t)(fq * 16 + l15) * 8]);
        rwl[fq] = *reinterpret_cast<const bf16x8*>(&W1tl[(size_t)(fq * 16 + l15) * 8]);
    }
    __syncthreads();   // qs visible + B0 drained
    int cur = 0;

    for (int k0 = 0; k0 < FF; k0 += 64) {
        // ---- A2 via MFMA using prefetched W1 frags (wave w -> rows w*16..+15)
        {
            bf16x8 wh[4], wl[4];
#pragma unroll
            for (int fq = 0; fq < 4; fq++) {
                wh[fq] = lh0 ? rwh[fq] : z8;
                wl[fq] = lh0 ? rwl[fq] : z8;
            }
            int m = w * 16 + l15;
            int mrow = lh0 ? m : 128;
            bf16x8 qh  = *reinterpret_cast<const bf16x8*>(&qsh[mrow][0]);
            bf16x8 ql_ = *reinterpret_cast<const bf16x8*>(&qsl[mrow][0]);
#pragma unroll
            for (int fq = 0; fq < 4; fq++) {
                f32x4 d = z4;
                d = MFMA(wh[fq], qh, d);
                d = MFMA(wh[fq], ql_, d);
                d = MFMA(wl[fq], qh, d);
                float4 b1v = *reinterpret_cast<const float4*>(&b1[k0 + fq * 16 + lh * 4]);
                float v0 = fmaxf(d[0] + b1v.x, 0.f);
                float v1 = fmaxf(d[1] + b1v.y, 0.f);
                float v2 = fmaxf(d[2] + b1v.z, 0.f);
                float v3 = fmaxf(d[3] + b1v.w, 0.f);
                ushort_t h0_, l0_, h1_, l1_, h2_, l2_, h3_, l3_;
                tsplit_fast(v0, h0_, l0_);
                tsplit_fast(v1, h1_, l1_);
                tsplit_fast(v2, h2_, l2_);
                tsplit_fast(v3, h3_, l3_);
                uint2 hu, lu;
                hu.x = (uint)h0_ | ((uint)h1_ << 16);
                hu.y = (uint)h2_ | ((uint)h3_ << 16);
                lu.x = (uint)l0_ | ((uint)l1_ << 16);
                lu.y = (uint)l2_ | ((uint)l3_ << 16);
                *reinterpret_cast<uint2*>(&Abh[m][fq * 16 + lh * 4]) = hu;
                *reinterpret_cast<uint2*>(&Abl[m][fq * 16 + lh * 4]) = lu;
            }
        }
        __syncthreads();   // A2 visible; no outstanding DMA here
        // ---- issue next B tile DMA + W1 prefetch (overlap with main GEMM)
        if (k0 + 64 < FF) {
            int k1 = k0 + 64;
            stageB(cur ^ 1, k1);
#pragma unroll
            for (int fq = 0; fq < 4; fq++) {
                rwh[fq] = *reinterpret_cast<const bf16x8*>(&W1th[(size_t)(k1 + fq * 16 + l15) * 8]);
                rwl[fq] = *reinterpret_cast<const bf16x8*>(&W1tl[(size_t)(k1 + fq * 16 + l15) * 8]);
            }
        }
        // ---- main GEMM: wave owns 64x32
#pragma unroll
        for (int ks = 0; ks < 2; ks++) {
            bf16x8 ah[4], al_[4];
#pragma unroll
            for (int mt = 0; mt < 4; mt++) {
                ah[mt]  = *reinterpret_cast<const bf16x8*>(&Abh[wr + mt * 16 + l15][ks * 32 + lh * 8]);
                al_[mt] = *reinterpret_cast<const bf16x8*>(&Abl[wr + mt * 16 + l15][ks * 32 + lh * 8]);
            }
#pragma unroll
            for (int nt = 0; nt < 2; nt++) {
                int row = wc + nt * 16 + l15;
                bf16x8 bh = SWZREAD(sBh[cur], row, ks);
                bf16x8 bl = SWZREAD(sBl[cur], row, ks);
#pragma unroll
                for (int mt = 0; mt < 4; mt++) {
                    acc[mt][nt] = MFMA(ah[mt], bh, acc[mt][nt]);
                    acc[mt][nt] = MFMA(ah[mt], bl, acc[mt][nt]);
                    acc[mt][nt] = MFMA(al_[mt], bh, acc[mt][nt]);
                }
            }
        }
        __syncthreads();   // drains next-tile DMA; frees A-LDS + buf[cur]
        cur ^= 1;
    }
#pragma unroll
    for (int nt = 0; nt < 2; nt++) {
        int col = n0 + wc + nt * 16 + l15;
        float bs = b2[col];
#pragma unroll
        for (int mt = 0; mt < 4; mt++)
#pragma unroll
            for (int r = 0; r < 4; r++)
                outp[(size_t)(m0 + wr + mt * 16 + lh * 4 + r) * DD + col] = acc[mt][nt][r] + bs;
    }
}

// ---------------------------------------------------------------------------
// Kernel 6: pooled[b,d] = mean_s h[b,s,d]
// ---------------------------------------------------------------------------
__global__ __launch_bounds__(256) void pool_mean(const uint* __restrict__ Hp,
                                                 float* __restrict__ pooled) {
    int idx = blockIdx.x * 256 + threadIdx.x;
    if (idx >= BB * DD) return;
    int b = idx >> 9, d = idx & 511;
    float s = 0.f;
    for (int j = 0; j < SS; j++) s += unpackf(Hp[((size_t)b * SS + j) * DD + d]);
    pooled[idx] = s * (1.f / SS);
}

// ---------------------------------------------------------------------------
// Kernel 7: out[b,c] = pooled[b,:] . clf_w[:,c] + clf_b[c]
// ---------------------------------------------------------------------------
__global__ __launch_bounds__(64) void classifier(const float* __restrict__ pooled,
                                                 const float* __restrict__ W,
                                                 const float* __restrict__ bias,
                                                 float* __restrict__ out) {
    int o = blockIdx.x;
    int b = o / CC, c = o % CC;
    int lane = threadIdx.x;
    float s = 0.f;
    for (int d = lane; d < DD; d += 64) s += pooled[b * DD + d] * W[d * CC + c];
#pragma unroll
    for (int off = 32; off > 0; off >>= 1) s += __shfl_xor(s, off);
    if (lane == 0) out[o] = s + bias[c];
}

// ---------------------------------------------------------------------------
extern "C" void kernel_launch(void* const* d_in, const int* in_sizes, int n_in,
                              void* d_out, int out_size, void* d_ws, size_t ws_size,
                              hipStream_t stream) {
    (void)in_sizes; (void)n_in; (void)out_size; (void)ws_size;
    const int*   x      = (const int*)d_in[0];
    const float* emb    = (const float*)d_in[1];
    const float* ln1_g  = (const float*)d_in[2];
    const float* ln1_b  = (const float*)d_in[3];
    const float* ln2_g  = (const float*)d_in[4];
    const float* ln2_b  = (const float*)d_in[5];
    const float* attn_w = (const float*)d_in[6];
    const float* attn_b = (const float*)d_in[7];
    const float* theta  = (const float*)d_in[8];
    const float* ffn_w1 = (const float*)d_in[9];
    const float* ffn_b1 = (const float*)d_in[10];
    const float* ffn_w2 = (const float*)d_in[11];
    const float* ffn_b2 = (const float*)d_in[12];
    const float* clf_w  = (const float*)d_in[13];
    const float* clf_b  = (const float*)d_in[14];
    float* out = (float*)d_out;

    char* ws = (char*)d_ws;
    uint*     Hp     = (uint*)(ws);                     // 32 MB packed hi|lo
    float*    t2     = (float*)(ws + 33554432);         // 32 MB fp32
    ushort_t* t1h    = (ushort_t*)(ws + 67108864);      // 16 MB bf16 hi
    ushort_t* t1l    = (ushort_t*)(ws + 83886080);      // 16 MB bf16 lo
    float*    pooled = (float*)(ws + 100663296);        // 64 KB
    ushort_t* Wath   = (ushort_t*)(ws + 100728832);     // 512 KB attn_w hi
    ushort_t* Watl   = (ushort_t*)(ws + 101253120);     // 512 KB attn_w lo
    ushort_t* W1th6  = (ushort_t*)(ws + 101777408);     // 192 KB W1t hi
    ushort_t* W1tl6  = (ushort_t*)(ws + 101974016);     // 192 KB W1t lo
    ushort_t* W2th   = (ushort_t*)(ws + 67108864);      // reuses t1h region
    ushort_t* W2tl   = (ushort_t*)(ws + 67108864 + 2097152);

    embed_pe<<<(BB * SS * DD + 255) / 256, 256, 0, stream>>>(x, emb, Hp);
    prep_w1t<<<dim3(FF / 256, LL), 256, 0, stream>>>(ffn_w1, W1th6, W1tl6);

    for (int l = 0; l < LL; l++) {
        flash_attn_split<<<dim3(SS / 128, HH, BB), 512, 0, stream>>>(Hp, t1h, t1l);
        transpose_split_w<<<(DD / 64) * (DD / 64), 256, 0, stream>>>(
            attn_w + (size_t)l * DD * DD, Wath, Watl, DD, DD);
        gemm_split<<<(16384 / 128) * (DD / 128), 512, 0, stream>>>(
            t1h, t1l, Wath, Watl, attn_b + l * DD, t2, BB * SS, DD, DD);
        ln_residual<<<BB * SS / 4, 256, 0, stream>>>(Hp, t2, ln1_g + l * DD, ln1_b + l * DD);
        transpose_split_w<<<(FF / 64) * (DD / 64), 256, 0, stream>>>(
            ffn_w2 + (size_t)l * FF * DD, W2th, W2tl, FF, DD);
        ffn_split<<<(16384 / 128) * (DD / 128), 512, 0, stream>>>(
            Hp, W1th6 + (size_t)l * FF * 8, W1tl6 + (size_t)l * FF * 8, ffn_b1 + l * FF,
            W2th, W2tl, ffn_b2 + l * DD, theta + l * NQ, t2);
        ln_residual<<<BB * SS / 4, 256, 0, stream>>>(Hp, t2, ln2_g + l * DD, ln2_b + l * DD);
    }

    pool_mean<<<(BB * DD + 255) / 256, 256, 0, stream>>>(Hp, pooled);
    classifier<<<BB * CC, 64, 0, stream>>>(pooled, clf_w, clf_b, out);
}

// Round 14
// 1940.934 us; speedup vs baseline: 1.3781x; 1.0274x over previous
//
#include <hip/hip_runtime.h>
#include <hip/hip_bf16.h>
#include <math.h>

#define BB 32
#define SS 512
#define DD 512
#define HH 8
#define DK 64
#define LL 6
#define NQ 8
#define FF 2048
#define CC 10

typedef unsigned int uint;
typedef unsigned short ushort_t;
using bf16x8 = __attribute__((ext_vector_type(8))) short;
using f32x4  = __attribute__((ext_vector_type(4))) float;

#define MFMA(a, b, c) __builtin_amdgcn_mfma_f32_16x16x32_bf16((a), (b), (c), 0, 0, 0)

union U8 { ushort_t u[8]; bf16x8 v; };

__device__ __forceinline__ void gload16(const void* g, void* l) {
    __builtin_amdgcn_global_load_lds((__attribute__((address_space(1))) void*)g,
                                     (__attribute__((address_space(3))) void*)l,
                                     16, 0, 0);
}

__device__ inline ushort_t f2bf(float x) {           // fp32 -> bf16, RNE
    uint u = __float_as_uint(x);
    u += 0x7FFFu + ((u >> 16) & 1u);
    return (ushort_t)(u >> 16);
}
// truncation split: hi = top 16 bits, lo = RNE(residual)
__device__ inline void tsplit(float v, ushort_t& hi, ushort_t& lo) {
    uint u = __float_as_uint(v);
    hi = (ushort_t)(u >> 16);
    lo = f2bf(v - __uint_as_float(u & 0xFFFF0000u));
}
// cheap variant (lo also truncated): used on A2 only
__device__ inline void tsplit_fast(float v, ushort_t& hi, ushort_t& lo) {
    uint u = __float_as_uint(v);
    hi = (ushort_t)(u >> 16);
    float res = v - __uint_as_float(u & 0xFFFF0000u);
    lo = (ushort_t)(__float_as_uint(res) >> 16);
}
__device__ inline uint packsplit(float v) {
    uint u = __float_as_uint(v) & 0xFFFF0000u;
    uint ru = __float_as_uint(v - __uint_as_float(u));
    ru += 0x7FFFu + ((ru >> 16) & 1u);
    return u | (ru >> 16);
}
__device__ inline float unpackf(uint u) {
    return __uint_as_float(u & 0xFFFF0000u) + __uint_as_float(u << 16);
}

// ---------------------------------------------------------------------------
// Kernel 1: h = emb[x] + pe, stored packed hi|lo bf16
// ---------------------------------------------------------------------------
__global__ __launch_bounds__(256) void embed_pe(const int* __restrict__ x,
                                                const float* __restrict__ emb,
                                                uint* __restrict__ Hp) {
    int idx = blockIdx.x * 256 + threadIdx.x;
    if (idx >= BB * SS * DD) return;
    int d = idx & (DD - 1);
    int s = (idx >> 9) & (SS - 1);
    int tok = x[idx >> 9];
    int i2 = d >> 1;
    float freq = expf((float)(2 * i2) * (-9.210340371976184f / (float)DD));
    float ang = (float)s * freq;
    float pe = (d & 1) ? cosf(ang) : sinf(ang);
    Hp[idx] = packsplit(emb[(size_t)tok * DD + d] + pe);
}

// ---------------------------------------------------------------------------
// Kernel 1b: transpose + split fp32 [K][N] -> bf16 hi/lo [N][K]
// ---------------------------------------------------------------------------
__global__ __launch_bounds__(256) void transpose_split_w(const float* __restrict__ in,
                                                         ushort_t* __restrict__ outh,
                                                         ushort_t* __restrict__ outl,
                                                         int K, int N) {
    __shared__ ushort_t th[64][68], tl[64][68];
    int nb = N >> 6;
    int k0 = ((int)blockIdx.x / nb) << 6;
    int n0 = ((int)blockIdx.x % nb) << 6;
    int t = threadIdx.x;
    int r = t >> 2, cb = (t & 3) << 4;
#pragma unroll
    for (int c = 0; c < 4; c++) {
        float4 v = *reinterpret_cast<const float4*>(&in[(size_t)(k0 + r) * N + n0 + cb + 4 * c]);
        float vv[4] = {v.x, v.y, v.z, v.w};
#pragma unroll
        for (int e = 0; e < 4; e++) {
            ushort_t hb, lb; tsplit(vv[e], hb, lb);
            th[r][cb + 4 * c + e] = hb;
            tl[r][cb + 4 * c + e] = lb;
        }
    }
    __syncthreads();
    int n = t >> 2, kb = (t & 3) << 4;
#pragma unroll
    for (int c = 0; c < 4; c++) {
        ushort4 oh, ol;
        oh.x = th[kb + 4 * c + 0][n]; ol.x = tl[kb + 4 * c + 0][n];
        oh.y = th[kb + 4 * c + 1][n]; ol.y = tl[kb + 4 * c + 1][n];
        oh.z = th[kb + 4 * c + 2][n]; ol.z = tl[kb + 4 * c + 2][n];
        oh.w = th[kb + 4 * c + 3][n]; ol.w = tl[kb + 4 * c + 3][n];
        *reinterpret_cast<ushort4*>(&outh[(size_t)(n0 + n) * K + k0 + kb + 4 * c]) = oh;
        *reinterpret_cast<ushort4*>(&outl[(size_t)(n0 + n) * K + k0 + kb + 4 * c]) = ol;
    }
}

// ---------------------------------------------------------------------------
// Kernel 1c: W1 [L][8][FF] -> transposed split planes [L][FF][8] bf16 hi/lo
// ---------------------------------------------------------------------------
__global__ __launch_bounds__(256) void prep_w1t(const float* __restrict__ W1all,
                                                ushort_t* __restrict__ outh,
                                                ushort_t* __restrict__ outl) {
    int l = blockIdx.y;
    int f = blockIdx.x * 256 + threadIdx.x;
    const float* W1 = W1all + (size_t)l * NQ * FF;
    U8 ph, pl;
#pragma unroll
    for (int n = 0; n < 8; n++) {
        ushort_t hb, lb; tsplit(W1[n * FF + f], hb, lb);
        ph.u[n] = hb; pl.u[n] = lb;
    }
    *reinterpret_cast<bf16x8*>(&outh[((size_t)l * FF + f) * 8]) = ph.v;
    *reinterpret_cast<bf16x8*>(&outl[((size_t)l * FF + f) * 8]) = pl.v;
}

// ---------------------------------------------------------------------------
// Kernel 2: split-precision MFMA flash attention, QBLK=128, 8 waves.
// (unchanged from round 8)
// ---------------------------------------------------------------------------
__global__ __launch_bounds__(512, 4) void flash_attn_split(const uint* __restrict__ Hp,
                                                           ushort_t* __restrict__ outh,
                                                           ushort_t* __restrict__ outl) {
    __shared__ __align__(16) ushort_t Kh[64][72], Kl[64][72];
    __shared__ __align__(16) ushort_t Vh[64][72], Vl[64][72];   // [d][j]
    __shared__ __align__(16) ushort_t Ph[128][72], Pl[128][72];

    int i0 = blockIdx.x * 128;
    int h0 = blockIdx.y * DK;
    int b  = blockIdx.z;
    const uint* baseH = Hp + (size_t)b * (SS * DD);

    int t = threadIdx.x;
    int w = t >> 6;
    int ln = t & 63;
    int l15 = ln & 15, lh = ln >> 4;

    bf16x8 aqh0, aqh1, aql0, aql1;
    {
        int row = i0 + w * 16 + l15;
        const uint* src = &baseH[(size_t)row * DD + h0 + lh * 8];
        uint4 p0 = *reinterpret_cast<const uint4*>(src);
        uint4 p1 = *reinterpret_cast<const uint4*>(src + 4);
        uint4 p2 = *reinterpret_cast<const uint4*>(src + 32);
        uint4 p3 = *reinterpret_cast<const uint4*>(src + 36);
        uint a0[8] = {p0.x, p0.y, p0.z, p0.w, p1.x, p1.y, p1.z, p1.w};
        uint a1[8] = {p2.x, p2.y, p2.z, p2.w, p3.x, p3.y, p3.z, p3.w};
        U8 h0u, l0u, h1u, l1u;
#pragma unroll
        for (int e = 0; e < 8; e++) {
            h0u.u[e] = (ushort_t)(a0[e] >> 16);
            l0u.u[e] = (ushort_t)(a0[e] & 0xFFFFu);
            h1u.u[e] = (ushort_t)(a1[e] >> 16);
            l1u.u[e] = (ushort_t)(a1[e] & 0xFFFFu);
        }
        aqh0 = h0u.v; aql0 = l0u.v; aqh1 = h1u.v; aql1 = l1u.v;
    }

    float m_[4], l_[4], al[4];
    f32x4 acc[4];
    f32x4 z4 = {0.f, 0.f, 0.f, 0.f};
#pragma unroll
    for (int r = 0; r < 4; r++) { m_[r] = -1e30f; l_[r] = 0.f; acc[r] = z4; }

    int kr = t >> 3, kcb = (t & 7) * 8;
    int vc = t & 7, vr = t >> 3;

    for (int j0 = 0; j0 < SS; j0 += 64) {
        __syncthreads();
        {
            const uint* src = &baseH[(size_t)(j0 + kr) * DD + h0 + kcb];
            uint4 p0 = *reinterpret_cast<const uint4*>(src);
            uint4 p1 = *reinterpret_cast<const uint4*>(src + 4);
            uint a[8] = {p0.x, p0.y, p0.z, p0.w, p1.x, p1.y, p1.z, p1.w};
            U8 kh, kl;
#pragma unroll
            for (int e = 0; e < 8; e++) {
                kh.u[e] = (ushort_t)(a[e] >> 16);
                kl.u[e] = (ushort_t)(a[e] & 0xFFFFu);
            }
            *reinterpret_cast<bf16x8*>(&Kh[kr][kcb]) = kh.v;
            *reinterpret_cast<bf16x8*>(&Kl[kr][kcb]) = kl.v;
        }
        __syncthreads();
#pragma unroll
        for (int e = 0; e < 8; e++) {
            int d = vc + 8 * e;
            Vh[d][vr] = Kh[vr][d];
            Vl[d][vr] = Kl[vr][d];
        }
        f32x4 sc[4];
#pragma unroll
        for (int tt = 0; tt < 4; tt++) {
            bf16x8 bh0 = *reinterpret_cast<const bf16x8*>(&Kh[tt * 16 + l15][lh * 8]);
            bf16x8 bh1 = *reinterpret_cast<const bf16x8*>(&Kh[tt * 16 + l15][32 + lh * 8]);
            bf16x8 bl0 = *reinterpret_cast<const bf16x8*>(&Kl[tt * 16 + l15][lh * 8]);
            bf16x8 bl1 = *reinterpret_cast<const bf16x8*>(&Kl[tt * 16 + l15][32 + lh * 8]);
            f32x4 s = z4;
            s = MFMA(aqh0, bh0, s);
            s = MFMA(aqh1, bh1, s);
            s = MFMA(aqh0, bl0, s);
            s = MFMA(aqh1, bl1, s);
            s = MFMA(aql0, bh0, s);
            s = MFMA(aql1, bh1, s);
            sc[tt] = s * 0.125f;
        }
#pragma unroll
        for (int r = 0; r < 4; r++) {
            float mx = fmaxf(fmaxf(sc[0][r], sc[1][r]), fmaxf(sc[2][r], sc[3][r]));
            mx = fmaxf(mx, __shfl_xor(mx, 1));
            mx = fmaxf(mx, __shfl_xor(mx, 2));
            mx = fmaxf(mx, __shfl_xor(mx, 4));
            mx = fmaxf(mx, __shfl_xor(mx, 8));
            float nm = fmaxf(m_[r], mx);
            al[r] = __expf(m_[r] - nm);
            m_[r] = nm;
            float rs = 0.f;
#pragma unroll
            for (int tt = 0; tt < 4; tt++) {
                float p = __expf(sc[tt][r] - nm);
                sc[tt][r] = p;
                rs += p;
            }
            rs += __shfl_xor(rs, 1);
            rs += __shfl_xor(rs, 2);
            rs += __shfl_xor(rs, 4);
            rs += __shfl_xor(rs, 8);
            l_[r] = l_[r] * al[r] + rs;
        }
#pragma unroll
        for (int tt = 0; tt < 4; tt++)
#pragma unroll
            for (int r = 0; r < 4; r++) {
                ushort_t hb, lb; tsplit(sc[tt][r], hb, lb);
                Ph[w * 16 + lh * 4 + r][tt * 16 + l15] = hb;
                Pl[w * 16 + lh * 4 + r][tt * 16 + l15] = lb;
            }
        __syncthreads();
#pragma unroll
        for (int td = 0; td < 4; td++) {
            acc[td][0] *= al[0];
            acc[td][1] *= al[1];
            acc[td][2] *= al[2];
            acc[td][3] *= al[3];
        }
        bf16x8 aph0 = *reinterpret_cast<const bf16x8*>(&Ph[w * 16 + l15][lh * 8]);
        bf16x8 aph1 = *reinterpret_cast<const bf16x8*>(&Ph[w * 16 + l15][32 + lh * 8]);
        bf16x8 apl0 = *reinterpret_cast<const bf16x8*>(&Pl[w * 16 + l15][lh * 8]);
        bf16x8 apl1 = *reinterpret_cast<const bf16x8*>(&Pl[w * 16 + l15][32 + lh * 8]);
#pragma unroll
        for (int td = 0; td < 4; td++) {
            bf16x8 bvh0 = *reinterpret_cast<const bf16x8*>(&Vh[td * 16 + l15][lh * 8]);
            bf16x8 bvh1 = *reinterpret_cast<const bf16x8*>(&Vh[td * 16 + l15][32 + lh * 8]);
            bf16x8 bvl0 = *reinterpret_cast<const bf16x8*>(&Vl[td * 16 + l15][lh * 8]);
            bf16x8 bvl1 = *reinterpret_cast<const bf16x8*>(&Vl[td * 16 + l15][32 + lh * 8]);
            acc[td] = MFMA(aph0, bvh0, acc[td]);
            acc[td] = MFMA(aph1, bvh1, acc[td]);
            acc[td] = MFMA(aph0, bvl0, acc[td]);
            acc[td] = MFMA(aph1, bvl1, acc[td]);
            acc[td] = MFMA(apl0, bvh0, acc[td]);
            acc[td] = MFMA(apl1, bvh1, acc[td]);
        }
    }

#pragma unroll
    for (int r = 0; r < 4; r++) {
        float inv = 1.f / l_[r];
        int row = i0 + w * 16 + lh * 4 + r;
#pragma unroll
        for (int td = 0; td < 4; td++) {
            float o = acc[td][r] * inv;
            ushort_t hb, lb; tsplit(o, hb, lb);
            size_t idx = (size_t)b * SS * DD + (size_t)row * DD + h0 + td * 16 + l15;
            outh[idx] = hb;
            outl[idx] = lb;
        }
    }
}

// swizzled fragment read from an unpadded [128][64] plane:
// logical 16B chunk (ks*4+lh) of row -> physical chunk XOR (row&7)
#define SWZREAD(plane, row, ks) \
    (*reinterpret_cast<const bf16x8*>(&(plane)[row][((((ks) * 4 + lh) ^ ((row) & 7)) * 8)]))

// ---------------------------------------------------------------------------
// Kernel 3: C fp32 = A(hi/lo [M][K]) @ Bt(pre-split hi/lo [N][K]) + bias.
// 128x128 tile, BK=64, 512 thr / 8 waves. SINGLE-buffered LDS filled by
// global_load_lds DMA (linear dest, inverse-swizzled source, swizzled read).
// 64 KB LDS -> 2 blocks/CU; co-resident block covers DMA latency.
// ---------------------------------------------------------------------------
__global__ __launch_bounds__(512, 4) void gemm_split(const ushort_t* __restrict__ Ah,
                                                     const ushort_t* __restrict__ Al,
                                                     const ushort_t* __restrict__ Bth,
                                                     const ushort_t* __restrict__ Btl,
                                                     const float* __restrict__ bias,
                                                     float* __restrict__ C,
                                                     int M, int N, int K) {
    __shared__ __align__(16) ushort_t sAh[128][64], sAl[128][64];
    __shared__ __align__(16) ushort_t sBh[128][64], sBl[128][64];
    int nb = N >> 7;
    int m0 = ((int)blockIdx.x / nb) << 7;
    int n0 = ((int)blockIdx.x % nb) << 7;
    int t = threadIdx.x;
    int w = t >> 6, ln = t & 63, l15 = ln & 15, lh = ln >> 4;
    int wr = (w >> 2) * 64, wc = (w & 3) * 32;

    f32x4 z4 = {0.f, 0.f, 0.f, 0.f};
    f32x4 acc[4][2];
#pragma unroll
    for (int i = 0; i < 4; i++)
#pragma unroll
        for (int j = 0; j < 2; j++) acc[i][j] = z4;

    int srow = ln >> 3;                 // 0..7 row within wave chunk
    int schunk = (ln & 7) ^ srow;       // inverse-swizzled source 16B chunk

    int ntile = K >> 6;
    for (int kt = 0; kt < ntile; kt++) {
        __syncthreads();   // prev GEMM done -> LDS free
        int kk = kt * 64;
#pragma unroll
        for (int p = 0; p < 2; p++) {
            int rbase = (w + p * 8) * 8;
            int grow = rbase + srow;
            int gc = kk + schunk * 8;
            gload16(&Ah[(size_t)(m0 + grow) * K + gc],  &sAh[rbase][0]);
            gload16(&Al[(size_t)(m0 + grow) * K + gc],  &sAl[rbase][0]);
            gload16(&Bth[(size_t)(n0 + grow) * K + gc], &sBh[rbase][0]);
            gload16(&Btl[(size_t)(n0 + grow) * K + gc], &sBl[rbase][0]);
        }
        __syncthreads();   // drain DMA -> tile resident
#pragma unroll
        for (int ks = 0; ks < 2; ks++) {
            bf16x8 ah[4], al_[4];
#pragma unroll
            for (int mt = 0; mt < 4; mt++) {
                int row = wr + mt * 16 + l15;
                ah[mt]  = SWZREAD(sAh, row, ks);
                al_[mt] = SWZREAD(sAl, row, ks);
            }
#pragma unroll
            for (int nt = 0; nt < 2; nt++) {
                int row = wc + nt * 16 + l15;
                bf16x8 bh = SWZREAD(sBh, row, ks);
                bf16x8 bl = SWZREAD(sBl, row, ks);
#pragma unroll
                for (int mt = 0; mt < 4; mt++) {
                    acc[mt][nt] = MFMA(ah[mt], bh, acc[mt][nt]);
                    acc[mt][nt] = MFMA(ah[mt], bl, acc[mt][nt]);
                    acc[mt][nt] = MFMA(al_[mt], bh, acc[mt][nt]);
                }
            }
        }
    }
#pragma unroll
    for (int nt = 0; nt < 2; nt++) {
        int col = n0 + wc + nt * 16 + l15;
        float bs = bias[col];
#pragma unroll
        for (int mt = 0; mt < 4; mt++)
#pragma unroll
            for (int r = 0; r < 4; r++)
                C[(size_t)(m0 + wr + mt * 16 + lh * 4 + r) * N + col] = acc[mt][nt][r] + bs;
    }
}

// ---------------------------------------------------------------------------
// Kernel 4: Hp = pack(layernorm(unpack(Hp) + add) * g + b)
// ---------------------------------------------------------------------------
__global__ __launch_bounds__(256) void ln_residual(uint* __restrict__ Hp,
                                                   const float* __restrict__ add,
                                                   const float* __restrict__ g,
                                                   const float* __restrict__ bta) {
    int row = blockIdx.x * 4 + (threadIdx.x >> 6);
    int lane = threadIdx.x & 63;
    uint* hp = Hp + (size_t)row * DD;
    const float* ap = add + (size_t)row * DD;
    float v[8];
    float sum = 0.f;
#pragma unroll
    for (int i = 0; i < 8; i++) {
        int d = lane + i * 64;
        v[i] = unpackf(hp[d]) + ap[d];
        sum += v[i];
    }
#pragma unroll
    for (int off = 32; off > 0; off >>= 1) sum += __shfl_xor(sum, off);
    float mu = sum * (1.f / DD);
    float s2 = 0.f;
#pragma unroll
    for (int i = 0; i < 8; i++) {
        float d2 = v[i] - mu;
        s2 += d2 * d2;
    }
#pragma unroll
    for (int off = 32; off > 0; off >>= 1) s2 += __shfl_xor(s2, off);
    float inv = rsqrtf(s2 * (1.f / DD) + 1e-5f);
#pragma unroll
    for (int i = 0; i < 8; i++) {
        int d = lane + i * 64;
        hp[d] = packsplit((v[i] - mu) * inv * g[d] + bta[d]);
    }
}

// ---------------------------------------------------------------------------
// Kernel 5: fused FFN, 128x128 tile, BK=64, 512 thr / 8 waves.
// Per k-tile: bar -> issue B-DMA (latency hides under A2) -> A2 on matrix
// pipe -> bar(drain) -> main GEMM. Single-buffered sB -> 73 KB, 2 blocks/CU.
// W1 fragments register-prefetched one tile ahead.
// ---------------------------------------------------------------------------
__global__ __launch_bounds__(512, 4) void ffn_split(const uint* __restrict__ Hp,
                                                    const ushort_t* __restrict__ W1th,
                                                    const ushort_t* __restrict__ W1tl,
                                                    const float* __restrict__ b1,
                                                    const ushort_t* __restrict__ W2th,
                                                    const ushort_t* __restrict__ W2tl,
                                                    const float* __restrict__ b2,
                                                    const float* __restrict__ theta,
                                                    float* __restrict__ outp) {
    __shared__ __align__(16) ushort_t Abh[128][72], Abl[128][72];
    __shared__ __align__(16) ushort_t sBh[128][64], sBl[128][64];
    __shared__ __align__(16) ushort_t qsh[129][8], qsl[129][8];
    __shared__ float tcs[8];

    int t = threadIdx.x;
    int m0 = (int)(blockIdx.x >> 2) * 128;
    int n0 = (int)(blockIdx.x & 3) * 128;
    if (t < 8) {
        tcs[t] = cosf(theta[t]);
        qsh[128][t] = 0;
        qsl[128][t] = 0;
    }
    __syncthreads();
#pragma unroll
    for (int i = 0; i < 2; i++) {
        int idx = t + i * 512;
        int m = idx >> 3, n = idx & 7;
        float q = cosf(unpackf(Hp[(size_t)(m0 + m) * DD + n])) * tcs[n];
        ushort_t hb, lb; tsplit(q, hb, lb);
        qsh[m][n] = hb;
        qsl[m][n] = lb;
    }

    int w = t >> 6, ln = t & 63, l15 = ln & 15, lh = ln >> 4;
    int wr = (w >> 2) * 64, wc = (w & 3) * 32;
    bool lh0 = (lh == 0);
    f32x4 z4 = {0.f, 0.f, 0.f, 0.f};
    bf16x8 z8 = {0, 0, 0, 0, 0, 0, 0, 0};
    f32x4 acc[4][2];
#pragma unroll
    for (int i = 0; i < 4; i++)
#pragma unroll
        for (int j = 0; j < 2; j++) acc[i][j] = z4;

    int srow = ln >> 3;
    int schunk = (ln & 7) ^ srow;

    // W1 fragment prefetch for tile 0
    bf16x8 rwh[4], rwl[4];
#pragma unroll
    for (int fq = 0; fq < 4; fq++) {
        rwh[fq] = *reinterpret_cast<const bf16x8*>(&W1th[(size_t)(fq * 16 + l15) * 8]);
        rwl[fq] = *reinterpret_cast<const bf16x8*>(&W1tl[(size_t)(fq * 16 + l15) * 8]);
    }

    for (int k0 = 0; k0 < FF; k0 += 64) {
        __syncthreads();   // prev GEMM done -> Ab & sB free; qs visible (iter 0)
        // ---- issue B tile DMA (completes under the A2 phase below)
#pragma unroll
        for (int p = 0; p < 2; p++) {
            int rbase = (w + p * 8) * 8;
            int grow = rbase + srow;
            int gc = k0 + schunk * 8;
            gload16(&W2th[(size_t)(n0 + grow) * FF + gc], &sBh[rbase][0]);
            gload16(&W2tl[(size_t)(n0 + grow) * FF + gc], &sBl[rbase][0]);
        }
        // ---- A2 via MFMA using prefetched W1 frags (wave w -> rows w*16..+15)
        {
            bf16x8 wh[4], wl[4];
#pragma unroll
            for (int fq = 0; fq < 4; fq++) {
                wh[fq] = lh0 ? rwh[fq] : z8;
                wl[fq] = lh0 ? rwl[fq] : z8;
            }
            int m = w * 16 + l15;
            int mrow = lh0 ? m : 128;
            bf16x8 qh  = *reinterpret_cast<const bf16x8*>(&qsh[mrow][0]);
            bf16x8 ql_ = *reinterpret_cast<const bf16x8*>(&qsl[mrow][0]);
#pragma unroll
            for (int fq = 0; fq < 4; fq++) {
                f32x4 d = z4;
                d = MFMA(wh[fq], qh, d);
                d = MFMA(wh[fq], ql_, d);
                d = MFMA(wl[fq], qh, d);
                float4 b1v = *reinterpret_cast<const float4*>(&b1[k0 + fq * 16 + lh * 4]);
                float v0 = fmaxf(d[0] + b1v.x, 0.f);
                float v1 = fmaxf(d[1] + b1v.y, 0.f);
                float v2 = fmaxf(d[2] + b1v.z, 0.f);
                float v3 = fmaxf(d[3] + b1v.w, 0.f);
                ushort_t h0_, l0_, h1_, l1_, h2_, l2_, h3_, l3_;
                tsplit_fast(v0, h0_, l0_);
                tsplit_fast(v1, h1_, l1_);
                tsplit_fast(v2, h2_, l2_);
                tsplit_fast(v3, h3_, l3_);
                uint2 hu, lu;
                hu.x = (uint)h0_ | ((uint)h1_ << 16);
                hu.y = (uint)h2_ | ((uint)h3_ << 16);
                lu.x = (uint)l0_ | ((uint)l1_ << 16);
                lu.y = (uint)l2_ | ((uint)l3_ << 16);
                *reinterpret_cast<uint2*>(&Abh[m][fq * 16 + lh * 4]) = hu;
                *reinterpret_cast<uint2*>(&Abl[m][fq * 16 + lh * 4]) = lu;
            }
        }
        __syncthreads();   // A2 visible + B DMA drained
        // ---- W1 prefetch for next tile (covered by main GEMM)
        if (k0 + 64 < FF) {
            int k1 = k0 + 64;
#pragma unroll
            for (int fq = 0; fq < 4; fq++) {
                rwh[fq] = *reinterpret_cast<const bf16x8*>(&W1th[(size_t)(k1 + fq * 16 + l15) * 8]);
                rwl[fq] = *reinterpret_cast<const bf16x8*>(&W1tl[(size_t)(k1 + fq * 16 + l15) * 8]);
            }
        }
        // ---- main GEMM: wave owns 64x32
#pragma unroll
        for (int ks = 0; ks < 2; ks++) {
            bf16x8 ah[4], al_[4];
#pragma unroll
            for (int mt = 0; mt < 4; mt++) {
                ah[mt]  = *reinterpret_cast<const bf16x8*>(&Abh[wr + mt * 16 + l15][ks * 32 + lh * 8]);
                al_[mt] = *reinterpret_cast<const bf16x8*>(&Abl[wr + mt * 16 + l15][ks * 32 + lh * 8]);
            }
#pragma unroll
            for (int nt = 0; nt < 2; nt++) {
                int row = wc + nt * 16 + l15;
                bf16x8 bh = SWZREAD(sBh, row, ks);
                bf16x8 bl = SWZREAD(sBl, row, ks);
#pragma unroll
                for (int mt = 0; mt < 4; mt++) {
                    acc[mt][nt] = MFMA(ah[mt], bh, acc[mt][nt]);
                    acc[mt][nt] = MFMA(ah[mt], bl, acc[mt][nt]);
                    acc[mt][nt] = MFMA(al_[mt], bh, acc[mt][nt]);
                }
            }
        }
    }
#pragma unroll
    for (int nt = 0; nt < 2; nt++) {
        int col = n0 + wc + nt * 16 + l15;
        float bs = b2[col];
#pragma unroll
        for (int mt = 0; mt < 4; mt++)
#pragma unroll
            for (int r = 0; r < 4; r++)
                outp[(size_t)(m0 + wr + mt * 16 + lh * 4 + r) * DD + col] = acc[mt][nt][r] + bs;
    }
}

// ---------------------------------------------------------------------------
// Kernel 6: pooled[b,d] = mean_s h[b,s,d]
// ---------------------------------------------------------------------------
__global__ __launch_bounds__(256) void pool_mean(const uint* __restrict__ Hp,
                                                 float* __restrict__ pooled) {
    int idx = blockIdx.x * 256 + threadIdx.x;
    if (idx >= BB * DD) return;
    int b = idx >> 9, d = idx & 511;
    float s = 0.f;
    for (int j = 0; j < SS; j++) s += unpackf(Hp[((size_t)b * SS + j) * DD + d]);
    pooled[idx] = s * (1.f / SS);
}

// ---------------------------------------------------------------------------
// Kernel 7: out[b,c] = pooled[b,:] . clf_w[:,c] + clf_b[c]
// ---------------------------------------------------------------------------
__global__ __launch_bounds__(64) void classifier(const float* __restrict__ pooled,
                                                 const float* __restrict__ W,
                                                 const float* __restrict__ bias,
                                                 float* __restrict__ out) {
    int o = blockIdx.x;
    int b = o / CC, c = o % CC;
    int lane = threadIdx.x;
    float s = 0.f;
    for (int d = lane; d < DD; d += 64) s += pooled[b * DD + d] * W[d * CC + c];
#pragma unroll
    for (int off = 32; off > 0; off >>= 1) s += __shfl_xor(s, off);
    if (lane == 0) out[o] = s + bias[c];
}

// ---------------------------------------------------------------------------
extern "C" void kernel_launch(void* const* d_in, const int* in_sizes, int n_in,
                              void* d_out, int out_size, void* d_ws, size_t ws_size,
                              hipStream_t stream) {
    (void)in_sizes; (void)n_in; (void)out_size; (void)ws_size;
    const int*   x      = (const int*)d_in[0];
    const float* emb    = (const float*)d_in[1];
    const float* ln1_g  = (const float*)d_in[2];
    const float* ln1_b  = (const float*)d_in[3];
    const float* ln2_g  = (const float*)d_in[4];
    const float* ln2_b  = (const float*)d_in[5];
    const float* attn_w = (const float*)d_in[6];
    const float* attn_b = (const float*)d_in[7];
    const float* theta  = (const float*)d_in[8];
    const float* ffn_w1 = (const float*)d_in[9];
    const float* ffn_b1 = (const float*)d_in[10];
    const float* ffn_w2 = (const float*)d_in[11];
    const float* ffn_b2 = (const float*)d_in[12];
    const float* clf_w  = (const float*)d_in[13];
    const float* clf_b  = (const float*)d_in[14];
    float* out = (float*)d_out;

    char* ws = (char*)d_ws;
    uint*     Hp     = (uint*)(ws);                     // 32 MB packed hi|lo
    float*    t2     = (float*)(ws + 33554432);         // 32 MB fp32
    ushort_t* t1h    = (ushort_t*)(ws + 67108864);      // 16 MB bf16 hi
    ushort_t* t1l    = (ushort_t*)(ws + 83886080);      // 16 MB bf16 lo
    float*    pooled = (float*)(ws + 100663296);        // 64 KB
    ushort_t* Wath   = (ushort_t*)(ws + 100728832);     // 512 KB attn_w hi
    ushort_t* Watl   = (ushort_t*)(ws + 101253120);     // 512 KB attn_w lo
    ushort_t* W1th6  = (ushort_t*)(ws + 101777408);     // 192 KB W1t hi
    ushort_t* W1tl6  = (ushort_t*)(ws + 101974016);     // 192 KB W1t lo
    ushort_t* W2th   = (ushort_t*)(ws + 67108864);      // reuses t1h region
    ushort_t* W2tl   = (ushort_t*)(ws + 67108864 + 2097152);

    embed_pe<<<(BB * SS * DD + 255) / 256, 256, 0, stream>>>(x, emb, Hp);
    prep_w1t<<<dim3(FF / 256, LL), 256, 0, stream>>>(ffn_w1, W1th6, W1tl6);

    for (int l = 0; l < LL; l++) {
        flash_attn_split<<<dim3(SS / 128, HH, BB), 512, 0, stream>>>(Hp, t1h, t1l);
        transpose_split_w<<<(DD / 64) * (DD / 64), 256, 0, stream>>>(
            attn_w + (size_t)l * DD * DD, Wath, Watl, DD, DD);
        gemm_split<<<(16384 / 128) * (DD / 128), 512, 0, stream>>>(
            t1h, t1l, Wath, Watl, attn_b + l * DD, t2, BB * SS, DD, DD);
        ln_residual<<<BB * SS / 4, 256, 0, stream>>>(Hp, t2, ln1_g + l * DD, ln1_b + l * DD);
        transpose_split_w<<<(FF / 64) * (DD / 64), 256, 0, stream>>>(
            ffn_w2 + (size_t)l * FF * DD, W2th, W2tl, FF, DD);
        ffn_split<<<(16384 / 128) * (DD / 128), 512, 0, stream>>>(
            Hp, W1th6 + (size_t)l * FF * 8, W1tl6 + (size_t)l * FF * 8, ffn_b1 + l * FF,
            W2th, W2tl, ffn_b2 + l * DD, theta + l * NQ, t2);
        ln_residual<<<BB * SS / 4, 256, 0, stream>>>(Hp, t2, ln2_g + l * DD, ln2_b + l * DD);
    }

    pool_mean<<<(BB * DD + 255) / 256, 256, 0, stream>>>(Hp, pooled);
    classifier<<<BB * CC, 64, 0, stream>>>(pooled, clf_w, clf_b, out);
}

// Round 16
// 1851.478 us; speedup vs baseline: 1.4446x; 1.0483x over previous
//
#include <hip/hip_runtime.h>
#include <hip/hip_bf16.h>
#include <math.h>

#define BB 32
#define SS 512
#define DD 512
#define HH 8
#define DK 64
#define LL 6
#define NQ 8
#define FF 2048
#define CC 10

typedef unsigned int uint;
typedef unsigned short ushort_t;
using bf16x8 = __attribute__((ext_vector_type(8))) short;
using f32x4  = __attribute__((ext_vector_type(4))) float;

#define MFMA(a, b, c) __builtin_amdgcn_mfma_f32_16x16x32_bf16((a), (b), (c), 0, 0, 0)

union U8 { ushort_t u[8]; bf16x8 v; };

__device__ __forceinline__ void gload16(const void* g, void* l) {
    __builtin_amdgcn_global_load_lds((__attribute__((address_space(1))) void*)g,
                                     (__attribute__((address_space(3))) void*)l,
                                     16, 0, 0);
}

__device__ inline ushort_t f2bf(float x) {           // fp32 -> bf16, RNE
    uint u = __float_as_uint(x);
    u += 0x7FFFu + ((u >> 16) & 1u);
    return (ushort_t)(u >> 16);
}
// truncation split: hi = top 16 bits, lo = RNE(residual)
__device__ inline void tsplit(float v, ushort_t& hi, ushort_t& lo) {
    uint u = __float_as_uint(v);
    hi = (ushort_t)(u >> 16);
    lo = f2bf(v - __uint_as_float(u & 0xFFFF0000u));
}
// cheap variant (lo also truncated): used on A2 only
__device__ inline void tsplit_fast(float v, ushort_t& hi, ushort_t& lo) {
    uint u = __float_as_uint(v);
    hi = (ushort_t)(u >> 16);
    float res = v - __uint_as_float(u & 0xFFFF0000u);
    lo = (ushort_t)(__float_as_uint(res) >> 16);
}
__device__ inline uint packsplit(float v) {
    uint u = __float_as_uint(v) & 0xFFFF0000u;
    uint ru = __float_as_uint(v - __uint_as_float(u));
    ru += 0x7FFFu + ((ru >> 16) & 1u);
    return u | (ru >> 16);
}
__device__ inline float unpackf(uint u) {
    return __uint_as_float(u & 0xFFFF0000u) + __uint_as_float(u << 16);
}

// ---------------------------------------------------------------------------
// Kernel 1: h = emb[x] + pe, stored packed hi|lo bf16
// ---------------------------------------------------------------------------
__global__ __launch_bounds__(256) void embed_pe(const int* __restrict__ x,
                                                const float* __restrict__ emb,
                                                uint* __restrict__ Hp) {
    int idx = blockIdx.x * 256 + threadIdx.x;
    if (idx >= BB * SS * DD) return;
    int d = idx & (DD - 1);
    int s = (idx >> 9) & (SS - 1);
    int tok = x[idx >> 9];
    int i2 = d >> 1;
    float freq = expf((float)(2 * i2) * (-9.210340371976184f / (float)DD));
    float ang = (float)s * freq;
    float pe = (d & 1) ? cosf(ang) : sinf(ang);
    Hp[idx] = packsplit(emb[(size_t)tok * DD + d] + pe);
}

// ---------------------------------------------------------------------------
// Kernel 1b: transpose + split fp32 [K][N] -> bf16 hi/lo [N][K]  (r8-proven)
// ---------------------------------------------------------------------------
__global__ __launch_bounds__(256) void transpose_split_w(const float* __restrict__ in,
                                                         ushort_t* __restrict__ outh,
                                                         ushort_t* __restrict__ outl,
                                                         int K, int N) {
    __shared__ ushort_t th[64][68], tl[64][68];
    int nb = N >> 6;
    int k0 = ((int)blockIdx.x / nb) << 6;
    int n0 = ((int)blockIdx.x % nb) << 6;
    int t = threadIdx.x;
    int r = t >> 2, cb = (t & 3) << 4;
#pragma unroll
    for (int c = 0; c < 4; c++) {
        float4 v = *reinterpret_cast<const float4*>(&in[(size_t)(k0 + r) * N + n0 + cb + 4 * c]);
        float vv[4] = {v.x, v.y, v.z, v.w};
#pragma unroll
        for (int e = 0; e < 4; e++) {
            ushort_t hb, lb; tsplit(vv[e], hb, lb);
            th[r][cb + 4 * c + e] = hb;
            tl[r][cb + 4 * c + e] = lb;
        }
    }
    __syncthreads();
    int n = t >> 2, kb = (t & 3) << 4;
#pragma unroll
    for (int c = 0; c < 4; c++) {
        ushort4 oh, ol;
        oh.x = th[kb + 4 * c + 0][n]; ol.x = tl[kb + 4 * c + 0][n];
        oh.y = th[kb + 4 * c + 1][n]; ol.y = tl[kb + 4 * c + 1][n];
        oh.z = th[kb + 4 * c + 2][n]; ol.z = tl[kb + 4 * c + 2][n];
        oh.w = th[kb + 4 * c + 3][n]; ol.w = tl[kb + 4 * c + 3][n];
        *reinterpret_cast<ushort4*>(&outh[(size_t)(n0 + n) * K + k0 + kb + 4 * c]) = oh;
        *reinterpret_cast<ushort4*>(&outl[(size_t)(n0 + n) * K + k0 + kb + 4 * c]) = ol;
    }
}

// ---------------------------------------------------------------------------
// Kernel 1c: W1 [L][8][FF] -> transposed split planes [L][FF][8] bf16 hi/lo
// ---------------------------------------------------------------------------
__global__ __launch_bounds__(256) void prep_w1t(const float* __restrict__ W1all,
                                                ushort_t* __restrict__ outh,
                                                ushort_t* __restrict__ outl) {
    int l = blockIdx.y;
    int f = blockIdx.x * 256 + threadIdx.x;
    const float* W1 = W1all + (size_t)l * NQ * FF;
    U8 ph, pl;
#pragma unroll
    for (int n = 0; n < 8; n++) {
        ushort_t hb, lb; tsplit(W1[n * FF + f], hb, lb);
        ph.u[n] = hb; pl.u[n] = lb;
    }
    *reinterpret_cast<bf16x8*>(&outh[((size_t)l * FF + f) * 8]) = ph.v;
    *reinterpret_cast<bf16x8*>(&outl[((size_t)l * FF + f) * 8]) = pl.v;
}

// ---------------------------------------------------------------------------
// Kernel 2: split-precision MFMA flash attention, QBLK=128, 8 waves.
// (r8-proven, unchanged)
// ---------------------------------------------------------------------------
__global__ __launch_bounds__(512, 4) void flash_attn_split(const uint* __restrict__ Hp,
                                                           ushort_t* __restrict__ outh,
                                                           ushort_t* __restrict__ outl) {
    __shared__ __align__(16) ushort_t Kh[64][72], Kl[64][72];
    __shared__ __align__(16) ushort_t Vh[64][72], Vl[64][72];   // [d][j]
    __shared__ __align__(16) ushort_t Ph[128][72], Pl[128][72];

    int i0 = blockIdx.x * 128;
    int h0 = blockIdx.y * DK;
    int b  = blockIdx.z;
    const uint* baseH = Hp + (size_t)b * (SS * DD);

    int t = threadIdx.x;
    int w = t >> 6;
    int ln = t & 63;
    int l15 = ln & 15, lh = ln >> 4;

    bf16x8 aqh0, aqh1, aql0, aql1;
    {
        int row = i0 + w * 16 + l15;
        const uint* src = &baseH[(size_t)row * DD + h0 + lh * 8];
        uint4 p0 = *reinterpret_cast<const uint4*>(src);
        uint4 p1 = *reinterpret_cast<const uint4*>(src + 4);
        uint4 p2 = *reinterpret_cast<const uint4*>(src + 32);
        uint4 p3 = *reinterpret_cast<const uint4*>(src + 36);
        uint a0[8] = {p0.x, p0.y, p0.z, p0.w, p1.x, p1.y, p1.z, p1.w};
        uint a1[8] = {p2.x, p2.y, p2.z, p2.w, p3.x, p3.y, p3.z, p3.w};
        U8 h0u, l0u, h1u, l1u;
#pragma unroll
        for (int e = 0; e < 8; e++) {
            h0u.u[e] = (ushort_t)(a0[e] >> 16);
            l0u.u[e] = (ushort_t)(a0[e] & 0xFFFFu);
            h1u.u[e] = (ushort_t)(a1[e] >> 16);
            l1u.u[e] = (ushort_t)(a1[e] & 0xFFFFu);
        }
        aqh0 = h0u.v; aql0 = l0u.v; aqh1 = h1u.v; aql1 = l1u.v;
    }

    float m_[4], l_[4], al[4];
    f32x4 acc[4];
    f32x4 z4 = {0.f, 0.f, 0.f, 0.f};
#pragma unroll
    for (int r = 0; r < 4; r++) { m_[r] = -1e30f; l_[r] = 0.f; acc[r] = z4; }

    int kr = t >> 3, kcb = (t & 7) * 8;
    int vc = t & 7, vr = t >> 3;

    for (int j0 = 0; j0 < SS; j0 += 64) {
        __syncthreads();
        {
            const uint* src = &baseH[(size_t)(j0 + kr) * DD + h0 + kcb];
            uint4 p0 = *reinterpret_cast<const uint4*>(src);
            uint4 p1 = *reinterpret_cast<const uint4*>(src + 4);
            uint a[8] = {p0.x, p0.y, p0.z, p0.w, p1.x, p1.y, p1.z, p1.w};
            U8 kh, kl;
#pragma unroll
            for (int e = 0; e < 8; e++) {
                kh.u[e] = (ushort_t)(a[e] >> 16);
                kl.u[e] = (ushort_t)(a[e] & 0xFFFFu);
            }
            *reinterpret_cast<bf16x8*>(&Kh[kr][kcb]) = kh.v;
            *reinterpret_cast<bf16x8*>(&Kl[kr][kcb]) = kl.v;
        }
        __syncthreads();
#pragma unroll
        for (int e = 0; e < 8; e++) {
            int d = vc + 8 * e;
            Vh[d][vr] = Kh[vr][d];
            Vl[d][vr] = Kl[vr][d];
        }
        f32x4 sc[4];
#pragma unroll
        for (int tt = 0; tt < 4; tt++) {
            bf16x8 bh0 = *reinterpret_cast<const bf16x8*>(&Kh[tt * 16 + l15][lh * 8]);
            bf16x8 bh1 = *reinterpret_cast<const bf16x8*>(&Kh[tt * 16 + l15][32 + lh * 8]);
            bf16x8 bl0 = *reinterpret_cast<const bf16x8*>(&Kl[tt * 16 + l15][lh * 8]);
            bf16x8 bl1 = *reinterpret_cast<const bf16x8*>(&Kl[tt * 16 + l15][32 + lh * 8]);
            f32x4 s = z4;
            s = MFMA(aqh0, bh0, s);
            s = MFMA(aqh1, bh1, s);
            s = MFMA(aqh0, bl0, s);
            s = MFMA(aqh1, bl1, s);
            s = MFMA(aql0, bh0, s);
            s = MFMA(aql1, bh1, s);
            sc[tt] = s * 0.125f;
        }
#pragma unroll
        for (int r = 0; r < 4; r++) {
            float mx = fmaxf(fmaxf(sc[0][r], sc[1][r]), fmaxf(sc[2][r], sc[3][r]));
            mx = fmaxf(mx, __shfl_xor(mx, 1));
            mx = fmaxf(mx, __shfl_xor(mx, 2));
            mx = fmaxf(mx, __shfl_xor(mx, 4));
            mx = fmaxf(mx, __shfl_xor(mx, 8));
            float nm = fmaxf(m_[r], mx);
            al[r] = __expf(m_[r] - nm);
            m_[r] = nm;
            float rs = 0.f;
#pragma unroll
            for (int tt = 0; tt < 4; tt++) {
                float p = __expf(sc[tt][r] - nm);
                sc[tt][r] = p;
                rs += p;
            }
            rs += __shfl_xor(rs, 1);
            rs += __shfl_xor(rs, 2);
            rs += __shfl_xor(rs, 4);
            rs += __shfl_xor(rs, 8);
            l_[r] = l_[r] * al[r] + rs;
        }
#pragma unroll
        for (int tt = 0; tt < 4; tt++)
#pragma unroll
            for (int r = 0; r < 4; r++) {
                ushort_t hb, lb; tsplit(sc[tt][r], hb, lb);
                Ph[w * 16 + lh * 4 + r][tt * 16 + l15] = hb;
                Pl[w * 16 + lh * 4 + r][tt * 16 + l15] = lb;
            }
        __syncthreads();
#pragma unroll
        for (int td = 0; td < 4; td++) {
            acc[td][0] *= al[0];
            acc[td][1] *= al[1];
            acc[td][2] *= al[2];
            acc[td][3] *= al[3];
        }
        bf16x8 aph0 = *reinterpret_cast<const bf16x8*>(&Ph[w * 16 + l15][lh * 8]);
        bf16x8 aph1 = *reinterpret_cast<const bf16x8*>(&Ph[w * 16 + l15][32 + lh * 8]);
        bf16x8 apl0 = *reinterpret_cast<const bf16x8*>(&Pl[w * 16 + l15][lh * 8]);
        bf16x8 apl1 = *reinterpret_cast<const bf16x8*>(&Pl[w * 16 + l15][32 + lh * 8]);
#pragma unroll
        for (int td = 0; td < 4; td++) {
            bf16x8 bvh0 = *reinterpret_cast<const bf16x8*>(&Vh[td * 16 + l15][lh * 8]);
            bf16x8 bvh1 = *reinterpret_cast<const bf16x8*>(&Vh[td * 16 + l15][32 + lh * 8]);
            bf16x8 bvl0 = *reinterpret_cast<const bf16x8*>(&Vl[td * 16 + l15][lh * 8]);
            bf16x8 bvl1 = *reinterpret_cast<const bf16x8*>(&Vl[td * 16 + l15][32 + lh * 8]);
            acc[td] = MFMA(aph0, bvh0, acc[td]);
            acc[td] = MFMA(aph1, bvh1, acc[td]);
            acc[td] = MFMA(aph0, bvl0, acc[td]);
            acc[td] = MFMA(aph1, bvl1, acc[td]);
            acc[td] = MFMA(apl0, bvh0, acc[td]);
            acc[td] = MFMA(apl1, bvh1, acc[td]);
        }
    }

#pragma unroll
    for (int r = 0; r < 4; r++) {
        float inv = 1.f / l_[r];
        int row = i0 + w * 16 + lh * 4 + r;
#pragma unroll
        for (int td = 0; td < 4; td++) {
            float o = acc[td][r] * inv;
            ushort_t hb, lb; tsplit(o, hb, lb);
            size_t idx = (size_t)b * SS * DD + (size_t)row * DD + h0 + td * 16 + l15;
            outh[idx] = hb;
            outl[idx] = lb;
        }
    }
}

// ---------------------------------------------------------------------------
// Kernel 3: C fp32 = A(hi/lo [M][K]) @ Bt(pre-split hi/lo [N][K]) + bias.
// 128x128 tile, BK=64, 256 thr / 4 waves (r8-proven). Pure uint4 staging.
// ---------------------------------------------------------------------------
__global__ __launch_bounds__(256, 2) void gemm_split(const ushort_t* __restrict__ Ah,
                                                     const ushort_t* __restrict__ Al,
                                                     const ushort_t* __restrict__ Bth,
                                                     const ushort_t* __restrict__ Btl,
                                                     const float* __restrict__ bias,
                                                     float* __restrict__ C,
                                                     int M, int N, int K) {
    __shared__ __align__(16) ushort_t Abh[128][72], Abl[128][72];
    __shared__ __align__(16) ushort_t Bbh[128][72], Bbl[128][72];
    int nb = N >> 7;
    int m0 = ((int)blockIdx.x / nb) << 7;
    int n0 = ((int)blockIdx.x % nb) << 7;
    int t = threadIdx.x;
    int w = t >> 6, ln = t & 63, l15 = ln & 15, lh = ln >> 4;
    int wr = (w >> 1) * 64, wc = (w & 1) * 64;

    f32x4 z4 = {0.f, 0.f, 0.f, 0.f};
    f32x4 acc[4][4];
#pragma unroll
    for (int i = 0; i < 4; i++)
#pragma unroll
        for (int j = 0; j < 4; j++) acc[i][j] = z4;

    int arr = t >> 3, akk = (t & 7) * 8;

    for (int k0 = 0; k0 < K; k0 += 64) {
        __syncthreads();
#pragma unroll
        for (int r = 0; r < 4; r++) {
            int row = arr + r * 32;
            *reinterpret_cast<uint4*>(&Abh[row][akk]) =
                *reinterpret_cast<const uint4*>(&Ah[(size_t)(m0 + row) * K + k0 + akk]);
            *reinterpret_cast<uint4*>(&Abl[row][akk]) =
                *reinterpret_cast<const uint4*>(&Al[(size_t)(m0 + row) * K + k0 + akk]);
            *reinterpret_cast<uint4*>(&Bbh[row][akk]) =
                *reinterpret_cast<const uint4*>(&Bth[(size_t)(n0 + row) * K + k0 + akk]);
            *reinterpret_cast<uint4*>(&Bbl[row][akk]) =
                *reinterpret_cast<const uint4*>(&Btl[(size_t)(n0 + row) * K + k0 + akk]);
        }
        __syncthreads();
#pragma unroll
        for (int ks = 0; ks < 2; ks++) {
            bf16x8 ah[4], al_[4];
#pragma unroll
            for (int mt = 0; mt < 4; mt++) {
                ah[mt]  = *reinterpret_cast<const bf16x8*>(&Abh[wr + mt * 16 + l15][ks * 32 + lh * 8]);
                al_[mt] = *reinterpret_cast<const bf16x8*>(&Abl[wr + mt * 16 + l15][ks * 32 + lh * 8]);
            }
#pragma unroll
            for (int nt = 0; nt < 4; nt++) {
                bf16x8 bh = *reinterpret_cast<const bf16x8*>(&Bbh[wc + nt * 16 + l15][ks * 32 + lh * 8]);
                bf16x8 bl = *reinterpret_cast<const bf16x8*>(&Bbl[wc + nt * 16 + l15][ks * 32 + lh * 8]);
#pragma unroll
                for (int mt = 0; mt < 4; mt++) {
                    acc[mt][nt] = MFMA(ah[mt], bh, acc[mt][nt]);
                    acc[mt][nt] = MFMA(ah[mt], bl, acc[mt][nt]);
                    acc[mt][nt] = MFMA(al_[mt], bh, acc[mt][nt]);
                }
            }
        }
    }
#pragma unroll
    for (int nt = 0; nt < 4; nt++) {
        int col = n0 + wc + nt * 16 + l15;
        float bs = bias[col];
#pragma unroll
        for (int mt = 0; mt < 4; mt++)
#pragma unroll
            for (int r = 0; r < 4; r++)
                C[(size_t)(m0 + wr + mt * 16 + lh * 4 + r) * N + col] = acc[mt][nt][r] + bs;
    }
}

// ---------------------------------------------------------------------------
// Kernel 4: Hp = pack(layernorm(unpack(Hp) + add) * g + b)
// ---------------------------------------------------------------------------
__global__ __launch_bounds__(256) void ln_residual(uint* __restrict__ Hp,
                                                   const float* __restrict__ add,
                                                   const float* __restrict__ g,
                                                   const float* __restrict__ bta) {
    int row = blockIdx.x * 4 + (threadIdx.x >> 6);
    int lane = threadIdx.x & 63;
    uint* hp = Hp + (size_t)row * DD;
    const float* ap = add + (size_t)row * DD;
    float v[8];
    float sum = 0.f;
#pragma unroll
    for (int i = 0; i < 8; i++) {
        int d = lane + i * 64;
        v[i] = unpackf(hp[d]) + ap[d];
        sum += v[i];
    }
#pragma unroll
    for (int off = 32; off > 0; off >>= 1) sum += __shfl_xor(sum, off);
    float mu = sum * (1.f / DD);
    float s2 = 0.f;
#pragma unroll
    for (int i = 0; i < 8; i++) {
        float d2 = v[i] - mu;
        s2 += d2 * d2;
    }
#pragma unroll
    for (int off = 32; off > 0; off >>= 1) s2 += __shfl_xor(s2, off);
    float inv = rsqrtf(s2 * (1.f / DD) + 1e-5f);
#pragma unroll
    for (int i = 0; i < 8; i++) {
        int d = lane + i * 64;
        hp[d] = packsplit((v[i] - mu) * inv * g[d] + bta[d]);
    }
}

// swizzled fragment read from an unpadded [128][64] plane:
// logical 16B chunk (ks*4+lh) of row -> physical chunk XOR (row&7)
#define SWZREAD(plane, row, ks) \
    (*reinterpret_cast<const bf16x8*>(&(plane)[row][((((ks) * 4 + lh) ^ ((row) & 7)) * 8)]))

// ---------------------------------------------------------------------------
// Kernel 5: fused FFN, 128x128 tile, BK=64, 512 thr / 8 waves.  (r14-proven)
// Per k-tile: bar -> issue B-DMA (latency hides under A2) -> A2 on matrix
// pipe -> bar(drain) -> main GEMM. Single-buffered sB -> 73 KB, 2 blocks/CU.
// ---------------------------------------------------------------------------
__global__ __launch_bounds__(512, 4) void ffn_split(const uint* __restrict__ Hp,
                                                    const ushort_t* __restrict__ W1th,
                                                    const ushort_t* __restrict__ W1tl,
                                                    const float* __restrict__ b1,
                                                    const ushort_t* __restrict__ W2th,
                                                    const ushort_t* __restrict__ W2tl,
                                                    const float* __restrict__ b2,
                                                    const float* __restrict__ theta,
                                                    float* __restrict__ outp) {
    __shared__ __align__(16) ushort_t Abh[128][72], Abl[128][72];
    __shared__ __align__(16) ushort_t sBh[128][64], sBl[128][64];
    __shared__ __align__(16) ushort_t qsh[129][8], qsl[129][8];
    __shared__ float tcs[8];

    int t = threadIdx.x;
    int m0 = (int)(blockIdx.x >> 2) * 128;
    int n0 = (int)(blockIdx.x & 3) * 128;
    if (t < 8) {
        tcs[t] = cosf(theta[t]);
        qsh[128][t] = 0;
        qsl[128][t] = 0;
    }
    __syncthreads();
#pragma unroll
    for (int i = 0; i < 2; i++) {
        int idx = t + i * 512;
        int m = idx >> 3, n = idx & 7;
        float q = cosf(unpackf(Hp[(size_t)(m0 + m) * DD + n])) * tcs[n];
        ushort_t hb, lb; tsplit(q, hb, lb);
        qsh[m][n] = hb;
        qsl[m][n] = lb;
    }

    int w = t >> 6, ln = t & 63, l15 = ln & 15, lh = ln >> 4;
    int wr = (w >> 2) * 64, wc = (w & 3) * 32;
    bool lh0 = (lh == 0);
    f32x4 z4 = {0.f, 0.f, 0.f, 0.f};
    bf16x8 z8 = {0, 0, 0, 0, 0, 0, 0, 0};
    f32x4 acc[4][2];
#pragma unroll
    for (int i = 0; i < 4; i++)
#pragma unroll
        for (int j = 0; j < 2; j++) acc[i][j] = z4;

    int srow = ln >> 3;
    int schunk = (ln & 7) ^ srow;

    // W1 fragment prefetch for tile 0
    bf16x8 rwh[4], rwl[4];
#pragma unroll
    for (int fq = 0; fq < 4; fq++) {
        rwh[fq] = *reinterpret_cast<const bf16x8*>(&W1th[(size_t)(fq * 16 + l15) * 8]);
        rwl[fq] = *reinterpret_cast<const bf16x8*>(&W1tl[(size_t)(fq * 16 + l15) * 8]);
    }

    for (int k0 = 0; k0 < FF; k0 += 64) {
        __syncthreads();   // prev GEMM done -> Ab & sB free; qs visible (iter 0)
        // ---- issue B tile DMA (completes under the A2 phase below)
#pragma unroll
        for (int p = 0; p < 2; p++) {
            int rbase = (w + p * 8) * 8;
            int grow = rbase + srow;
            int gc = k0 + schunk * 8;
            gload16(&W2th[(size_t)(n0 + grow) * FF + gc], &sBh[rbase][0]);
            gload16(&W2tl[(size_t)(n0 + grow) * FF + gc], &sBl[rbase][0]);
        }
        // ---- A2 via MFMA using prefetched W1 frags (wave w -> rows w*16..+15)
        {
            bf16x8 wh[4], wl[4];
#pragma unroll
            for (int fq = 0; fq < 4; fq++) {
                wh[fq] = lh0 ? rwh[fq] : z8;
                wl[fq] = lh0 ? rwl[fq] : z8;
            }
            int m = w * 16 + l15;
            int mrow = lh0 ? m : 128;
            bf16x8 qh  = *reinterpret_cast<const bf16x8*>(&qsh[mrow][0]);
            bf16x8 ql_ = *reinterpret_cast<const bf16x8*>(&qsl[mrow][0]);
#pragma unroll
            for (int fq = 0; fq < 4; fq++) {
                f32x4 d = z4;
                d = MFMA(wh[fq], qh, d);
                d = MFMA(wh[fq], ql_, d);
                d = MFMA(wl[fq], qh, d);
                float4 b1v = *reinterpret_cast<const float4*>(&b1[k0 + fq * 16 + lh * 4]);
                float v0 = fmaxf(d[0] + b1v.x, 0.f);
                float v1 = fmaxf(d[1] + b1v.y, 0.f);
                float v2 = fmaxf(d[2] + b1v.z, 0.f);
                float v3 = fmaxf(d[3] + b1v.w, 0.f);
                ushort_t h0_, l0_, h1_, l1_, h2_, l2_, h3_, l3_;
                tsplit_fast(v0, h0_, l0_);
                tsplit_fast(v1, h1_, l1_);
                tsplit_fast(v2, h2_, l2_);
                tsplit_fast(v3, h3_, l3_);
                uint2 hu, lu;
                hu.x = (uint)h0_ | ((uint)h1_ << 16);
                hu.y = (uint)h2_ | ((uint)h3_ << 16);
                lu.x = (uint)l0_ | ((uint)l1_ << 16);
                lu.y = (uint)l2_ | ((uint)l3_ << 16);
                *reinterpret_cast<uint2*>(&Abh[m][fq * 16 + lh * 4]) = hu;
                *reinterpret_cast<uint2*>(&Abl[m][fq * 16 + lh * 4]) = lu;
            }
        }
        __syncthreads();   // A2 visible + B DMA drained
        // ---- W1 prefetch for next tile (covered by main GEMM)
        if (k0 + 64 < FF) {
            int k1 = k0 + 64;
#pragma unroll
            for (int fq = 0; fq < 4; fq++) {
                rwh[fq] = *reinterpret_cast<const bf16x8*>(&W1th[(size_t)(k1 + fq * 16 + l15) * 8]);
                rwl[fq] = *reinterpret_cast<const bf16x8*>(&W1tl[(size_t)(k1 + fq * 16 + l15) * 8]);
            }
        }
        // ---- main GEMM: wave owns 64x32
#pragma unroll
        for (int ks = 0; ks < 2; ks++) {
            bf16x8 ah[4], al_[4];
#pragma unroll
            for (int mt = 0; mt < 4; mt++) {
                ah[mt]  = *reinterpret_cast<const bf16x8*>(&Abh[wr + mt * 16 + l15][ks * 32 + lh * 8]);
                al_[mt] = *reinterpret_cast<const bf16x8*>(&Abl[wr + mt * 16 + l15][ks * 32 + lh * 8]);
            }
#pragma unroll
            for (int nt = 0; nt < 2; nt++) {
                int row = wc + nt * 16 + l15;
                bf16x8 bh = SWZREAD(sBh, row, ks);
                bf16x8 bl = SWZREAD(sBl, row, ks);
#pragma unroll
                for (int mt = 0; mt < 4; mt++) {
                    acc[mt][nt] = MFMA(ah[mt], bh, acc[mt][nt]);
                    acc[mt][nt] = MFMA(ah[mt], bl, acc[mt][nt]);
                    acc[mt][nt] = MFMA(al_[mt], bh, acc[mt][nt]);
                }
            }
        }
    }
#pragma unroll
    for (int nt = 0; nt < 2; nt++) {
        int col = n0 + wc + nt * 16 + l15;
        float bs = b2[col];
#pragma unroll
        for (int mt = 0; mt < 4; mt++)
#pragma unroll
            for (int r = 0; r < 4; r++)
                outp[(size_t)(m0 + wr + mt * 16 + lh * 4 + r) * DD + col] = acc[mt][nt][r] + bs;
    }
}

// ---------------------------------------------------------------------------
// Kernel 6: pooled[b,d] = mean_s h[b,s,d]
// ---------------------------------------------------------------------------
__global__ __launch_bounds__(256) void pool_mean(const uint* __restrict__ Hp,
                                                 float* __restrict__ pooled) {
    int idx = blockIdx.x * 256 + threadIdx.x;
    if (idx >= BB * DD) return;
    int b = idx >> 9, d = idx & 511;
    float s = 0.f;
    for (int j = 0; j < SS; j++) s += unpackf(Hp[((size_t)b * SS + j) * DD + d]);
    pooled[idx] = s * (1.f / SS);
}

// ---------------------------------------------------------------------------
// Kernel 7: out[b,c] = pooled[b,:] . clf_w[:,c] + clf_b[c]
// ---------------------------------------------------------------------------
__global__ __launch_bounds__(64) void classifier(const float* __restrict__ pooled,
                                                 const float* __restrict__ W,
                                                 const float* __restrict__ bias,
                                                 float* __restrict__ out) {
    int o = blockIdx.x;
    int b = o / CC, c = o % CC;
    int lane = threadIdx.x;
    float s = 0.f;
    for (int d = lane; d < DD; d += 64) s += pooled[b * DD + d] * W[d * CC + c];
#pragma unroll
    for (int off = 32; off > 0; off >>= 1) s += __shfl_xor(s, off);
    if (lane == 0) out[o] = s + bias[c];
}

// ---------------------------------------------------------------------------
extern "C" void kernel_launch(void* const* d_in, const int* in_sizes, int n_in,
                              void* d_out, int out_size, void* d_ws, size_t ws_size,
                              hipStream_t stream) {
    (void)in_sizes; (void)n_in; (void)out_size; (void)ws_size;
    const int*   x      = (const int*)d_in[0];
    const float* emb    = (const float*)d_in[1];
    const float* ln1_g  = (const float*)d_in[2];
    const float* ln1_b  = (const float*)d_in[3];
    const float* ln2_g  = (const float*)d_in[4];
    const float* ln2_b  = (const float*)d_in[5];
    const float* attn_w = (const float*)d_in[6];
    const float* attn_b = (const float*)d_in[7];
    const float* theta  = (const float*)d_in[8];
    const float* ffn_w1 = (const float*)d_in[9];
    const float* ffn_b1 = (const float*)d_in[10];
    const float* ffn_w2 = (const float*)d_in[11];
    const float* ffn_b2 = (const float*)d_in[12];
    const float* clf_w  = (const float*)d_in[13];
    const float* clf_b  = (const float*)d_in[14];
    float* out = (float*)d_out;

    char* ws = (char*)d_ws;
    uint*     Hp     = (uint*)(ws);                     // 32 MB packed hi|lo
    float*    t2     = (float*)(ws + 33554432);         // 32 MB fp32
    ushort_t* t1h    = (ushort_t*)(ws + 67108864);      // 16 MB bf16 hi
    ushort_t* t1l    = (ushort_t*)(ws + 83886080);      // 16 MB bf16 lo
    float*    pooled = (float*)(ws + 100663296);        // 64 KB
    ushort_t* Wath   = (ushort_t*)(ws + 100728832);     // 512 KB attn_w hi
    ushort_t* Watl   = (ushort_t*)(ws + 101253120);     // 512 KB attn_w lo
    ushort_t* W1th6  = (ushort_t*)(ws + 101777408);     // 192 KB W1t hi
    ushort_t* W1tl6  = (ushort_t*)(ws + 101974016);     // 192 KB W1t lo
    ushort_t* W2th   = (ushort_t*)(ws + 67108864);      // reuses t1h region
    ushort_t* W2tl   = (ushort_t*)(ws + 67108864 + 2097152);

    embed_pe<<<(BB * SS * DD + 255) / 256, 256, 0, stream>>>(x, emb, Hp);
    prep_w1t<<<dim3(FF / 256, LL), 256, 0, stream>>>(ffn_w1, W1th6, W1tl6);

    for (int l = 0; l < LL; l++) {
        flash_attn_split<<<dim3(SS / 128, HH, BB), 512, 0, stream>>>(Hp, t1h, t1l);
        transpose_split_w<<<(DD / 64) * (DD / 64), 256, 0, stream>>>(
            attn_w + (size_t)l * DD * DD, Wath, Watl, DD, DD);
        gemm_split<<<(16384 / 128) * (DD / 128), 256, 0, stream>>>(
            t1h, t1l, Wath, Watl, attn_b + l * DD, t2, BB * SS, DD, DD);
        ln_residual<<<BB * SS / 4, 256, 0, stream>>>(Hp, t2, ln1_g + l * DD, ln1_b + l * DD);
        transpose_split_w<<<(FF / 64) * (DD / 64), 256, 0, stream>>>(
            ffn_w2 + (size_t)l * FF * DD, W2th, W2tl, FF, DD);
        ffn_split<<<(16384 / 128) * (DD / 128), 512, 0, stream>>>(
            Hp, W1th6 + (size_t)l * FF * 8, W1tl6 + (size_t)l * FF * 8, ffn_b1 + l * FF,
            W2th, W2tl, ffn_b2 + l * DD, theta + l * NQ, t2);
        ln_residual<<<BB * SS / 4, 256, 0, stream>>>(Hp, t2, ln2_g + l * DD, ln2_b + l * DD);
    }

    pool_mean<<<(BB * DD + 255) / 256, 256, 0, stream>>>(Hp, pooled);
    classifier<<<BB * CC, 64, 0, stream>>>(pooled, clf_w, clf_b, out);
}

// Round 17
// 1779.609 us; speedup vs baseline: 1.5030x; 1.0404x over previous
//
#include <hip/hip_runtime.h>
#include <hip/hip_bf16.h>
#include <math.h>

#define BB 32
#define SS 512
#define DD 512
#define HH 8
#define DK 64
#define LL 6
#define NQ 8
#define FF 2048
#define CC 10

typedef unsigned int uint;
typedef unsigned short ushort_t;
using bf16x8 = __attribute__((ext_vector_type(8))) short;
using f32x4  = __attribute__((ext_vector_type(4))) float;

#define MFMA(a, b, c) __builtin_amdgcn_mfma_f32_16x16x32_bf16((a), (b), (c), 0, 0, 0)

union U8 { ushort_t u[8]; bf16x8 v; };

__device__ __forceinline__ void gload16(const void* g, void* l) {
    __builtin_amdgcn_global_load_lds((__attribute__((address_space(1))) void*)g,
                                     (__attribute__((address_space(3))) void*)l,
                                     16, 0, 0);
}

__device__ inline ushort_t f2bf(float x) {           // fp32 -> bf16, RNE
    uint u = __float_as_uint(x);
    u += 0x7FFFu + ((u >> 16) & 1u);
    return (ushort_t)(u >> 16);
}
// truncation split: hi = top 16 bits, lo = RNE(residual)
__device__ inline void tsplit(float v, ushort_t& hi, ushort_t& lo) {
    uint u = __float_as_uint(v);
    hi = (ushort_t)(u >> 16);
    lo = f2bf(v - __uint_as_float(u & 0xFFFF0000u));
}
// cheap variant (lo also truncated): used on A2 only
__device__ inline void tsplit_fast(float v, ushort_t& hi, ushort_t& lo) {
    uint u = __float_as_uint(v);
    hi = (ushort_t)(u >> 16);
    float res = v - __uint_as_float(u & 0xFFFF0000u);
    lo = (ushort_t)(__float_as_uint(res) >> 16);
}
__device__ inline uint packsplit(float v) {
    uint u = __float_as_uint(v) & 0xFFFF0000u;
    uint ru = __float_as_uint(v - __uint_as_float(u));
    ru += 0x7FFFu + ((ru >> 16) & 1u);
    return u | (ru >> 16);
}
__device__ inline float unpackf(uint u) {
    return __uint_as_float(u & 0xFFFF0000u) + __uint_as_float(u << 16);
}

// ---------------------------------------------------------------------------
// Kernel 1: h = emb[x] + pe, stored packed hi|lo bf16
// ---------------------------------------------------------------------------
__global__ __launch_bounds__(256) void embed_pe(const int* __restrict__ x,
                                                const float* __restrict__ emb,
                                                uint* __restrict__ Hp) {
    int idx = blockIdx.x * 256 + threadIdx.x;
    if (idx >= BB * SS * DD) return;
    int d = idx & (DD - 1);
    int s = (idx >> 9) & (SS - 1);
    int tok = x[idx >> 9];
    int i2 = d >> 1;
    float freq = expf((float)(2 * i2) * (-9.210340371976184f / (float)DD));
    float ang = (float)s * freq;
    float pe = (d & 1) ? cosf(ang) : sinf(ang);
    Hp[idx] = packsplit(emb[(size_t)tok * DD + d] + pe);
}

// ---------------------------------------------------------------------------
// Kernel 1b: transpose + split fp32 [K][N] -> bf16 hi/lo [N][K]
// grid.y = layer (stride lstrideK*N elements in, lstrideK*N out)
// ---------------------------------------------------------------------------
__global__ __launch_bounds__(256) void transpose_split_w(const float* __restrict__ in,
                                                         ushort_t* __restrict__ outh,
                                                         ushort_t* __restrict__ outl,
                                                         int K, int N) {
    __shared__ ushort_t th[64][68], tl[64][68];
    size_t loff = (size_t)blockIdx.y * K * N;
    const float* src = in + loff;
    ushort_t* oh = outh + loff;
    ushort_t* ol = outl + loff;
    int nb = N >> 6;
    int k0 = ((int)blockIdx.x / nb) << 6;
    int n0 = ((int)blockIdx.x % nb) << 6;
    int t = threadIdx.x;
    int r = t >> 2, cb = (t & 3) << 4;
#pragma unroll
    for (int c = 0; c < 4; c++) {
        float4 v = *reinterpret_cast<const float4*>(&src[(size_t)(k0 + r) * N + n0 + cb + 4 * c]);
        float vv[4] = {v.x, v.y, v.z, v.w};
#pragma unroll
        for (int e = 0; e < 4; e++) {
            ushort_t hb, lb; tsplit(vv[e], hb, lb);
            th[r][cb + 4 * c + e] = hb;
            tl[r][cb + 4 * c + e] = lb;
        }
    }
    __syncthreads();
    int n = t >> 2, kb = (t & 3) << 4;
#pragma unroll
    for (int c = 0; c < 4; c++) {
        ushort4 ohv, olv;
        ohv.x = th[kb + 4 * c + 0][n]; olv.x = tl[kb + 4 * c + 0][n];
        ohv.y = th[kb + 4 * c + 1][n]; olv.y = tl[kb + 4 * c + 1][n];
        ohv.z = th[kb + 4 * c + 2][n]; olv.z = tl[kb + 4 * c + 2][n];
        ohv.w = th[kb + 4 * c + 3][n]; olv.w = tl[kb + 4 * c + 3][n];
        *reinterpret_cast<ushort4*>(&oh[(size_t)(n0 + n) * K + k0 + kb + 4 * c]) = ohv;
        *reinterpret_cast<ushort4*>(&ol[(size_t)(n0 + n) * K + k0 + kb + 4 * c]) = olv;
    }
}

// ---------------------------------------------------------------------------
// Kernel 1c: W1 [L][8][FF] -> transposed split planes [L][FF][8] bf16 hi/lo
// ---------------------------------------------------------------------------
__global__ __launch_bounds__(256) void prep_w1t(const float* __restrict__ W1all,
                                                ushort_t* __restrict__ outh,
                                                ushort_t* __restrict__ outl) {
    int l = blockIdx.y;
    int f = blockIdx.x * 256 + threadIdx.x;
    const float* W1 = W1all + (size_t)l * NQ * FF;
    U8 ph, pl;
#pragma unroll
    for (int n = 0; n < 8; n++) {
        ushort_t hb, lb; tsplit(W1[n * FF + f], hb, lb);
        ph.u[n] = hb; pl.u[n] = lb;
    }
    *reinterpret_cast<bf16x8*>(&outh[((size_t)l * FF + f) * 8]) = ph.v;
    *reinterpret_cast<bf16x8*>(&outl[((size_t)l * FF + f) * 8]) = pl.v;
}

// ---------------------------------------------------------------------------
// Kernel 2: split-precision MFMA flash attention, QBLK=128, 8 waves.
// (r8-proven + setprio hints around MFMA clusters)
// ---------------------------------------------------------------------------
__global__ __launch_bounds__(512, 4) void flash_attn_split(const uint* __restrict__ Hp,
                                                           ushort_t* __restrict__ outh,
                                                           ushort_t* __restrict__ outl) {
    __shared__ __align__(16) ushort_t Kh[64][72], Kl[64][72];
    __shared__ __align__(16) ushort_t Vh[64][72], Vl[64][72];   // [d][j]
    __shared__ __align__(16) ushort_t Ph[128][72], Pl[128][72];

    int i0 = blockIdx.x * 128;
    int h0 = blockIdx.y * DK;
    int b  = blockIdx.z;
    const uint* baseH = Hp + (size_t)b * (SS * DD);

    int t = threadIdx.x;
    int w = t >> 6;
    int ln = t & 63;
    int l15 = ln & 15, lh = ln >> 4;

    bf16x8 aqh0, aqh1, aql0, aql1;
    {
        int row = i0 + w * 16 + l15;
        const uint* src = &baseH[(size_t)row * DD + h0 + lh * 8];
        uint4 p0 = *reinterpret_cast<const uint4*>(src);
        uint4 p1 = *reinterpret_cast<const uint4*>(src + 4);
        uint4 p2 = *reinterpret_cast<const uint4*>(src + 32);
        uint4 p3 = *reinterpret_cast<const uint4*>(src + 36);
        uint a0[8] = {p0.x, p0.y, p0.z, p0.w, p1.x, p1.y, p1.z, p1.w};
        uint a1[8] = {p2.x, p2.y, p2.z, p2.w, p3.x, p3.y, p3.z, p3.w};
        U8 h0u, l0u, h1u, l1u;
#pragma unroll
        for (int e = 0; e < 8; e++) {
            h0u.u[e] = (ushort_t)(a0[e] >> 16);
            l0u.u[e] = (ushort_t)(a0[e] & 0xFFFFu);
            h1u.u[e] = (ushort_t)(a1[e] >> 16);
            l1u.u[e] = (ushort_t)(a1[e] & 0xFFFFu);
        }
        aqh0 = h0u.v; aql0 = l0u.v; aqh1 = h1u.v; aql1 = l1u.v;
    }

    float m_[4], l_[4], al[4];
    f32x4 acc[4];
    f32x4 z4 = {0.f, 0.f, 0.f, 0.f};
#pragma unroll
    for (int r = 0; r < 4; r++) { m_[r] = -1e30f; l_[r] = 0.f; acc[r] = z4; }

    int kr = t >> 3, kcb = (t & 7) * 8;
    int vc = t & 7, vr = t >> 3;

    for (int j0 = 0; j0 < SS; j0 += 64) {
        __syncthreads();
        {
            const uint* src = &baseH[(size_t)(j0 + kr) * DD + h0 + kcb];
            uint4 p0 = *reinterpret_cast<const uint4*>(src);
            uint4 p1 = *reinterpret_cast<const uint4*>(src + 4);
            uint a[8] = {p0.x, p0.y, p0.z, p0.w, p1.x, p1.y, p1.z, p1.w};
            U8 kh, kl;
#pragma unroll
            for (int e = 0; e < 8; e++) {
                kh.u[e] = (ushort_t)(a[e] >> 16);
                kl.u[e] = (ushort_t)(a[e] & 0xFFFFu);
            }
            *reinterpret_cast<bf16x8*>(&Kh[kr][kcb]) = kh.v;
            *reinterpret_cast<bf16x8*>(&Kl[kr][kcb]) = kl.v;
        }
        __syncthreads();
#pragma unroll
        for (int e = 0; e < 8; e++) {
            int d = vc + 8 * e;
            Vh[d][vr] = Kh[vr][d];
            Vl[d][vr] = Kl[vr][d];
        }
        f32x4 sc[4];
        __builtin_amdgcn_s_setprio(1);
#pragma unroll
        for (int tt = 0; tt < 4; tt++) {
            bf16x8 bh0 = *reinterpret_cast<const bf16x8*>(&Kh[tt * 16 + l15][lh * 8]);
            bf16x8 bh1 = *reinterpret_cast<const bf16x8*>(&Kh[tt * 16 + l15][32 + lh * 8]);
            bf16x8 bl0 = *reinterpret_cast<const bf16x8*>(&Kl[tt * 16 + l15][lh * 8]);
            bf16x8 bl1 = *reinterpret_cast<const bf16x8*>(&Kl[tt * 16 + l15][32 + lh * 8]);
            f32x4 s = z4;
            s = MFMA(aqh0, bh0, s);
            s = MFMA(aqh1, bh1, s);
            s = MFMA(aqh0, bl0, s);
            s = MFMA(aqh1, bl1, s);
            s = MFMA(aql0, bh0, s);
            s = MFMA(aql1, bh1, s);
            sc[tt] = s * 0.125f;
        }
        __builtin_amdgcn_s_setprio(0);
#pragma unroll
        for (int r = 0; r < 4; r++) {
            float mx = fmaxf(fmaxf(sc[0][r], sc[1][r]), fmaxf(sc[2][r], sc[3][r]));
            mx = fmaxf(mx, __shfl_xor(mx, 1));
            mx = fmaxf(mx, __shfl_xor(mx, 2));
            mx = fmaxf(mx, __shfl_xor(mx, 4));
            mx = fmaxf(mx, __shfl_xor(mx, 8));
            float nm = fmaxf(m_[r], mx);
            al[r] = __expf(m_[r] - nm);
            m_[r] = nm;
            float rs = 0.f;
#pragma unroll
            for (int tt = 0; tt < 4; tt++) {
                float p = __expf(sc[tt][r] - nm);
                sc[tt][r] = p;
                rs += p;
            }
            rs += __shfl_xor(rs, 1);
            rs += __shfl_xor(rs, 2);
            rs += __shfl_xor(rs, 4);
            rs += __shfl_xor(rs, 8);
            l_[r] = l_[r] * al[r] + rs;
        }
#pragma unroll
        for (int tt = 0; tt < 4; tt++)
#pragma unroll
            for (int r = 0; r < 4; r++) {
                ushort_t hb, lb; tsplit(sc[tt][r], hb, lb);
                Ph[w * 16 + lh * 4 + r][tt * 16 + l15] = hb;
                Pl[w * 16 + lh * 4 + r][tt * 16 + l15] = lb;
            }
        __syncthreads();
#pragma unroll
        for (int td = 0; td < 4; td++) {
            acc[td][0] *= al[0];
            acc[td][1] *= al[1];
            acc[td][2] *= al[2];
            acc[td][3] *= al[3];
        }
        bf16x8 aph0 = *reinterpret_cast<const bf16x8*>(&Ph[w * 16 + l15][lh * 8]);
        bf16x8 aph1 = *reinterpret_cast<const bf16x8*>(&Ph[w * 16 + l15][32 + lh * 8]);
        bf16x8 apl0 = *reinterpret_cast<const bf16x8*>(&Pl[w * 16 + l15][lh * 8]);
        bf16x8 apl1 = *reinterpret_cast<const bf16x8*>(&Pl[w * 16 + l15][32 + lh * 8]);
        __builtin_amdgcn_s_setprio(1);
#pragma unroll
        for (int td = 0; td < 4; td++) {
            bf16x8 bvh0 = *reinterpret_cast<const bf16x8*>(&Vh[td * 16 + l15][lh * 8]);
            bf16x8 bvh1 = *reinterpret_cast<const bf16x8*>(&Vh[td * 16 + l15][32 + lh * 8]);
            bf16x8 bvl0 = *reinterpret_cast<const bf16x8*>(&Vl[td * 16 + l15][lh * 8]);
            bf16x8 bvl1 = *reinterpret_cast<const bf16x8*>(&Vl[td * 16 + l15][32 + lh * 8]);
            acc[td] = MFMA(aph0, bvh0, acc[td]);
            acc[td] = MFMA(aph1, bvh1, acc[td]);
            acc[td] = MFMA(aph0, bvl0, acc[td]);
            acc[td] = MFMA(aph1, bvl1, acc[td]);
            acc[td] = MFMA(apl0, bvh0, acc[td]);
            acc[td] = MFMA(apl1, bvh1, acc[td]);
        }
        __builtin_amdgcn_s_setprio(0);
    }

#pragma unroll
    for (int r = 0; r < 4; r++) {
        float inv = 1.f / l_[r];
        int row = i0 + w * 16 + lh * 4 + r;
#pragma unroll
        for (int td = 0; td < 4; td++) {
            float o = acc[td][r] * inv;
            ushort_t hb, lb; tsplit(o, hb, lb);
            size_t idx = (size_t)b * SS * DD + (size_t)row * DD + h0 + td * 16 + l15;
            outh[idx] = hb;
            outl[idx] = lb;
        }
    }
}

// ---------------------------------------------------------------------------
// Kernel 3: C fp32 = A(hi/lo [M][K]) @ Bt(pre-split hi/lo [N][K]) + bias.
// 128x128 tile, BK=64, 256 thr / 4 waves (r8-proven). Pure uint4 staging.
// ---------------------------------------------------------------------------
__global__ __launch_bounds__(256, 2) void gemm_split(const ushort_t* __restrict__ Ah,
                                                     const ushort_t* __restrict__ Al,
                                                     const ushort_t* __restrict__ Bth,
                                                     const ushort_t* __restrict__ Btl,
                                                     const float* __restrict__ bias,
                                                     float* __restrict__ C,
                                                     int M, int N, int K) {
    __shared__ __align__(16) ushort_t Abh[128][72], Abl[128][72];
    __shared__ __align__(16) ushort_t Bbh[128][72], Bbl[128][72];
    int nb = N >> 7;
    int m0 = ((int)blockIdx.x / nb) << 7;
    int n0 = ((int)blockIdx.x % nb) << 7;
    int t = threadIdx.x;
    int w = t >> 6, ln = t & 63, l15 = ln & 15, lh = ln >> 4;
    int wr = (w >> 1) * 64, wc = (w & 1) * 64;

    f32x4 z4 = {0.f, 0.f, 0.f, 0.f};
    f32x4 acc[4][4];
#pragma unroll
    for (int i = 0; i < 4; i++)
#pragma unroll
        for (int j = 0; j < 4; j++) acc[i][j] = z4;

    int arr = t >> 3, akk = (t & 7) * 8;

    for (int k0 = 0; k0 < K; k0 += 64) {
        __syncthreads();
#pragma unroll
        for (int r = 0; r < 4; r++) {
            int row = arr + r * 32;
            *reinterpret_cast<uint4*>(&Abh[row][akk]) =
                *reinterpret_cast<const uint4*>(&Ah[(size_t)(m0 + row) * K + k0 + akk]);
            *reinterpret_cast<uint4*>(&Abl[row][akk]) =
                *reinterpret_cast<const uint4*>(&Al[(size_t)(m0 + row) * K + k0 + akk]);
            *reinterpret_cast<uint4*>(&Bbh[row][akk]) =
                *reinterpret_cast<const uint4*>(&Bth[(size_t)(n0 + row) * K + k0 + akk]);
            *reinterpret_cast<uint4*>(&Bbl[row][akk]) =
                *reinterpret_cast<const uint4*>(&Btl[(size_t)(n0 + row) * K + k0 + akk]);
        }
        __syncthreads();
#pragma unroll
        for (int ks = 0; ks < 2; ks++) {
            bf16x8 ah[4], al_[4];
#pragma unroll
            for (int mt = 0; mt < 4; mt++) {
                ah[mt]  = *reinterpret_cast<const bf16x8*>(&Abh[wr + mt * 16 + l15][ks * 32 + lh * 8]);
                al_[mt] = *reinterpret_cast<const bf16x8*>(&Abl[wr + mt * 16 + l15][ks * 32 + lh * 8]);
            }
#pragma unroll
            for (int nt = 0; nt < 4; nt++) {
                bf16x8 bh = *reinterpret_cast<const bf16x8*>(&Bbh[wc + nt * 16 + l15][ks * 32 + lh * 8]);
                bf16x8 bl = *reinterpret_cast<const bf16x8*>(&Bbl[wc + nt * 16 + l15][ks * 32 + lh * 8]);
#pragma unroll
                for (int mt = 0; mt < 4; mt++) {
                    acc[mt][nt] = MFMA(ah[mt], bh, acc[mt][nt]);
                    acc[mt][nt] = MFMA(ah[mt], bl, acc[mt][nt]);
                    acc[mt][nt] = MFMA(al_[mt], bh, acc[mt][nt]);
                }
            }
        }
    }
#pragma unroll
    for (int nt = 0; nt < 4; nt++) {
        int col = n0 + wc + nt * 16 + l15;
        float bs = bias[col];
#pragma unroll
        for (int mt = 0; mt < 4; mt++)
#pragma unroll
            for (int r = 0; r < 4; r++)
                C[(size_t)(m0 + wr + mt * 16 + lh * 4 + r) * N + col] = acc[mt][nt][r] + bs;
    }
}

// ---------------------------------------------------------------------------
// Kernel 4: Hp = pack(layernorm(unpack(Hp) + add) * g + b)
// ---------------------------------------------------------------------------
__global__ __launch_bounds__(256) void ln_residual(uint* __restrict__ Hp,
                                                   const float* __restrict__ add,
                                                   const float* __restrict__ g,
                                                   const float* __restrict__ bta) {
    int row = blockIdx.x * 4 + (threadIdx.x >> 6);
    int lane = threadIdx.x & 63;
    uint* hp = Hp + (size_t)row * DD;
    const float* ap = add + (size_t)row * DD;
    float v[8];
    float sum = 0.f;
#pragma unroll
    for (int i = 0; i < 8; i++) {
        int d = lane + i * 64;
        v[i] = unpackf(hp[d]) + ap[d];
        sum += v[i];
    }
#pragma unroll
    for (int off = 32; off > 0; off >>= 1) sum += __shfl_xor(sum, off);
    float mu = sum * (1.f / DD);
    float s2 = 0.f;
#pragma unroll
    for (int i = 0; i < 8; i++) {
        float d2 = v[i] - mu;
        s2 += d2 * d2;
    }
#pragma unroll
    for (int off = 32; off > 0; off >>= 1) s2 += __shfl_xor(s2, off);
    float inv = rsqrtf(s2 * (1.f / DD) + 1e-5f);
#pragma unroll
    for (int i = 0; i < 8; i++) {
        int d = lane + i * 64;
        hp[d] = packsplit((v[i] - mu) * inv * g[d] + bta[d]);
    }
}

// swizzled fragment read from an unpadded [128][64] plane:
// logical 16B chunk (ks*4+lh) of row -> physical chunk XOR (row&7)
#define SWZREAD(plane, row, ks) \
    (*reinterpret_cast<const bf16x8*>(&(plane)[row][((((ks) * 4 + lh) ^ ((row) & 7)) * 8)]))

// ---------------------------------------------------------------------------
// Kernel 5: fused FFN, 128x128 tile, BK=64, 512 thr / 8 waves.  (r14-proven
// + setprio hints). Per k-tile: bar -> B-DMA under A2 -> bar -> main GEMM.
// ---------------------------------------------------------------------------
__global__ __launch_bounds__(512, 4) void ffn_split(const uint* __restrict__ Hp,
                                                    const ushort_t* __restrict__ W1th,
                                                    const ushort_t* __restrict__ W1tl,
                                                    const float* __restrict__ b1,
                                                    const ushort_t* __restrict__ W2th,
                                                    const ushort_t* __restrict__ W2tl,
                                                    const float* __restrict__ b2,
                                                    const float* __restrict__ theta,
                                                    float* __restrict__ outp) {
    __shared__ __align__(16) ushort_t Abh[128][72], Abl[128][72];
    __shared__ __align__(16) ushort_t sBh[128][64], sBl[128][64];
    __shared__ __align__(16) ushort_t qsh[129][8], qsl[129][8];
    __shared__ float tcs[8];

    int t = threadIdx.x;
    int m0 = (int)(blockIdx.x >> 2) * 128;
    int n0 = (int)(blockIdx.x & 3) * 128;
    if (t < 8) {
        tcs[t] = cosf(theta[t]);
        qsh[128][t] = 0;
        qsl[128][t] = 0;
    }
    __syncthreads();
#pragma unroll
    for (int i = 0; i < 2; i++) {
        int idx = t + i * 512;
        int m = idx >> 3, n = idx & 7;
        float q = cosf(unpackf(Hp[(size_t)(m0 + m) * DD + n])) * tcs[n];
        ushort_t hb, lb; tsplit(q, hb, lb);
        qsh[m][n] = hb;
        qsl[m][n] = lb;
    }

    int w = t >> 6, ln = t & 63, l15 = ln & 15, lh = ln >> 4;
    int wr = (w >> 2) * 64, wc = (w & 3) * 32;
    bool lh0 = (lh == 0);
    f32x4 z4 = {0.f, 0.f, 0.f, 0.f};
    bf16x8 z8 = {0, 0, 0, 0, 0, 0, 0, 0};
    f32x4 acc[4][2];
#pragma unroll
    for (int i = 0; i < 4; i++)
#pragma unroll
        for (int j = 0; j < 2; j++) acc[i][j] = z4;

    int srow = ln >> 3;
    int schunk = (ln & 7) ^ srow;

    // W1 fragment prefetch for tile 0
    bf16x8 rwh[4], rwl[4];
#pragma unroll
    for (int fq = 0; fq < 4; fq++) {
        rwh[fq] = *reinterpret_cast<const bf16x8*>(&W1th[(size_t)(fq * 16 + l15) * 8]);
        rwl[fq] = *reinterpret_cast<const bf16x8*>(&W1tl[(size_t)(fq * 16 + l15) * 8]);
    }

    for (int k0 = 0; k0 < FF; k0 += 64) {
        __syncthreads();   // prev GEMM done -> Ab & sB free; qs visible (iter 0)
        // ---- issue B tile DMA (completes under the A2 phase below)
#pragma unroll
        for (int p = 0; p < 2; p++) {
            int rbase = (w + p * 8) * 8;
            int grow = rbase + srow;
            int gc = k0 + schunk * 8;
            gload16(&W2th[(size_t)(n0 + grow) * FF + gc], &sBh[rbase][0]);
            gload16(&W2tl[(size_t)(n0 + grow) * FF + gc], &sBl[rbase][0]);
        }
        // ---- A2 via MFMA using prefetched W1 frags (wave w -> rows w*16..+15)
        {
            bf16x8 wh[4], wl[4];
#pragma unroll
            for (int fq = 0; fq < 4; fq++) {
                wh[fq] = lh0 ? rwh[fq] : z8;
                wl[fq] = lh0 ? rwl[fq] : z8;
            }
            int m = w * 16 + l15;
            int mrow = lh0 ? m : 128;
            bf16x8 qh  = *reinterpret_cast<const bf16x8*>(&qsh[mrow][0]);
            bf16x8 ql_ = *reinterpret_cast<const bf16x8*>(&qsl[mrow][0]);
            __builtin_amdgcn_s_setprio(1);
#pragma unroll
            for (int fq = 0; fq < 4; fq++) {
                f32x4 d = z4;
                d = MFMA(wh[fq], qh, d);
                d = MFMA(wh[fq], ql_, d);
                d = MFMA(wl[fq], qh, d);
                float4 b1v = *reinterpret_cast<const float4*>(&b1[k0 + fq * 16 + lh * 4]);
                float v0 = fmaxf(d[0] + b1v.x, 0.f);
                float v1 = fmaxf(d[1] + b1v.y, 0.f);
                float v2 = fmaxf(d[2] + b1v.z, 0.f);
                float v3 = fmaxf(d[3] + b1v.w, 0.f);
                ushort_t h0_, l0_, h1_, l1_, h2_, l2_, h3_, l3_;
                tsplit_fast(v0, h0_, l0_);
                tsplit_fast(v1, h1_, l1_);
                tsplit_fast(v2, h2_, l2_);
                tsplit_fast(v3, h3_, l3_);
                uint2 hu, lu;
                hu.x = (uint)h0_ | ((uint)h1_ << 16);
                hu.y = (uint)h2_ | ((uint)h3_ << 16);
                lu.x = (uint)l0_ | ((uint)l1_ << 16);
                lu.y = (uint)l2_ | ((uint)l3_ << 16);
                *reinterpret_cast<uint2*>(&Abh[m][fq * 16 + lh * 4]) = hu;
                *reinterpret_cast<uint2*>(&Abl[m][fq * 16 + lh * 4]) = lu;
            }
            __builtin_amdgcn_s_setprio(0);
        }
        __syncthreads();   // A2 visible + B DMA drained
        // ---- W1 prefetch for next tile (covered by main GEMM)
        if (k0 + 64 < FF) {
            int k1 = k0 + 64;
#pragma unroll
            for (int fq = 0; fq < 4; fq++) {
                rwh[fq] = *reinterpret_cast<const bf16x8*>(&W1th[(size_t)(k1 + fq * 16 + l15) * 8]);
                rwl[fq] = *reinterpret_cast<const bf16x8*>(&W1tl[(size_t)(k1 + fq * 16 + l15) * 8]);
            }
        }
        // ---- main GEMM: wave owns 64x32
        __builtin_amdgcn_s_setprio(1);
#pragma unroll
        for (int ks = 0; ks < 2; ks++) {
            bf16x8 ah[4], al_[4];
#pragma unroll
            for (int mt = 0; mt < 4; mt++) {
                ah[mt]  = *reinterpret_cast<const bf16x8*>(&Abh[wr + mt * 16 + l15][ks * 32 + lh * 8]);
                al_[mt] = *reinterpret_cast<const bf16x8*>(&Abl[wr + mt * 16 + l15][ks * 32 + lh * 8]);
            }
#pragma unroll
            for (int nt = 0; nt < 2; nt++) {
                int row = wc + nt * 16 + l15;
                bf16x8 bh = SWZREAD(sBh, row, ks);
                bf16x8 bl = SWZREAD(sBl, row, ks);
#pragma unroll
                for (int mt = 0; mt < 4; mt++) {
                    acc[mt][nt] = MFMA(ah[mt], bh, acc[mt][nt]);
                    acc[mt][nt] = MFMA(ah[mt], bl, acc[mt][nt]);
                    acc[mt][nt] = MFMA(al_[mt], bh, acc[mt][nt]);
                }
            }
        }
        __builtin_amdgcn_s_setprio(0);
    }
#pragma unroll
    for (int nt = 0; nt < 2; nt++) {
        int col = n0 + wc + nt * 16 + l15;
        float bs = b2[col];
#pragma unroll
        for (int mt = 0; mt < 4; mt++)
#pragma unroll
            for (int r = 0; r < 4; r++)
                outp[(size_t)(m0 + wr + mt * 16 + lh * 4 + r) * DD + col] = acc[mt][nt][r] + bs;
    }
}

// ---------------------------------------------------------------------------
// Kernel 6: pooled[b,d] = mean_s h[b,s,d]
// ---------------------------------------------------------------------------
__global__ __launch_bounds__(256) void pool_mean(const uint* __restrict__ Hp,
                                                 float* __restrict__ pooled) {
    int idx = blockIdx.x * 256 + threadIdx.x;
    if (idx >= BB * DD) return;
    int b = idx >> 9, d = idx & 511;
    float s = 0.f;
    for (int j = 0; j < SS; j++) s += unpackf(Hp[((size_t)b * SS + j) * DD + d]);
    pooled[idx] = s * (1.f / SS);
}

// ---------------------------------------------------------------------------
// Kernel 7: out[b,c] = pooled[b,:] . clf_w[:,c] + clf_b[c]
// ---------------------------------------------------------------------------
__global__ __launch_bounds__(64) void classifier(const float* __restrict__ pooled,
                                                 const float* __restrict__ W,
                                                 const float* __restrict__ bias,
                                                 float* __restrict__ out) {
    int o = blockIdx.x;
    int b = o / CC, c = o % CC;
    int lane = threadIdx.x;
    float s = 0.f;
    for (int d = lane; d < DD; d += 64) s += pooled[b * DD + d] * W[d * CC + c];
#pragma unroll
    for (int off = 32; off > 0; off >>= 1) s += __shfl_xor(s, off);
    if (lane == 0) out[o] = s + bias[c];
}

// ---------------------------------------------------------------------------
extern "C" void kernel_launch(void* const* d_in, const int* in_sizes, int n_in,
                              void* d_out, int out_size, void* d_ws, size_t ws_size,
                              hipStream_t stream) {
    (void)in_sizes; (void)n_in; (void)out_size;
    const int*   x      = (const int*)d_in[0];
    const float* emb    = (const float*)d_in[1];
    const float* ln1_g  = (const float*)d_in[2];
    const float* ln1_b  = (const float*)d_in[3];
    const float* ln2_g  = (const float*)d_in[4];
    const float* ln2_b  = (const float*)d_in[5];
    const float* attn_w = (const float*)d_in[6];
    const float* attn_b = (const float*)d_in[7];
    const float* theta  = (const float*)d_in[8];
    const float* ffn_w1 = (const float*)d_in[9];
    const float* ffn_b1 = (const float*)d_in[10];
    const float* ffn_w2 = (const float*)d_in[11];
    const float* ffn_b2 = (const float*)d_in[12];
    const float* clf_w  = (const float*)d_in[13];
    const float* clf_b  = (const float*)d_in[14];
    float* out = (float*)d_out;

    char* ws = (char*)d_ws;
    uint*     Hp     = (uint*)(ws);                     // 32 MB packed hi|lo
    float*    t2     = (float*)(ws + 33554432);         // 32 MB fp32
    ushort_t* t1h    = (ushort_t*)(ws + 67108864);      // 16 MB bf16 hi
    ushort_t* t1l    = (ushort_t*)(ws + 83886080);      // 16 MB bf16 lo
    float*    pooled = (float*)(ws + 100663296);        // 64 KB
    ushort_t* Wath   = (ushort_t*)(ws + 100728832);     // 512 KB attn_w hi
    ushort_t* Watl   = (ushort_t*)(ws + 101253120);     // 512 KB attn_w lo
    ushort_t* W1th6  = (ushort_t*)(ws + 101777408);     // 192 KB W1t hi
    ushort_t* W1tl6  = (ushort_t*)(ws + 101974016);     // 192 KB W1t lo
    ushort_t* W2th   = (ushort_t*)(ws + 67108864);      // reuses t1h region
    ushort_t* W2tl   = (ushort_t*)(ws + 67108864 + 2097152);
    // optional hoisted attn_w planes for all 6 layers (6 MB), if ws allows
    ushort_t* Wath6  = (ushort_t*)(ws + 102170624);     // 3 MB
    ushort_t* Watl6  = (ushort_t*)(ws + 105316352);     // 3 MB (ends 108,462,080)
    bool hoist = ws_size >= 108462080ull;

    embed_pe<<<(BB * SS * DD + 255) / 256, 256, 0, stream>>>(x, emb, Hp);
    prep_w1t<<<dim3(FF / 256, LL), 256, 0, stream>>>(ffn_w1, W1th6, W1tl6);
    if (hoist)
        transpose_split_w<<<dim3(64, LL), 256, 0, stream>>>(attn_w, Wath6, Watl6, DD, DD);

    for (int l = 0; l < LL; l++) {
        flash_attn_split<<<dim3(SS / 128, HH, BB), 512, 0, stream>>>(Hp, t1h, t1l);
        const ushort_t* WathL;
        const ushort_t* WatlL;
        if (hoist) {
            WathL = Wath6 + (size_t)l * DD * DD;
            WatlL = Watl6 + (size_t)l * DD * DD;
        } else {
            transpose_split_w<<<dim3(64, 1), 256, 0, stream>>>(
                attn_w + (size_t)l * DD * DD, Wath, Watl, DD, DD);
            WathL = Wath;
            WatlL = Watl;
        }
        gemm_split<<<(16384 / 128) * (DD / 128), 256, 0, stream>>>(
            t1h, t1l, WathL, WatlL, attn_b + l * DD, t2, BB * SS, DD, DD);
        ln_residual<<<BB * SS / 4, 256, 0, stream>>>(Hp, t2, ln1_g + l * DD, ln1_b + l * DD);
        transpose_split_w<<<dim3((FF / 64) * (DD / 64), 1), 256, 0, stream>>>(
            ffn_w2 + (size_t)l * FF * DD, W2th, W2tl, FF, DD);
        ffn_split<<<(16384 / 128) * (DD / 128), 512, 0, stream>>>(
            Hp, W1th6 + (size_t)l * FF * 8, W1tl6 + (size_t)l * FF * 8, ffn_b1 + l * FF,
            W2th, W2tl, ffn_b2 + l * DD, theta + l * NQ, t2);
        ln_residual<<<BB * SS / 4, 256, 0, stream>>>(Hp, t2, ln2_g + l * DD, ln2_b + l * DD);
    }

    pool_mean<<<(BB * DD + 255) / 256, 256, 0, stream>>>(Hp, pooled);
    classifier<<<BB * CC, 64, 0, stream>>>(pooled, clf_w, clf_b, out);
}

// Round 18
// 1758.666 us; speedup vs baseline: 1.5209x; 1.0119x over previous
//
#include <hip/hip_runtime.h>
#include <hip/hip_bf16.h>
#include <math.h>

#define BB 32
#define SS 512
#define DD 512
#define HH 8
#define DK 64
#define LL 6
#define NQ 8
#define FF 2048
#define CC 10

typedef unsigned int uint;
typedef unsigned short ushort_t;
using bf16x8 = __attribute__((ext_vector_type(8))) short;
using f32x4  = __attribute__((ext_vector_type(4))) float;

#define MFMA(a, b, c) __builtin_amdgcn_mfma_f32_16x16x32_bf16((a), (b), (c), 0, 0, 0)

union U8 { ushort_t u[8]; bf16x8 v; };

__device__ __forceinline__ void gload16(const void* g, void* l) {
    __builtin_amdgcn_global_load_lds((__attribute__((address_space(1))) void*)g,
                                     (__attribute__((address_space(3))) void*)l,
                                     16, 0, 0);
}

__device__ inline ushort_t f2bf(float x) {           // fp32 -> bf16, RNE
    uint u = __float_as_uint(x);
    u += 0x7FFFu + ((u >> 16) & 1u);
    return (ushort_t)(u >> 16);
}
// truncation split: hi = top 16 bits, lo = RNE(residual)
__device__ inline void tsplit(float v, ushort_t& hi, ushort_t& lo) {
    uint u = __float_as_uint(v);
    hi = (ushort_t)(u >> 16);
    lo = f2bf(v - __uint_as_float(u & 0xFFFF0000u));
}
// cheap variant (lo also truncated): A2 / P / O paths
__device__ inline void tsplit_fast(float v, ushort_t& hi, ushort_t& lo) {
    uint u = __float_as_uint(v);
    hi = (ushort_t)(u >> 16);
    float res = v - __uint_as_float(u & 0xFFFF0000u);
    lo = (ushort_t)(__float_as_uint(res) >> 16);
}
__device__ inline uint packsplit(float v) {
    uint u = __float_as_uint(v) & 0xFFFF0000u;
    uint ru = __float_as_uint(v - __uint_as_float(u));
    ru += 0x7FFFu + ((ru >> 16) & 1u);
    return u | (ru >> 16);
}
__device__ inline float unpackf(uint u) {
    return __uint_as_float(u & 0xFFFF0000u) + __uint_as_float(u << 16);
}

// ---------------------------------------------------------------------------
// Kernel 1: h = emb[x] + pe, stored packed hi|lo bf16
// ---------------------------------------------------------------------------
__global__ __launch_bounds__(256) void embed_pe(const int* __restrict__ x,
                                                const float* __restrict__ emb,
                                                uint* __restrict__ Hp) {
    int idx = blockIdx.x * 256 + threadIdx.x;
    if (idx >= BB * SS * DD) return;
    int d = idx & (DD - 1);
    int s = (idx >> 9) & (SS - 1);
    int tok = x[idx >> 9];
    int i2 = d >> 1;
    float freq = expf((float)(2 * i2) * (-9.210340371976184f / (float)DD));
    float ang = (float)s * freq;
    float pe = (d & 1) ? cosf(ang) : sinf(ang);
    Hp[idx] = packsplit(emb[(size_t)tok * DD + d] + pe);
}

// ---------------------------------------------------------------------------
// Kernel 1b: transpose + split fp32 [K][N] -> bf16 hi/lo [N][K]
// grid.y = layer (stride K*N elements both in and out)
// ---------------------------------------------------------------------------
__global__ __launch_bounds__(256) void transpose_split_w(const float* __restrict__ in,
                                                         ushort_t* __restrict__ outh,
                                                         ushort_t* __restrict__ outl,
                                                         int K, int N) {
    __shared__ ushort_t th[64][68], tl[64][68];
    size_t loff = (size_t)blockIdx.y * K * N;
    const float* src = in + loff;
    ushort_t* oh = outh + loff;
    ushort_t* ol = outl + loff;
    int nb = N >> 6;
    int k0 = ((int)blockIdx.x / nb) << 6;
    int n0 = ((int)blockIdx.x % nb) << 6;
    int t = threadIdx.x;
    int r = t >> 2, cb = (t & 3) << 4;
#pragma unroll
    for (int c = 0; c < 4; c++) {
        float4 v = *reinterpret_cast<const float4*>(&src[(size_t)(k0 + r) * N + n0 + cb + 4 * c]);
        float vv[4] = {v.x, v.y, v.z, v.w};
#pragma unroll
        for (int e = 0; e < 4; e++) {
            ushort_t hb, lb; tsplit(vv[e], hb, lb);
            th[r][cb + 4 * c + e] = hb;
            tl[r][cb + 4 * c + e] = lb;
        }
    }
    __syncthreads();
    int n = t >> 2, kb = (t & 3) << 4;
#pragma unroll
    for (int c = 0; c < 4; c++) {
        ushort4 ohv, olv;
        ohv.x = th[kb + 4 * c + 0][n]; olv.x = tl[kb + 4 * c + 0][n];
        ohv.y = th[kb + 4 * c + 1][n]; olv.y = tl[kb + 4 * c + 1][n];
        ohv.z = th[kb + 4 * c + 2][n]; olv.z = tl[kb + 4 * c + 2][n];
        ohv.w = th[kb + 4 * c + 3][n]; olv.w = tl[kb + 4 * c + 3][n];
        *reinterpret_cast<ushort4*>(&oh[(size_t)(n0 + n) * K + k0 + kb + 4 * c]) = ohv;
        *reinterpret_cast<ushort4*>(&ol[(size_t)(n0 + n) * K + k0 + kb + 4 * c]) = olv;
    }
}

// ---------------------------------------------------------------------------
// Kernel 1c: W1 [L][8][FF] -> transposed split planes [L][FF][8] bf16 hi/lo
// ---------------------------------------------------------------------------
__global__ __launch_bounds__(256) void prep_w1t(const float* __restrict__ W1all,
                                                ushort_t* __restrict__ outh,
                                                ushort_t* __restrict__ outl) {
    int l = blockIdx.y;
    int f = blockIdx.x * 256 + threadIdx.x;
    const float* W1 = W1all + (size_t)l * NQ * FF;
    U8 ph, pl;
#pragma unroll
    for (int n = 0; n < 8; n++) {
        ushort_t hb, lb; tsplit(W1[n * FF + f], hb, lb);
        ph.u[n] = hb; pl.u[n] = lb;
    }
    *reinterpret_cast<bf16x8*>(&outh[((size_t)l * FF + f) * 8]) = ph.v;
    *reinterpret_cast<bf16x8*>(&outl[((size_t)l * FF + f) * 8]) = pl.v;
}

// ---------------------------------------------------------------------------
// Kernel 2: split-precision MFMA flash attention, QBLK=128, 8 waves.
// (r17 + tsplit_fast on P and O writes)
// ---------------------------------------------------------------------------
__global__ __launch_bounds__(512, 4) void flash_attn_split(const uint* __restrict__ Hp,
                                                           ushort_t* __restrict__ outh,
                                                           ushort_t* __restrict__ outl) {
    __shared__ __align__(16) ushort_t Kh[64][72], Kl[64][72];
    __shared__ __align__(16) ushort_t Vh[64][72], Vl[64][72];   // [d][j]
    __shared__ __align__(16) ushort_t Ph[128][72], Pl[128][72];

    int i0 = blockIdx.x * 128;
    int h0 = blockIdx.y * DK;
    int b  = blockIdx.z;
    const uint* baseH = Hp + (size_t)b * (SS * DD);

    int t = threadIdx.x;
    int w = t >> 6;
    int ln = t & 63;
    int l15 = ln & 15, lh = ln >> 4;

    bf16x8 aqh0, aqh1, aql0, aql1;
    {
        int row = i0 + w * 16 + l15;
        const uint* src = &baseH[(size_t)row * DD + h0 + lh * 8];
        uint4 p0 = *reinterpret_cast<const uint4*>(src);
        uint4 p1 = *reinterpret_cast<const uint4*>(src + 4);
        uint4 p2 = *reinterpret_cast<const uint4*>(src + 32);
        uint4 p3 = *reinterpret_cast<const uint4*>(src + 36);
        uint a0[8] = {p0.x, p0.y, p0.z, p0.w, p1.x, p1.y, p1.z, p1.w};
        uint a1[8] = {p2.x, p2.y, p2.z, p2.w, p3.x, p3.y, p3.z, p3.w};
        U8 h0u, l0u, h1u, l1u;
#pragma unroll
        for (int e = 0; e < 8; e++) {
            h0u.u[e] = (ushort_t)(a0[e] >> 16);
            l0u.u[e] = (ushort_t)(a0[e] & 0xFFFFu);
            h1u.u[e] = (ushort_t)(a1[e] >> 16);
            l1u.u[e] = (ushort_t)(a1[e] & 0xFFFFu);
        }
        aqh0 = h0u.v; aql0 = l0u.v; aqh1 = h1u.v; aql1 = l1u.v;
    }

    float m_[4], l_[4], al[4];
    f32x4 acc[4];
    f32x4 z4 = {0.f, 0.f, 0.f, 0.f};
#pragma unroll
    for (int r = 0; r < 4; r++) { m_[r] = -1e30f; l_[r] = 0.f; acc[r] = z4; }

    int kr = t >> 3, kcb = (t & 7) * 8;
    int vc = t & 7, vr = t >> 3;

    for (int j0 = 0; j0 < SS; j0 += 64) {
        __syncthreads();
        {
            const uint* src = &baseH[(size_t)(j0 + kr) * DD + h0 + kcb];
            uint4 p0 = *reinterpret_cast<const uint4*>(src);
            uint4 p1 = *reinterpret_cast<const uint4*>(src + 4);
            uint a[8] = {p0.x, p0.y, p0.z, p0.w, p1.x, p1.y, p1.z, p1.w};
            U8 kh, kl;
#pragma unroll
            for (int e = 0; e < 8; e++) {
                kh.u[e] = (ushort_t)(a[e] >> 16);
                kl.u[e] = (ushort_t)(a[e] & 0xFFFFu);
            }
            *reinterpret_cast<bf16x8*>(&Kh[kr][kcb]) = kh.v;
            *reinterpret_cast<bf16x8*>(&Kl[kr][kcb]) = kl.v;
        }
        __syncthreads();
#pragma unroll
        for (int e = 0; e < 8; e++) {
            int d = vc + 8 * e;
            Vh[d][vr] = Kh[vr][d];
            Vl[d][vr] = Kl[vr][d];
        }
        f32x4 sc[4];
        __builtin_amdgcn_s_setprio(1);
#pragma unroll
        for (int tt = 0; tt < 4; tt++) {
            bf16x8 bh0 = *reinterpret_cast<const bf16x8*>(&Kh[tt * 16 + l15][lh * 8]);
            bf16x8 bh1 = *reinterpret_cast<const bf16x8*>(&Kh[tt * 16 + l15][32 + lh * 8]);
            bf16x8 bl0 = *reinterpret_cast<const bf16x8*>(&Kl[tt * 16 + l15][lh * 8]);
            bf16x8 bl1 = *reinterpret_cast<const bf16x8*>(&Kl[tt * 16 + l15][32 + lh * 8]);
            f32x4 s = z4;
            s = MFMA(aqh0, bh0, s);
            s = MFMA(aqh1, bh1, s);
            s = MFMA(aqh0, bl0, s);
            s = MFMA(aqh1, bl1, s);
            s = MFMA(aql0, bh0, s);
            s = MFMA(aql1, bh1, s);
            sc[tt] = s * 0.125f;
        }
        __builtin_amdgcn_s_setprio(0);
#pragma unroll
        for (int r = 0; r < 4; r++) {
            float mx = fmaxf(fmaxf(sc[0][r], sc[1][r]), fmaxf(sc[2][r], sc[3][r]));
            mx = fmaxf(mx, __shfl_xor(mx, 1));
            mx = fmaxf(mx, __shfl_xor(mx, 2));
            mx = fmaxf(mx, __shfl_xor(mx, 4));
            mx = fmaxf(mx, __shfl_xor(mx, 8));
            float nm = fmaxf(m_[r], mx);
            al[r] = __expf(m_[r] - nm);
            m_[r] = nm;
            float rs = 0.f;
#pragma unroll
            for (int tt = 0; tt < 4; tt++) {
                float p = __expf(sc[tt][r] - nm);
                sc[tt][r] = p;
                rs += p;
            }
            rs += __shfl_xor(rs, 1);
            rs += __shfl_xor(rs, 2);
            rs += __shfl_xor(rs, 4);
            rs += __shfl_xor(rs, 8);
            l_[r] = l_[r] * al[r] + rs;
        }
#pragma unroll
        for (int tt = 0; tt < 4; tt++)
#pragma unroll
            for (int r = 0; r < 4; r++) {
                ushort_t hb, lb; tsplit_fast(sc[tt][r], hb, lb);
                Ph[w * 16 + lh * 4 + r][tt * 16 + l15] = hb;
                Pl[w * 16 + lh * 4 + r][tt * 16 + l15] = lb;
            }
        __syncthreads();
#pragma unroll
        for (int td = 0; td < 4; td++) {
            acc[td][0] *= al[0];
            acc[td][1] *= al[1];
            acc[td][2] *= al[2];
            acc[td][3] *= al[3];
        }
        bf16x8 aph0 = *reinterpret_cast<const bf16x8*>(&Ph[w * 16 + l15][lh * 8]);
        bf16x8 aph1 = *reinterpret_cast<const bf16x8*>(&Ph[w * 16 + l15][32 + lh * 8]);
        bf16x8 apl0 = *reinterpret_cast<const bf16x8*>(&Pl[w * 16 + l15][lh * 8]);
        bf16x8 apl1 = *reinterpret_cast<const bf16x8*>(&Pl[w * 16 + l15][32 + lh * 8]);
        __builtin_amdgcn_s_setprio(1);
#pragma unroll
        for (int td = 0; td < 4; td++) {
            bf16x8 bvh0 = *reinterpret_cast<const bf16x8*>(&Vh[td * 16 + l15][lh * 8]);
            bf16x8 bvh1 = *reinterpret_cast<const bf16x8*>(&Vh[td * 16 + l15][32 + lh * 8]);
            bf16x8 bvl0 = *reinterpret_cast<const bf16x8*>(&Vl[td * 16 + l15][lh * 8]);
            bf16x8 bvl1 = *reinterpret_cast<const bf16x8*>(&Vl[td * 16 + l15][32 + lh * 8]);
            acc[td] = MFMA(aph0, bvh0, acc[td]);
            acc[td] = MFMA(aph1, bvh1, acc[td]);
            acc[td] = MFMA(aph0, bvl0, acc[td]);
            acc[td] = MFMA(aph1, bvl1, acc[td]);
            acc[td] = MFMA(apl0, bvh0, acc[td]);
            acc[td] = MFMA(apl1, bvh1, acc[td]);
        }
        __builtin_amdgcn_s_setprio(0);
    }

#pragma unroll
    for (int r = 0; r < 4; r++) {
        float inv = 1.f / l_[r];
        int row = i0 + w * 16 + lh * 4 + r;
#pragma unroll
        for (int td = 0; td < 4; td++) {
            float o = acc[td][r] * inv;
            ushort_t hb, lb; tsplit_fast(o, hb, lb);
            size_t idx = (size_t)b * SS * DD + (size_t)row * DD + h0 + td * 16 + l15;
            outh[idx] = hb;
            outl[idx] = lb;
        }
    }
}

// ---------------------------------------------------------------------------
// Kernel 3: C fp32 = A(hi/lo [M][K]) @ Bt(pre-split hi/lo [N][K]) + bias.
// 128x128 tile, BK=64, 256 thr / 4 waves (r8-proven). Pure uint4 staging.
// ---------------------------------------------------------------------------
__global__ __launch_bounds__(256, 2) void gemm_split(const ushort_t* __restrict__ Ah,
                                                     const ushort_t* __restrict__ Al,
                                                     const ushort_t* __restrict__ Bth,
                                                     const ushort_t* __restrict__ Btl,
                                                     const float* __restrict__ bias,
                                                     float* __restrict__ C,
                                                     int M, int N, int K) {
    __shared__ __align__(16) ushort_t Abh[128][72], Abl[128][72];
    __shared__ __align__(16) ushort_t Bbh[128][72], Bbl[128][72];
    int nb = N >> 7;
    int m0 = ((int)blockIdx.x / nb) << 7;
    int n0 = ((int)blockIdx.x % nb) << 7;
    int t = threadIdx.x;
    int w = t >> 6, ln = t & 63, l15 = ln & 15, lh = ln >> 4;
    int wr = (w >> 1) * 64, wc = (w & 1) * 64;

    f32x4 z4 = {0.f, 0.f, 0.f, 0.f};
    f32x4 acc[4][4];
#pragma unroll
    for (int i = 0; i < 4; i++)
#pragma unroll
        for (int j = 0; j < 4; j++) acc[i][j] = z4;

    int arr = t >> 3, akk = (t & 7) * 8;

    for (int k0 = 0; k0 < K; k0 += 64) {
        __syncthreads();
#pragma unroll
        for (int r = 0; r < 4; r++) {
            int row = arr + r * 32;
            *reinterpret_cast<uint4*>(&Abh[row][akk]) =
                *reinterpret_cast<const uint4*>(&Ah[(size_t)(m0 + row) * K + k0 + akk]);
            *reinterpret_cast<uint4*>(&Abl[row][akk]) =
                *reinterpret_cast<const uint4*>(&Al[(size_t)(m0 + row) * K + k0 + akk]);
            *reinterpret_cast<uint4*>(&Bbh[row][akk]) =
                *reinterpret_cast<const uint4*>(&Bth[(size_t)(n0 + row) * K + k0 + akk]);
            *reinterpret_cast<uint4*>(&Bbl[row][akk]) =
                *reinterpret_cast<const uint4*>(&Btl[(size_t)(n0 + row) * K + k0 + akk]);
        }
        __syncthreads();
#pragma unroll
        for (int ks = 0; ks < 2; ks++) {
            bf16x8 ah[4], al_[4];
#pragma unroll
            for (int mt = 0; mt < 4; mt++) {
                ah[mt]  = *reinterpret_cast<const bf16x8*>(&Abh[wr + mt * 16 + l15][ks * 32 + lh * 8]);
                al_[mt] = *reinterpret_cast<const bf16x8*>(&Abl[wr + mt * 16 + l15][ks * 32 + lh * 8]);
            }
#pragma unroll
            for (int nt = 0; nt < 4; nt++) {
                bf16x8 bh = *reinterpret_cast<const bf16x8*>(&Bbh[wc + nt * 16 + l15][ks * 32 + lh * 8]);
                bf16x8 bl = *reinterpret_cast<const bf16x8*>(&Bbl[wc + nt * 16 + l15][ks * 32 + lh * 8]);
#pragma unroll
                for (int mt = 0; mt < 4; mt++) {
                    acc[mt][nt] = MFMA(ah[mt], bh, acc[mt][nt]);
                    acc[mt][nt] = MFMA(ah[mt], bl, acc[mt][nt]);
                    acc[mt][nt] = MFMA(al_[mt], bh, acc[mt][nt]);
                }
            }
        }
    }
#pragma unroll
    for (int nt = 0; nt < 4; nt++) {
        int col = n0 + wc + nt * 16 + l15;
        float bs = bias[col];
#pragma unroll
        for (int mt = 0; mt < 4; mt++)
#pragma unroll
            for (int r = 0; r < 4; r++)
                C[(size_t)(m0 + wr + mt * 16 + lh * 4 + r) * N + col] = acc[mt][nt][r] + bs;
    }
}

// ---------------------------------------------------------------------------
// Kernel 4: Hp = pack(layernorm(unpack(Hp) + add) * g + b)
// ---------------------------------------------------------------------------
__global__ __launch_bounds__(256) void ln_residual(uint* __restrict__ Hp,
                                                   const float* __restrict__ add,
                                                   const float* __restrict__ g,
                                                   const float* __restrict__ bta) {
    int row = blockIdx.x * 4 + (threadIdx.x >> 6);
    int lane = threadIdx.x & 63;
    uint* hp = Hp + (size_t)row * DD;
    const float* ap = add + (size_t)row * DD;
    float v[8];
    float sum = 0.f;
#pragma unroll
    for (int i = 0; i < 8; i++) {
        int d = lane + i * 64;
        v[i] = unpackf(hp[d]) + ap[d];
        sum += v[i];
    }
#pragma unroll
    for (int off = 32; off > 0; off >>= 1) sum += __shfl_xor(sum, off);
    float mu = sum * (1.f / DD);
    float s2 = 0.f;
#pragma unroll
    for (int i = 0; i < 8; i++) {
        float d2 = v[i] - mu;
        s2 += d2 * d2;
    }
#pragma unroll
    for (int off = 32; off > 0; off >>= 1) s2 += __shfl_xor(s2, off);
    float inv = rsqrtf(s2 * (1.f / DD) + 1e-5f);
#pragma unroll
    for (int i = 0; i < 8; i++) {
        int d = lane + i * 64;
        hp[d] = packsplit((v[i] - mu) * inv * g[d] + bta[d]);
    }
}

// swizzled fragment read from an unpadded [128][64] plane:
// logical 16B chunk (ks*4+lh) of row -> physical chunk XOR (row&7)
#define SWZREAD(plane, row, ks) \
    (*reinterpret_cast<const bf16x8*>(&(plane)[row][((((ks) * 4 + lh) ^ ((row) & 7)) * 8)]))

// ---------------------------------------------------------------------------
// Kernel 5: fused FFN, 128x128 tile, BK=64, 512 thr / 8 waves.  (r17-proven)
// ---------------------------------------------------------------------------
__global__ __launch_bounds__(512, 4) void ffn_split(const uint* __restrict__ Hp,
                                                    const ushort_t* __restrict__ W1th,
                                                    const ushort_t* __restrict__ W1tl,
                                                    const float* __restrict__ b1,
                                                    const ushort_t* __restrict__ W2th,
                                                    const ushort_t* __restrict__ W2tl,
                                                    const float* __restrict__ b2,
                                                    const float* __restrict__ theta,
                                                    float* __restrict__ outp) {
    __shared__ __align__(16) ushort_t Abh[128][72], Abl[128][72];
    __shared__ __align__(16) ushort_t sBh[128][64], sBl[128][64];
    __shared__ __align__(16) ushort_t qsh[129][8], qsl[129][8];
    __shared__ float tcs[8];

    int t = threadIdx.x;
    int m0 = (int)(blockIdx.x >> 2) * 128;
    int n0 = (int)(blockIdx.x & 3) * 128;
    if (t < 8) {
        tcs[t] = cosf(theta[t]);
        qsh[128][t] = 0;
        qsl[128][t] = 0;
    }
    __syncthreads();
#pragma unroll
    for (int i = 0; i < 2; i++) {
        int idx = t + i * 512;
        int m = idx >> 3, n = idx & 7;
        float q = cosf(unpackf(Hp[(size_t)(m0 + m) * DD + n])) * tcs[n];
        ushort_t hb, lb; tsplit(q, hb, lb);
        qsh[m][n] = hb;
        qsl[m][n] = lb;
    }

    int w = t >> 6, ln = t & 63, l15 = ln & 15, lh = ln >> 4;
    int wr = (w >> 2) * 64, wc = (w & 3) * 32;
    bool lh0 = (lh == 0);
    f32x4 z4 = {0.f, 0.f, 0.f, 0.f};
    bf16x8 z8 = {0, 0, 0, 0, 0, 0, 0, 0};
    f32x4 acc[4][2];
#pragma unroll
    for (int i = 0; i < 4; i++)
#pragma unroll
        for (int j = 0; j < 2; j++) acc[i][j] = z4;

    int srow = ln >> 3;
    int schunk = (ln & 7) ^ srow;

    bf16x8 rwh[4], rwl[4];
#pragma unroll
    for (int fq = 0; fq < 4; fq++) {
        rwh[fq] = *reinterpret_cast<const bf16x8*>(&W1th[(size_t)(fq * 16 + l15) * 8]);
        rwl[fq] = *reinterpret_cast<const bf16x8*>(&W1tl[(size_t)(fq * 16 + l15) * 8]);
    }

    for (int k0 = 0; k0 < FF; k0 += 64) {
        __syncthreads();
#pragma unroll
        for (int p = 0; p < 2; p++) {
            int rbase = (w + p * 8) * 8;
            int grow = rbase + srow;
            int gc = k0 + schunk * 8;
            gload16(&W2th[(size_t)(n0 + grow) * FF + gc], &sBh[rbase][0]);
            gload16(&W2tl[(size_t)(n0 + grow) * FF + gc], &sBl[rbase][0]);
        }
        {
            bf16x8 wh[4], wl[4];
#pragma unroll
            for (int fq = 0; fq < 4; fq++) {
                wh[fq] = lh0 ? rwh[fq] : z8;
                wl[fq] = lh0 ? rwl[fq] : z8;
            }
            int m = w * 16 + l15;
            int mrow = lh0 ? m : 128;
            bf16x8 qh  = *reinterpret_cast<const bf16x8*>(&qsh[mrow][0]);
            bf16x8 ql_ = *reinterpret_cast<const bf16x8*>(&qsl[mrow][0]);
            __builtin_amdgcn_s_setprio(1);
#pragma unroll
            for (int fq = 0; fq < 4; fq++) {
                f32x4 d = z4;
                d = MFMA(wh[fq], qh, d);
                d = MFMA(wh[fq], ql_, d);
                d = MFMA(wl[fq], qh, d);
                float4 b1v = *reinterpret_cast<const float4*>(&b1[k0 + fq * 16 + lh * 4]);
                float v0 = fmaxf(d[0] + b1v.x, 0.f);
                float v1 = fmaxf(d[1] + b1v.y, 0.f);
                float v2 = fmaxf(d[2] + b1v.z, 0.f);
                float v3 = fmaxf(d[3] + b1v.w, 0.f);
                ushort_t h0_, l0_, h1_, l1_, h2_, l2_, h3_, l3_;
                tsplit_fast(v0, h0_, l0_);
                tsplit_fast(v1, h1_, l1_);
                tsplit_fast(v2, h2_, l2_);
                tsplit_fast(v3, h3_, l3_);
                uint2 hu, lu;
                hu.x = (uint)h0_ | ((uint)h1_ << 16);
                hu.y = (uint)h2_ | ((uint)h3_ << 16);
                lu.x = (uint)l0_ | ((uint)l1_ << 16);
                lu.y = (uint)l2_ | ((uint)l3_ << 16);
                *reinterpret_cast<uint2*>(&Abh[m][fq * 16 + lh * 4]) = hu;
                *reinterpret_cast<uint2*>(&Abl[m][fq * 16 + lh * 4]) = lu;
            }
            __builtin_amdgcn_s_setprio(0);
        }
        __syncthreads();
        if (k0 + 64 < FF) {
            int k1 = k0 + 64;
#pragma unroll
            for (int fq = 0; fq < 4; fq++) {
                rwh[fq] = *reinterpret_cast<const bf16x8*>(&W1th[(size_t)(k1 + fq * 16 + l15) * 8]);
                rwl[fq] = *reinterpret_cast<const bf16x8*>(&W1tl[(size_t)(k1 + fq * 16 + l15) * 8]);
            }
        }
        __builtin_amdgcn_s_setprio(1);
#pragma unroll
        for (int ks = 0; ks < 2; ks++) {
            bf16x8 ah[4], al_[4];
#pragma unroll
            for (int mt = 0; mt < 4; mt++) {
                ah[mt]  = *reinterpret_cast<const bf16x8*>(&Abh[wr + mt * 16 + l15][ks * 32 + lh * 8]);
                al_[mt] = *reinterpret_cast<const bf16x8*>(&Abl[wr + mt * 16 + l15][ks * 32 + lh * 8]);
            }
#pragma unroll
            for (int nt = 0; nt < 2; nt++) {
                int row = wc + nt * 16 + l15;
                bf16x8 bh = SWZREAD(sBh, row, ks);
                bf16x8 bl = SWZREAD(sBl, row, ks);
#pragma unroll
                for (int mt = 0; mt < 4; mt++) {
                    acc[mt][nt] = MFMA(ah[mt], bh, acc[mt][nt]);
                    acc[mt][nt] = MFMA(ah[mt], bl, acc[mt][nt]);
                    acc[mt][nt] = MFMA(al_[mt], bh, acc[mt][nt]);
                }
            }
        }
        __builtin_amdgcn_s_setprio(0);
    }
#pragma unroll
    for (int nt = 0; nt < 2; nt++) {
        int col = n0 + wc + nt * 16 + l15;
        float bs = b2[col];
#pragma unroll
        for (int mt = 0; mt < 4; mt++)
#pragma unroll
            for (int r = 0; r < 4; r++)
                outp[(size_t)(m0 + wr + mt * 16 + lh * 4 + r) * DD + col] = acc[mt][nt][r] + bs;
    }
}

// ---------------------------------------------------------------------------
// Kernel 6: pooled[b,d] = mean_s h[b,s,d]
// ---------------------------------------------------------------------------
__global__ __launch_bounds__(256) void pool_mean(const uint* __restrict__ Hp,
                                                 float* __restrict__ pooled) {
    int idx = blockIdx.x * 256 + threadIdx.x;
    if (idx >= BB * DD) return;
    int b = idx >> 9, d = idx & 511;
    float s = 0.f;
    for (int j = 0; j < SS; j++) s += unpackf(Hp[((size_t)b * SS + j) * DD + d]);
    pooled[idx] = s * (1.f / SS);
}

// ---------------------------------------------------------------------------
// Kernel 7: out[b,c] = pooled[b,:] . clf_w[:,c] + clf_b[c]
// ---------------------------------------------------------------------------
__global__ __launch_bounds__(64) void classifier(const float* __restrict__ pooled,
                                                 const float* __restrict__ W,
                                                 const float* __restrict__ bias,
                                                 float* __restrict__ out) {
    int o = blockIdx.x;
    int b = o / CC, c = o % CC;
    int lane = threadIdx.x;
    float s = 0.f;
    for (int d = lane; d < DD; d += 64) s += pooled[b * DD + d] * W[d * CC + c];
#pragma unroll
    for (int off = 32; off > 0; off >>= 1) s += __shfl_xor(s, off);
    if (lane == 0) out[o] = s + bias[c];
}

// ---------------------------------------------------------------------------
extern "C" void kernel_launch(void* const* d_in, const int* in_sizes, int n_in,
                              void* d_out, int out_size, void* d_ws, size_t ws_size,
                              hipStream_t stream) {
    (void)in_sizes; (void)n_in; (void)out_size;
    const int*   x      = (const int*)d_in[0];
    const float* emb    = (const float*)d_in[1];
    const float* ln1_g  = (const float*)d_in[2];
    const float* ln1_b  = (const float*)d_in[3];
    const float* ln2_g  = (const float*)d_in[4];
    const float* ln2_b  = (const float*)d_in[5];
    const float* attn_w = (const float*)d_in[6];
    const float* attn_b = (const float*)d_in[7];
    const float* theta  = (const float*)d_in[8];
    const float* ffn_w1 = (const float*)d_in[9];
    const float* ffn_b1 = (const float*)d_in[10];
    const float* ffn_w2 = (const float*)d_in[11];
    const float* ffn_b2 = (const float*)d_in[12];
    const float* clf_w  = (const float*)d_in[13];
    const float* clf_b  = (const float*)d_in[14];
    float* out = (float*)d_out;

    char* ws = (char*)d_ws;
    uint*     Hp     = (uint*)(ws);                     // 32 MB packed hi|lo
    float*    t2     = (float*)(ws + 33554432);         // 32 MB fp32
    ushort_t* t1h    = (ushort_t*)(ws + 67108864);      // 16 MB bf16 hi
    ushort_t* t1l    = (ushort_t*)(ws + 83886080);      // 16 MB bf16 lo
    float*    pooled = (float*)(ws + 100663296);        // 64 KB
    ushort_t* Wath   = (ushort_t*)(ws + 100728832);     // 512 KB attn_w hi
    ushort_t* Watl   = (ushort_t*)(ws + 101253120);     // 512 KB attn_w lo
    ushort_t* W1th6  = (ushort_t*)(ws + 101777408);     // 192 KB W1t hi
    ushort_t* W1tl6  = (ushort_t*)(ws + 101974016);     // 192 KB W1t lo
    ushort_t* W2th   = (ushort_t*)(ws + 67108864);      // per-layer fallback (aliases t1h)
    ushort_t* W2tl   = (ushort_t*)(ws + 67108864 + 2097152);
    // hoisted weight planes (guarded by ws_size)
    ushort_t* Wath6  = (ushort_t*)(ws + 102170624);     // 3 MB
    ushort_t* Watl6  = (ushort_t*)(ws + 105316352);     // 3 MB (ends 108,462,080)
    ushort_t* W2th6  = (ushort_t*)(ws + 108462080);     // 12 MB
    ushort_t* W2tl6  = (ushort_t*)(ws + 121044992);     // 12 MB (ends 133,627,904)
    bool hoistA  = ws_size >= 108462080ull;
    bool hoistW2 = ws_size >= 133627904ull;

    embed_pe<<<(BB * SS * DD + 255) / 256, 256, 0, stream>>>(x, emb, Hp);
    prep_w1t<<<dim3(FF / 256, LL), 256, 0, stream>>>(ffn_w1, W1th6, W1tl6);
    if (hoistA)
        transpose_split_w<<<dim3(64, LL), 256, 0, stream>>>(attn_w, Wath6, Watl6, DD, DD);
    if (hoistW2)
        transpose_split_w<<<dim3((FF / 64) * (DD / 64), LL), 256, 0, stream>>>(
            ffn_w2, W2th6, W2tl6, FF, DD);

    for (int l = 0; l < LL; l++) {
        flash_attn_split<<<dim3(SS / 128, HH, BB), 512, 0, stream>>>(Hp, t1h, t1l);
        const ushort_t* WathL;
        const ushort_t* WatlL;
        if (hoistA) {
            WathL = Wath6 + (size_t)l * DD * DD;
            WatlL = Watl6 + (size_t)l * DD * DD;
        } else {
            transpose_split_w<<<dim3(64, 1), 256, 0, stream>>>(
                attn_w + (size_t)l * DD * DD, Wath, Watl, DD, DD);
            WathL = Wath;
            WatlL = Watl;
        }
        gemm_split<<<(16384 / 128) * (DD / 128), 256, 0, stream>>>(
            t1h, t1l, WathL, WatlL, attn_b + l * DD, t2, BB * SS, DD, DD);
        ln_residual<<<BB * SS / 4, 256, 0, stream>>>(Hp, t2, ln1_g + l * DD, ln1_b + l * DD);
        const ushort_t* W2thL;
        const ushort_t* W2tlL;
        if (hoistW2) {
            W2thL = W2th6 + (size_t)l * FF * DD;
            W2tlL = W2tl6 + (size_t)l * FF * DD;
        } else {
            transpose_split_w<<<dim3((FF / 64) * (DD / 64), 1), 256, 0, stream>>>(
                ffn_w2 + (size_t)l * FF * DD, W2th, W2tl, FF, DD);
            W2thL = W2th;
            W2tlL = W2tl;
        }
        ffn_split<<<(16384 / 128) * (DD / 128), 512, 0, stream>>>(
            Hp, W1th6 + (size_t)l * FF * 8, W1tl6 + (size_t)l * FF * 8, ffn_b1 + l * FF,
            W2thL, W2tlL, ffn_b2 + l * DD, theta + l * NQ, t2);
        ln_residual<<<BB * SS / 4, 256, 0, stream>>>(Hp, t2, ln2_g + l * DD, ln2_b + l * DD);
    }

    pool_mean<<<(BB * DD + 255) / 256, 256, 0, stream>>>(Hp, pooled);
    classifier<<<BB * CC, 64, 0, stream>>>(pooled, clf_w, clf_b, out);
}